// Round 1
// baseline (2637.056 us; speedup 1.0000x reference)
//
#include <hip/hip_runtime.h>

constexpr float BN_EPS = 1e-5f;

// ---------------- graph preprocessing ----------------

__global__ void k_init_deg(int* __restrict__ deg, int n) {
    int i = blockIdx.x * blockDim.x + threadIdx.x;
    if (i < n) deg[i] = 1;  // self loop
}

__global__ void k_deg(const int* __restrict__ dst, int* __restrict__ deg, int E) {
    int e = blockIdx.x * blockDim.x + threadIdx.x;
    if (e < E) atomicAdd(&deg[dst[e]], 1);
}

__global__ void k_dinv(const int* __restrict__ deg, float* __restrict__ dinv, int n) {
    int i = blockIdx.x * blockDim.x + threadIdx.x;
    if (i < n) dinv[i] = rsqrtf((float)deg[i]);
}

// exclusive scan of in-degree (deg-1) over n nodes; single block of 1024
__global__ void k_scan(const int* __restrict__ deg, int* __restrict__ offs,
                       int* __restrict__ cursor, int n) {
    __shared__ int part[1024];
    int tid = threadIdx.x;
    int chunk = (n + 1023) >> 10;
    int start = tid * chunk;
    int end = min(start + chunk, n);
    int s = 0;
    for (int i = start; i < end; ++i) s += deg[i] - 1;
    part[tid] = s;
    __syncthreads();
    for (int d = 1; d < 1024; d <<= 1) {
        int t = (tid >= d) ? part[tid - d] : 0;
        __syncthreads();
        if (tid >= d) part[tid] += t;
        __syncthreads();
    }
    int run = (tid > 0) ? part[tid - 1] : 0;
    for (int i = start; i < end; ++i) {
        offs[i] = run; cursor[i] = run;
        run += deg[i] - 1;
    }
    if (tid == 1023) offs[n] = run;
}

__global__ void k_fill(const int* __restrict__ src, const int* __restrict__ dst,
                       int* __restrict__ cursor, int* __restrict__ ss, int E) {
    int e = blockIdx.x * blockDim.x + threadIdx.x;
    if (e < E) {
        int p = atomicAdd(&cursor[dst[e]], 1);
        ss[p] = src[e];
    }
}

// ---------------- layer 0: aggregate 5-channel x, then GEMM to 128 ----------------

__global__ void k_agg5(const float* __restrict__ x, const int* __restrict__ ss,
                       const int* __restrict__ offs, const float* __restrict__ dinv,
                       float* __restrict__ out5, int n) {
    int node = blockIdx.x * blockDim.x + threadIdx.x;
    if (node >= n) return;
    float dn = dinv[node];
    float sw = dn * dn;
    const float* xr = x + (size_t)node * 5;
    float a0 = xr[0]*sw, a1 = xr[1]*sw, a2 = xr[2]*sw, a3 = xr[3]*sw, a4 = xr[4]*sw;
    int e1 = offs[node + 1];
    for (int e = offs[node]; e < e1; ++e) {
        int s = ss[e];
        float w = dinv[s] * dn;
        const float* xs = x + (size_t)s * 5;
        a0 += xs[0]*w; a1 += xs[1]*w; a2 += xs[2]*w; a3 += xs[3]*w; a4 += xs[4]*w;
    }
    float* o = out5 + (size_t)node * 5;
    o[0]=a0; o[1]=a1; o[2]=a2; o[3]=a3; o[4]=a4;
}

__global__ void k_gemm0(const float* __restrict__ out5, const float* __restrict__ W0,
                        const float* __restrict__ bias0, float* __restrict__ h, int n) {
    __shared__ float w[5 * 128];
    __shared__ float b[128];
    int tid = threadIdx.x;
    for (int i = tid; i < 640; i += blockDim.x) w[i] = W0[i];
    if (tid < 128) b[tid] = bias0[tid];
    __syncthreads();
    int idx = blockIdx.x * blockDim.x + tid;
    if (idx < n * 128) {
        int node = idx >> 7, c = idx & 127;
        const float* a = out5 + (size_t)node * 5;
        float r = b[c] + a[0]*w[c] + a[1]*w[128+c] + a[2]*w[256+c]
                       + a[3]*w[384+c] + a[4]*w[512+c];
        h[idx] = r;
    }
}

// ---------------- BatchNorm ----------------

// 256 blocks x 256 threads; per-block partial sum/sumsq per channel -> part[b*512 + ...]
__global__ void k_bnstats(const float* __restrict__ h, float* __restrict__ part, int n) {
    int tid = threadIdx.x;
    int c = tid & 127, half = tid >> 7;
    float s = 0.f, q = 0.f;
    for (int r = blockIdx.x * 2 + half; r < n; r += gridDim.x * 2) {
        float v = h[(size_t)r * 128 + c];
        s += v; q += v * v;
    }
    part[blockIdx.x * 512 + tid] = s;
    part[blockIdx.x * 512 + 256 + tid] = q;
}

__global__ void k_bnfinal(const float* __restrict__ part, int nblocks,
                          const float* __restrict__ gamma, const float* __restrict__ beta,
                          float* __restrict__ ab, int n) {
    int c = threadIdx.x;  // 128
    float s = 0.f, q = 0.f;
    for (int b = 0; b < nblocks; ++b) {
        const float* p = part + b * 512;
        s += p[c] + p[c + 128];
        q += p[256 + c] + p[256 + c + 128];
    }
    float mean = s / n;
    float var = q / n - mean * mean;
    float inv = rsqrtf(var + BN_EPS);
    float A = gamma[c] * inv;
    ab[c] = A;
    ab[128 + c] = beta[c] - mean * A;
}

__global__ void k_bnrelu(float* __restrict__ h, const float* __restrict__ ab, int n4) {
    int i = blockIdx.x * blockDim.x + threadIdx.x;
    if (i < n4) {
        float4 v = ((float4*)h)[i];
        int c4 = i & 31;
        float4 A = ((const float4*)ab)[c4];
        float4 B = ((const float4*)(ab + 128))[c4];
        v.x = fmaxf(0.f, v.x * A.x + B.x);
        v.y = fmaxf(0.f, v.y * A.y + B.y);
        v.z = fmaxf(0.f, v.z * A.z + B.z);
        v.w = fmaxf(0.f, v.w * A.w + B.w);
        ((float4*)h)[i] = v;
    }
}

// ---------------- 128x128 GEMM (fp32, LDS-tiled) ----------------

__global__ __launch_bounds__(256) void k_gemm128(const float* __restrict__ A,
                                                 const float* __restrict__ W,
                                                 float* __restrict__ C, int n) {
    __shared__ float As[128 * 128];  // 64 KiB, XOR-swizzled columns
    __shared__ float Ws[128 * 128];  // 64 KiB
    int tid = threadIdx.x;
    const float4* W4 = (const float4*)W;
    for (int i = tid; i < 4096; i += 256) ((float4*)Ws)[i] = W4[i];
    int row0 = blockIdx.x * 128;
    int nrows = min(128, n - row0);
    const float4* A4 = (const float4*)(A + (size_t)row0 * 128);
    for (int i = tid; i < nrows * 32; i += 256) {
        int r = i >> 5, k4 = i & 31;
        int sw = ((r >> 2) & 7) << 2;
        int col = (k4 * 4) ^ sw;
        *(float4*)&As[r * 128 + col] = A4[i];
    }
    __syncthreads();
    int rm = tid >> 3, cn = tid & 7;
    int r = rm * 4, c = cn * 16;
    float acc[4][16];
    #pragma unroll
    for (int i = 0; i < 4; ++i)
        #pragma unroll
        for (int j = 0; j < 16; ++j) acc[i][j] = 0.f;
    for (int k = 0; k < 128; k += 4) {
        float4 a[4];
        int sw = (rm & 7) << 2;
        #pragma unroll
        for (int rr = 0; rr < 4; ++rr)
            a[rr] = *(const float4*)&As[(r + rr) * 128 + (k ^ sw)];
        #pragma unroll
        for (int kk = 0; kk < 4; ++kk) {
            float4 w0 = *(const float4*)&Ws[(k + kk) * 128 + c];
            float4 w1 = *(const float4*)&Ws[(k + kk) * 128 + c + 4];
            float4 w2 = *(const float4*)&Ws[(k + kk) * 128 + c + 8];
            float4 w3 = *(const float4*)&Ws[(k + kk) * 128 + c + 12];
            #pragma unroll
            for (int rr = 0; rr < 4; ++rr) {
                float av = ((const float*)&a[rr])[kk];
                acc[rr][0] += av * w0.x; acc[rr][1] += av * w0.y;
                acc[rr][2] += av * w0.z; acc[rr][3] += av * w0.w;
                acc[rr][4] += av * w1.x; acc[rr][5] += av * w1.y;
                acc[rr][6] += av * w1.z; acc[rr][7] += av * w1.w;
                acc[rr][8] += av * w2.x; acc[rr][9] += av * w2.y;
                acc[rr][10] += av * w2.z; acc[rr][11] += av * w2.w;
                acc[rr][12] += av * w3.x; acc[rr][13] += av * w3.y;
                acc[rr][14] += av * w3.z; acc[rr][15] += av * w3.w;
            }
        }
    }
    #pragma unroll
    for (int rr = 0; rr < 4; ++rr) {
        int rrow = row0 + r + rr;
        if (rrow < n) {
            float4* outp = (float4*)&C[(size_t)rrow * 128 + c];
            outp[0] = make_float4(acc[rr][0], acc[rr][1], acc[rr][2], acc[rr][3]);
            outp[1] = make_float4(acc[rr][4], acc[rr][5], acc[rr][6], acc[rr][7]);
            outp[2] = make_float4(acc[rr][8], acc[rr][9], acc[rr][10], acc[rr][11]);
            outp[3] = make_float4(acc[rr][12], acc[rr][13], acc[rr][14], acc[rr][15]);
        }
    }
}

// ---------------- 128-channel aggregation: one wave per node ----------------

__global__ void k_agg128(const float* __restrict__ hin, const int* __restrict__ ss,
                         const int* __restrict__ offs, const float* __restrict__ dinv,
                         const float* __restrict__ bias, float* __restrict__ hout, int n) {
    int wid = threadIdx.x >> 6, lane = threadIdx.x & 63;
    int node = blockIdx.x * (blockDim.x >> 6) + wid;
    if (node >= n) return;
    float dn = dinv[node];
    const float2* h2 = (const float2*)hin;
    float sw = dn * dn;
    float2 hv = h2[(size_t)node * 64 + lane];
    float2 acc; acc.x = hv.x * sw; acc.y = hv.y * sw;
    int e1 = offs[node + 1];
    for (int e = offs[node]; e < e1; ++e) {
        int s = ss[e];
        float w = dinv[s] * dn;
        float2 v = h2[(size_t)s * 64 + lane];
        acc.x += v.x * w; acc.y += v.y * w;
    }
    float2 b = ((const float2*)bias)[lane];
    acc.x += b.x; acc.y += b.y;
    ((float2*)hout)[(size_t)node * 64 + lane] = acc;
}

// ---------------- pooling + head ----------------

__global__ void k_zero_pool(float* __restrict__ gsum, int* __restrict__ gcnt) {
    int i = blockIdx.x * blockDim.x + threadIdx.x;
    if (i < 64 * 128) gsum[i] = 0.f;
    if (i < 64) gcnt[i] = 0;
}

__global__ void k_cnt(const int* __restrict__ batch, int* __restrict__ gcnt, int n) {
    int i = blockIdx.x * blockDim.x + threadIdx.x;
    if (i < n) atomicAdd(&gcnt[batch[i]], 1);
}

// applies layer-3 BN+ReLU while pooling (batch is sorted -> flush on graph change)
__global__ void k_pool(const float* __restrict__ h, const int* __restrict__ batch,
                       const float* __restrict__ ab, float* __restrict__ gsum,
                       int n, int rows_per_block) {
    int tid = threadIdx.x; int c = tid & 127; int half = tid >> 7;
    int r0 = blockIdx.x * rows_per_block;
    int r1 = min(r0 + rows_per_block, n);
    int half_len = rows_per_block >> 1;
    int rs = r0 + half * half_len;
    int re = min(rs + half_len, r1);
    float A = ab[c], B = ab[128 + c];
    float acc = 0.f; int cur = -1;
    for (int r = rs; r < re; ++r) {
        int g = batch[r];
        if (g != cur) {
            if (cur >= 0) atomicAdd(&gsum[cur * 128 + c], acc);
            acc = 0.f; cur = g;
        }
        float v = h[(size_t)r * 128 + c];
        acc += fmaxf(0.f, v * A + B);
    }
    if (cur >= 0) atomicAdd(&gsum[cur * 128 + c], acc);
}

__global__ void k_final(const float* __restrict__ gsum, const int* __restrict__ gcnt,
                        const float* __restrict__ embW, const float* __restrict__ embb,
                        float* __restrict__ out) {
    __shared__ float row[128];
    int g = blockIdx.x, j = threadIdx.x;  // 64 threads
    float invc = 1.f / fmaxf((float)gcnt[g], 1.f);
    for (int i = j; i < 128; i += 64) row[i] = gsum[g * 128 + i] * invc;
    __syncthreads();
    float acc = embb[j];
    for (int cdx = 0; cdx < 128; ++cdx) acc += row[cdx] * embW[cdx * 64 + j];
    out[g * 64 + j] = acc;
}

// ---------------- launch ----------------

extern "C" void kernel_launch(void* const* d_in, const int* in_sizes, int n_in,
                              void* d_out, int out_size, void* d_ws, size_t ws_size,
                              hipStream_t stream) {
    const float* x     = (const float*)d_in[0];
    const float* W0    = (const float*)d_in[1];
    const float* Wh    = (const float*)d_in[2];
    const float* bias  = (const float*)d_in[3];
    const float* gamma = (const float*)d_in[4];
    const float* beta  = (const float*)d_in[5];
    const float* embW  = (const float*)d_in[6];
    const float* embb  = (const float*)d_in[7];
    const int*   ei    = (const int*)d_in[8];
    const int*   batch = (const int*)d_in[9];
    int N = in_sizes[9];
    int E = in_sizes[8] / 2;
    const int* src = ei;
    const int* dst = ei + E;

    char* w = (char*)d_ws;
    size_t off = 0;
    auto carve = [&](size_t bytes) {
        char* p = w + off;
        off = (off + bytes + 255) & ~(size_t)255;
        return (void*)p;
    };
    int*   deg    = (int*)carve((size_t)N * 4);
    float* dinv   = (float*)carve((size_t)N * 4);
    int*   offs   = (int*)carve((size_t)(N + 1) * 4);
    int*   cursor = (int*)carve((size_t)N * 4);
    int*   ss     = (int*)carve((size_t)E * 4);
    float* out5   = (float*)carve((size_t)N * 5 * 4);
    float* hA     = (float*)carve((size_t)N * 128 * 4);
    float* hB     = (float*)carve((size_t)N * 128 * 4);
    float* part   = (float*)carve(256 * 512 * 4);
    float* ab     = (float*)carve(256 * 4);
    float* gsum   = (float*)carve(64 * 128 * 4);
    int*   gcnt   = (int*)carve(64 * 4);
    (void)ws_size; (void)n_in; (void)out_size;

    int nb = (N + 255) / 256;
    int eb = (E + 255) / 256;
    int gb = (N + 127) / 128;
    int ab4 = (N + 3) / 4;

    k_init_deg<<<nb, 256, 0, stream>>>(deg, N);
    k_deg<<<eb, 256, 0, stream>>>(dst, deg, E);
    k_dinv<<<nb, 256, 0, stream>>>(deg, dinv, N);
    k_scan<<<1, 1024, 0, stream>>>(deg, offs, cursor, N);
    k_fill<<<eb, 256, 0, stream>>>(src, dst, cursor, ss, E);

    // layer 0: aggregate x (5ch) then GEMM to 128 (+bias0)
    k_agg5<<<nb, 256, 0, stream>>>(x, ss, offs, dinv, out5, N);
    k_gemm0<<<(N * 128 + 255) / 256, 256, 0, stream>>>(out5, W0, bias, hA, N);
    k_bnstats<<<256, 256, 0, stream>>>(hA, part, N);
    k_bnfinal<<<1, 128, 0, stream>>>(part, 256, gamma, beta, ab, N);
    k_bnrelu<<<(N * 32 + 255) / 256, 256, 0, stream>>>(hA, ab, N * 32);

    // layer 1
    k_gemm128<<<gb, 256, 0, stream>>>(hA, Wh, hB, N);
    k_agg128<<<ab4, 256, 0, stream>>>(hB, ss, offs, dinv, bias + 128, hA, N);
    k_bnstats<<<256, 256, 0, stream>>>(hA, part, N);
    k_bnfinal<<<1, 128, 0, stream>>>(part, 256, gamma + 128, beta + 128, ab, N);
    k_bnrelu<<<(N * 32 + 255) / 256, 256, 0, stream>>>(hA, ab, N * 32);

    // layer 2
    k_gemm128<<<gb, 256, 0, stream>>>(hA, Wh + 128 * 128, hB, N);
    k_agg128<<<ab4, 256, 0, stream>>>(hB, ss, offs, dinv, bias + 256, hA, N);
    k_bnstats<<<256, 256, 0, stream>>>(hA, part, N);
    k_bnfinal<<<1, 128, 0, stream>>>(part, 256, gamma + 256, beta + 256, ab, N);

    // pool (fuses layer-2 BN+ReLU) + head
    k_zero_pool<<<(64 * 128 + 255) / 256, 256, 0, stream>>>(gsum, gcnt);
    k_cnt<<<nb, 256, 0, stream>>>(batch, gcnt, N);
    int rpb = 512;
    k_pool<<<(N + rpb - 1) / rpb, 256, 0, stream>>>(hA, batch, ab, gsum, N, rpb);
    k_final<<<64, 64, 0, stream>>>(gsum, gcnt, embW, embb, (float*)d_out);
}

// Round 2
// 2102.697 us; speedup vs baseline: 1.2541x; 1.2541x over previous
//
#include <hip/hip_runtime.h>

constexpr float BN_EPS = 1e-5f;

// ---------------- graph preprocessing ----------------

__global__ void k_init_deg(int* __restrict__ deg, int n) {
    int i = blockIdx.x * blockDim.x + threadIdx.x;
    if (i < n) deg[i] = 1;  // self loop
}

__global__ void k_deg(const int* __restrict__ dst, int* __restrict__ deg, int E) {
    int e = blockIdx.x * blockDim.x + threadIdx.x;
    if (e < E) atomicAdd(&deg[dst[e]], 1);
}

__global__ void k_dinv(const int* __restrict__ deg, float* __restrict__ dinv, int n) {
    int i = blockIdx.x * blockDim.x + threadIdx.x;
    if (i < n) dinv[i] = rsqrtf((float)deg[i]);
}

// exclusive scan of in-degree (deg-1) over n nodes; single block of 1024
__global__ void k_scan(const int* __restrict__ deg, int* __restrict__ offs,
                       int* __restrict__ cursor, int n) {
    __shared__ int part[1024];
    int tid = threadIdx.x;
    int chunk = (n + 1023) >> 10;
    int start = tid * chunk;
    int end = min(start + chunk, n);
    int s = 0;
    for (int i = start; i < end; ++i) s += deg[i] - 1;
    part[tid] = s;
    __syncthreads();
    for (int d = 1; d < 1024; d <<= 1) {
        int t = (tid >= d) ? part[tid - d] : 0;
        __syncthreads();
        if (tid >= d) part[tid] += t;
        __syncthreads();
    }
    int run = (tid > 0) ? part[tid - 1] : 0;
    for (int i = start; i < end; ++i) {
        offs[i] = run; cursor[i] = run;
        run += deg[i] - 1;
    }
    if (tid == 1023) offs[n] = run;
}

__global__ void k_fill(const int* __restrict__ src, const int* __restrict__ dst,
                       int* __restrict__ cursor, int* __restrict__ ss, int E) {
    int e = blockIdx.x * blockDim.x + threadIdx.x;
    if (e < E) {
        int p = atomicAdd(&cursor[dst[e]], 1);
        ss[p] = src[e];
    }
}

// ---------------- layer 0: aggregate 5-channel x, then GEMM to 128 ----------------

__global__ void k_agg5(const float* __restrict__ x, const int* __restrict__ ss,
                       const int* __restrict__ offs, const float* __restrict__ dinv,
                       float* __restrict__ out5, int n) {
    int node = blockIdx.x * blockDim.x + threadIdx.x;
    if (node >= n) return;
    float dn = dinv[node];
    float sw = dn * dn;
    const float* xr = x + (size_t)node * 5;
    float a0 = xr[0]*sw, a1 = xr[1]*sw, a2 = xr[2]*sw, a3 = xr[3]*sw, a4 = xr[4]*sw;
    int e1 = offs[node + 1];
    for (int e = offs[node]; e < e1; ++e) {
        int s = ss[e];
        float w = dinv[s] * dn;
        const float* xs = x + (size_t)s * 5;
        a0 += xs[0]*w; a1 += xs[1]*w; a2 += xs[2]*w; a3 += xs[3]*w; a4 += xs[4]*w;
    }
    float* o = out5 + (size_t)node * 5;
    o[0]=a0; o[1]=a1; o[2]=a2; o[3]=a3; o[4]=a4;
}

__global__ void k_gemm0(const float* __restrict__ out5, const float* __restrict__ W0,
                        const float* __restrict__ bias0, float* __restrict__ h, int n) {
    __shared__ float w[5 * 128];
    __shared__ float b[128];
    int tid = threadIdx.x;
    for (int i = tid; i < 640; i += blockDim.x) w[i] = W0[i];
    if (tid < 128) b[tid] = bias0[tid];
    __syncthreads();
    int idx = blockIdx.x * blockDim.x + tid;
    if (idx < n * 128) {
        int node = idx >> 7, c = idx & 127;
        const float* a = out5 + (size_t)node * 5;
        float r = b[c] + a[0]*w[c] + a[1]*w[128+c] + a[2]*w[256+c]
                       + a[3]*w[384+c] + a[4]*w[512+c];
        h[idx] = r;
    }
}

// ---------------- BatchNorm ----------------

// 256 blocks x 256 threads; per-block partial sum/sumsq per channel -> part[b*512 + ...]
__global__ void k_bnstats(const float* __restrict__ h, float* __restrict__ part, int n) {
    int tid = threadIdx.x;
    int c = tid & 127, half = tid >> 7;
    float s = 0.f, q = 0.f;
    for (int r = blockIdx.x * 2 + half; r < n; r += gridDim.x * 2) {
        float v = h[(size_t)r * 128 + c];
        s += v; q += v * v;
    }
    part[blockIdx.x * 512 + tid] = s;
    part[blockIdx.x * 512 + 256 + tid] = q;
}

__global__ void k_bnfinal(const float* __restrict__ part, int nblocks,
                          const float* __restrict__ gamma, const float* __restrict__ beta,
                          float* __restrict__ ab, int n) {
    int c = threadIdx.x;  // 128
    float s = 0.f, q = 0.f;
    for (int b = 0; b < nblocks; ++b) {
        const float* p = part + b * 512;
        s += p[c] + p[c + 128];
        q += p[256 + c] + p[256 + c + 128];
    }
    float mean = s / n;
    float var = q / n - mean * mean;
    float inv = rsqrtf(var + BN_EPS);
    float A = gamma[c] * inv;
    ab[c] = A;
    ab[128 + c] = beta[c] - mean * A;
}

// ---------------- 128x128 GEMM (fp32, LDS-tiled), BN+ReLU fused on A-load ----------------

__global__ __launch_bounds__(256) void k_gemm128(const float* __restrict__ A,
                                                 const float* __restrict__ W,
                                                 const float* __restrict__ ab,
                                                 float* __restrict__ C, int n) {
    __shared__ float As[128 * 128];  // 64 KiB, XOR-swizzled columns
    __shared__ float Ws[128 * 128];  // 64 KiB
    int tid = threadIdx.x;
    const float4* W4 = (const float4*)W;
    for (int i = tid; i < 4096; i += 256) ((float4*)Ws)[i] = W4[i];
    int row0 = blockIdx.x * 128;
    int nrows = min(128, n - row0);
    const float4* A4 = (const float4*)(A + (size_t)row0 * 128);
    for (int i = tid; i < nrows * 32; i += 256) {
        int r = i >> 5, k4 = i & 31;
        float4 v = A4[i];
        float4 Aq = ((const float4*)ab)[k4];
        float4 Bq = ((const float4*)(ab + 128))[k4];
        v.x = fmaxf(0.f, v.x * Aq.x + Bq.x);
        v.y = fmaxf(0.f, v.y * Aq.y + Bq.y);
        v.z = fmaxf(0.f, v.z * Aq.z + Bq.z);
        v.w = fmaxf(0.f, v.w * Aq.w + Bq.w);
        int sw = ((r >> 2) & 7) << 2;
        int col = (k4 * 4) ^ sw;
        *(float4*)&As[r * 128 + col] = v;
    }
    __syncthreads();
    int rm = tid >> 3, cn = tid & 7;
    int r = rm * 4, c = cn * 16;
    float acc[4][16];
    #pragma unroll
    for (int i = 0; i < 4; ++i)
        #pragma unroll
        for (int j = 0; j < 16; ++j) acc[i][j] = 0.f;
    for (int k = 0; k < 128; k += 4) {
        float4 a[4];
        int sw = (rm & 7) << 2;
        #pragma unroll
        for (int rr = 0; rr < 4; ++rr)
            a[rr] = *(const float4*)&As[(r + rr) * 128 + (k ^ sw)];
        #pragma unroll
        for (int kk = 0; kk < 4; ++kk) {
            float4 w0 = *(const float4*)&Ws[(k + kk) * 128 + c];
            float4 w1 = *(const float4*)&Ws[(k + kk) * 128 + c + 4];
            float4 w2 = *(const float4*)&Ws[(k + kk) * 128 + c + 8];
            float4 w3 = *(const float4*)&Ws[(k + kk) * 128 + c + 12];
            #pragma unroll
            for (int rr = 0; rr < 4; ++rr) {
                float av = ((const float*)&a[rr])[kk];
                acc[rr][0] += av * w0.x; acc[rr][1] += av * w0.y;
                acc[rr][2] += av * w0.z; acc[rr][3] += av * w0.w;
                acc[rr][4] += av * w1.x; acc[rr][5] += av * w1.y;
                acc[rr][6] += av * w1.z; acc[rr][7] += av * w1.w;
                acc[rr][8] += av * w2.x; acc[rr][9] += av * w2.y;
                acc[rr][10] += av * w2.z; acc[rr][11] += av * w2.w;
                acc[rr][12] += av * w3.x; acc[rr][13] += av * w3.y;
                acc[rr][14] += av * w3.z; acc[rr][15] += av * w3.w;
            }
        }
    }
    #pragma unroll
    for (int rr = 0; rr < 4; ++rr) {
        int rrow = row0 + r + rr;
        if (rrow < n) {
            float4* outp = (float4*)&C[(size_t)rrow * 128 + c];
            outp[0] = make_float4(acc[rr][0], acc[rr][1], acc[rr][2], acc[rr][3]);
            outp[1] = make_float4(acc[rr][4], acc[rr][5], acc[rr][6], acc[rr][7]);
            outp[2] = make_float4(acc[rr][8], acc[rr][9], acc[rr][10], acc[rr][11]);
            outp[3] = make_float4(acc[rr][12], acc[rr][13], acc[rr][14], acc[rr][15]);
        }
    }
}

// ---------------- 128-channel aggregation: one wave per node ----------------

__global__ void k_agg128(const float* __restrict__ hin, const int* __restrict__ ss,
                         const int* __restrict__ offs, const float* __restrict__ dinv,
                         const float* __restrict__ bias, float* __restrict__ hout, int n) {
    int wid = threadIdx.x >> 6, lane = threadIdx.x & 63;
    int node = blockIdx.x * (blockDim.x >> 6) + wid;
    if (node >= n) return;
    float dn = dinv[node];
    const float2* h2 = (const float2*)hin;
    float sw = dn * dn;
    float2 hv = h2[(size_t)node * 64 + lane];
    float2 acc; acc.x = hv.x * sw; acc.y = hv.y * sw;
    int e1 = offs[node + 1];
    for (int e = offs[node]; e < e1; ++e) {
        int s = ss[e];
        float w = dinv[s] * dn;
        float2 v = h2[(size_t)s * 64 + lane];
        acc.x += v.x * w; acc.y += v.y * w;
    }
    float2 b = ((const float2*)bias)[lane];
    acc.x += b.x; acc.y += b.y;
    ((float2*)hout)[(size_t)node * 64 + lane] = acc;
}

// ---------------- pooling + head ----------------

__global__ void k_zero_pool(float* __restrict__ gsum) {
    int i = blockIdx.x * blockDim.x + threadIdx.x;
    if (i < 64 * 128) gsum[i] = 0.f;
}

// batch is sorted: per-graph counts via 65 binary searches, no atomics
__global__ void k_bounds(const int* __restrict__ batch, int* __restrict__ gcnt, int n) {
    __shared__ int b[65];
    int g = threadIdx.x;  // 128 threads, only 0..64 search
    if (g <= 64) {
        int lo = 0, hi = n;
        while (lo < hi) {
            int mid = (lo + hi) >> 1;
            if (batch[mid] < g) lo = mid + 1; else hi = mid;
        }
        b[g] = lo;
    }
    __syncthreads();
    if (g < 64) gcnt[g] = b[g + 1] - b[g];
}

// applies layer-3 BN+ReLU while pooling (batch is sorted -> flush on graph change)
__global__ void k_pool(const float* __restrict__ h, const int* __restrict__ batch,
                       const float* __restrict__ ab, float* __restrict__ gsum,
                       int n, int rows_per_block) {
    int tid = threadIdx.x; int c = tid & 127; int half = tid >> 7;
    int r0 = blockIdx.x * rows_per_block;
    int r1 = min(r0 + rows_per_block, n);
    int half_len = rows_per_block >> 1;
    int rs = r0 + half * half_len;
    int re = min(rs + half_len, r1);
    float A = ab[c], B = ab[128 + c];
    float acc = 0.f; int cur = -1;
    for (int r = rs; r < re; ++r) {
        int g = batch[r];
        if (g != cur) {
            if (cur >= 0) atomicAdd(&gsum[cur * 128 + c], acc);
            acc = 0.f; cur = g;
        }
        float v = h[(size_t)r * 128 + c];
        acc += fmaxf(0.f, v * A + B);
    }
    if (cur >= 0) atomicAdd(&gsum[cur * 128 + c], acc);
}

__global__ void k_final(const float* __restrict__ gsum, const int* __restrict__ gcnt,
                        const float* __restrict__ embW, const float* __restrict__ embb,
                        float* __restrict__ out) {
    __shared__ float row[128];
    int g = blockIdx.x, j = threadIdx.x;  // 64 threads
    float invc = 1.f / fmaxf((float)gcnt[g], 1.f);
    for (int i = j; i < 128; i += 64) row[i] = gsum[g * 128 + i] * invc;
    __syncthreads();
    float acc = embb[j];
    for (int cdx = 0; cdx < 128; ++cdx) acc += row[cdx] * embW[cdx * 64 + j];
    out[g * 64 + j] = acc;
}

// ---------------- launch ----------------

extern "C" void kernel_launch(void* const* d_in, const int* in_sizes, int n_in,
                              void* d_out, int out_size, void* d_ws, size_t ws_size,
                              hipStream_t stream) {
    const float* x     = (const float*)d_in[0];
    const float* W0    = (const float*)d_in[1];
    const float* Wh    = (const float*)d_in[2];
    const float* bias  = (const float*)d_in[3];
    const float* gamma = (const float*)d_in[4];
    const float* beta  = (const float*)d_in[5];
    const float* embW  = (const float*)d_in[6];
    const float* embb  = (const float*)d_in[7];
    const int*   ei    = (const int*)d_in[8];
    const int*   batch = (const int*)d_in[9];
    int N = in_sizes[9];
    int E = in_sizes[8] / 2;
    const int* src = ei;
    const int* dst = ei + E;

    char* w = (char*)d_ws;
    size_t off = 0;
    auto carve = [&](size_t bytes) {
        char* p = w + off;
        off = (off + bytes + 255) & ~(size_t)255;
        return (void*)p;
    };
    int*   deg    = (int*)carve((size_t)N * 4);
    float* dinv   = (float*)carve((size_t)N * 4);
    int*   offs   = (int*)carve((size_t)(N + 1) * 4);
    int*   cursor = (int*)carve((size_t)N * 4);
    int*   ss     = (int*)carve((size_t)E * 4);
    float* out5   = (float*)carve((size_t)N * 5 * 4);
    float* hA     = (float*)carve((size_t)N * 128 * 4);
    float* hB     = (float*)carve((size_t)N * 128 * 4);
    float* part   = (float*)carve(256 * 512 * 4);
    float* ab     = (float*)carve(256 * 4);
    float* gsum   = (float*)carve(64 * 128 * 4);
    int*   gcnt   = (int*)carve(64 * 4);
    (void)ws_size; (void)n_in; (void)out_size;

    int nb = (N + 255) / 256;
    int eb = (E + 255) / 256;
    int gb = (N + 127) / 128;
    int ab4 = (N + 3) / 4;

    k_init_deg<<<nb, 256, 0, stream>>>(deg, N);
    k_deg<<<eb, 256, 0, stream>>>(dst, deg, E);
    k_dinv<<<nb, 256, 0, stream>>>(deg, dinv, N);
    k_scan<<<1, 1024, 0, stream>>>(deg, offs, cursor, N);
    k_fill<<<eb, 256, 0, stream>>>(src, dst, cursor, ss, E);

    // layer 0: aggregate x (5ch) then GEMM to 128 (+bias0)
    k_agg5<<<nb, 256, 0, stream>>>(x, ss, offs, dinv, out5, N);
    k_gemm0<<<(N * 128 + 255) / 256, 256, 0, stream>>>(out5, W0, bias, hA, N);
    k_bnstats<<<256, 256, 0, stream>>>(hA, part, N);
    k_bnfinal<<<1, 128, 0, stream>>>(part, 256, gamma, beta, ab, N);

    // layer 1 (BN0+ReLU fused into A-load)
    k_gemm128<<<gb, 256, 0, stream>>>(hA, Wh, ab, hB, N);
    k_agg128<<<ab4, 256, 0, stream>>>(hB, ss, offs, dinv, bias + 128, hA, N);
    k_bnstats<<<256, 256, 0, stream>>>(hA, part, N);
    k_bnfinal<<<1, 128, 0, stream>>>(part, 256, gamma + 128, beta + 128, ab, N);

    // layer 2 (BN1+ReLU fused into A-load)
    k_gemm128<<<gb, 256, 0, stream>>>(hA, Wh + 128 * 128, ab, hB, N);
    k_agg128<<<ab4, 256, 0, stream>>>(hB, ss, offs, dinv, bias + 256, hA, N);
    k_bnstats<<<256, 256, 0, stream>>>(hA, part, N);
    k_bnfinal<<<1, 128, 0, stream>>>(part, 256, gamma + 256, beta + 256, ab, N);

    // pool (fuses layer-2 BN+ReLU) + head
    k_zero_pool<<<(64 * 128 + 255) / 256, 256, 0, stream>>>(gsum);
    k_bounds<<<1, 128, 0, stream>>>(batch, gcnt, N);
    int rpb = 512;
    k_pool<<<(N + rpb - 1) / rpb, 256, 0, stream>>>(hA, batch, ab, gsum, N, rpb);
    k_final<<<64, 64, 0, stream>>>(gsum, gcnt, embW, embb, (float*)d_out);
}

// Round 3
// 1767.669 us; speedup vs baseline: 1.4918x; 1.1895x over previous
//
#include <hip/hip_runtime.h>
#include <hip/hip_bf16.h>

constexpr float BN_EPS = 1e-5f;

// ---------------- graph preprocessing ----------------

__global__ void k_init_deg(int* __restrict__ deg, int n) {
    int i = blockIdx.x * blockDim.x + threadIdx.x;
    if (i < n) deg[i] = 1;  // self loop
}

__global__ void k_deg(const int* __restrict__ dst, int* __restrict__ deg, int E) {
    int e = blockIdx.x * blockDim.x + threadIdx.x;
    if (e < E) atomicAdd(&deg[dst[e]], 1);
}

// dinv + pre-scaled x' = x * dinv[row]
__global__ void k_dinv(const int* __restrict__ deg, const float* __restrict__ x,
                       float* __restrict__ dinv, float* __restrict__ xs, int n) {
    int i = blockIdx.x * blockDim.x + threadIdx.x;
    if (i >= n) return;
    float d = rsqrtf((float)deg[i]);
    dinv[i] = d;
    const float* xr = x + (size_t)i * 5;
    float* o = xs + (size_t)i * 5;
    #pragma unroll
    for (int j = 0; j < 5; ++j) o[j] = xr[j] * d;
}

// ---- parallel exclusive scan of (deg-1): 65536 threads, ct elems each ----

__global__ void k_scan1(const int* __restrict__ deg, int* __restrict__ tsum,
                        int* __restrict__ bsum, int n, int ct) {
    int t = threadIdx.x, b = blockIdx.x;
    int i = b * 256 + t;
    int s0 = i * ct, s1 = min(n, s0 + ct);
    int s = 0;
    for (int k = s0; k < s1; ++k) s += deg[k] - 1;
    tsum[i] = s;
    __shared__ int red[256];
    red[t] = s; __syncthreads();
    for (int d = 128; d > 0; d >>= 1) {
        if (t < d) red[t] += red[t + d];
        __syncthreads();
    }
    if (t == 0) bsum[b] = red[0];
}

__global__ void k_scan2(const int* __restrict__ bsum, int* __restrict__ bbase) {
    int t = threadIdx.x;  // 256
    __shared__ int sh[256];
    int v = bsum[t];
    sh[t] = v; __syncthreads();
    for (int d = 1; d < 256; d <<= 1) {
        int u = (t >= d) ? sh[t - d] : 0;
        __syncthreads();
        sh[t] += u;
        __syncthreads();
    }
    bbase[t] = sh[t] - v;  // exclusive
    if (t == 255) bbase[256] = sh[255];
}

__global__ void k_scan3(const int* __restrict__ deg, const int* __restrict__ tsum,
                        const int* __restrict__ bbase, int* __restrict__ offs,
                        int* __restrict__ cursor, int n, int ct) {
    int t = threadIdx.x, b = blockIdx.x;
    __shared__ int sh[256];
    int v = tsum[b * 256 + t];
    sh[t] = v; __syncthreads();
    for (int d = 1; d < 256; d <<= 1) {
        int u = (t >= d) ? sh[t - d] : 0;
        __syncthreads();
        sh[t] += u;
        __syncthreads();
    }
    int run = bbase[b] + sh[t] - v;
    int i = b * 256 + t;
    int s0 = i * ct, s1 = min(n, s0 + ct);
    for (int k = s0; k < s1; ++k) {
        offs[k] = run; cursor[k] = run;
        run += deg[k] - 1;
    }
    if (i == 65535) offs[n] = bbase[256];
}

__global__ void k_fill(const int* __restrict__ src, const int* __restrict__ dst,
                       int* __restrict__ cursor, int* __restrict__ ss, int E) {
    int e = blockIdx.x * blockDim.x + threadIdx.x;
    if (e < E) {
        int p = atomicAdd(&cursor[dst[e]], 1);
        ss[p] = src[e];
    }
}

// ---------------- layer 0: aggregate pre-scaled x' (5ch), then GEMM to 128 ----------------

__global__ void k_agg5(const float* __restrict__ xs, const int* __restrict__ ss,
                       const int* __restrict__ offs, const float* __restrict__ dinv,
                       float* __restrict__ out5, int n) {
    int node = blockIdx.x * blockDim.x + threadIdx.x;
    if (node >= n) return;
    const float* xr = xs + (size_t)node * 5;
    float a0 = xr[0], a1 = xr[1], a2 = xr[2], a3 = xr[3], a4 = xr[4];
    int e1 = offs[node + 1];
    for (int e = offs[node]; e < e1; ++e) {
        int s = ss[e];
        const float* p = xs + (size_t)s * 5;
        a0 += p[0]; a1 += p[1]; a2 += p[2]; a3 += p[3]; a4 += p[4];
    }
    float dn = dinv[node];
    float* o = out5 + (size_t)node * 5;
    o[0] = a0 * dn; o[1] = a1 * dn; o[2] = a2 * dn; o[3] = a3 * dn; o[4] = a4 * dn;
}

__global__ void k_gemm0(const float* __restrict__ out5, const float* __restrict__ W0,
                        const float* __restrict__ bias0, float* __restrict__ h, int n) {
    __shared__ float w[5 * 128];
    __shared__ float b[128];
    int tid = threadIdx.x;
    for (int i = tid; i < 640; i += blockDim.x) w[i] = W0[i];
    if (tid < 128) b[tid] = bias0[tid];
    __syncthreads();
    int idx = blockIdx.x * blockDim.x + tid;
    if (idx < n * 128) {
        int node = idx >> 7, c = idx & 127;
        const float* a = out5 + (size_t)node * 5;
        float r = b[c] + a[0]*w[c] + a[1]*w[128+c] + a[2]*w[256+c]
                       + a[3]*w[384+c] + a[4]*w[512+c];
        h[idx] = r;
    }
}

// ---------------- BatchNorm ----------------

__global__ void k_bnstats(const float* __restrict__ h, float* __restrict__ part, int n) {
    int tid = threadIdx.x;
    int c = tid & 127, half = tid >> 7;
    float s = 0.f, q = 0.f;
    for (int r = blockIdx.x * 2 + half; r < n; r += gridDim.x * 2) {
        float v = h[(size_t)r * 128 + c];
        s += v; q += v * v;
    }
    part[blockIdx.x * 512 + tid] = s;
    part[blockIdx.x * 512 + 256 + tid] = q;
}

__global__ void k_bnfinal(const float* __restrict__ part, int nblocks,
                          const float* __restrict__ gamma, const float* __restrict__ beta,
                          float* __restrict__ ab, int n) {
    int c = threadIdx.x;  // 128
    float s = 0.f, q = 0.f;
    for (int b = 0; b < nblocks; ++b) {
        const float* p = part + b * 512;
        s += p[c] + p[c + 128];
        q += p[256 + c] + p[256 + c + 128];
    }
    float mean = s / n;
    float var = q / n - mean * mean;
    float inv = rsqrtf(var + BN_EPS);
    float A = gamma[c] * inv;
    ab[c] = A;
    ab[128 + c] = beta[c] - mean * A;
}

// ------- 128x128 GEMM (fp32, LDS-tiled), BN+ReLU fused on A-load,
//         epilogue: scale row by dinv[row], emit bf16 -------

__global__ __launch_bounds__(256) void k_gemm128(const float* __restrict__ A,
                                                 const float* __restrict__ W,
                                                 const float* __restrict__ ab,
                                                 const float* __restrict__ dinv,
                                                 __hip_bfloat16* __restrict__ C, int n) {
    __shared__ float As[128 * 128];  // 64 KiB, XOR-swizzled columns
    __shared__ float Ws[128 * 128];  // 64 KiB
    int tid = threadIdx.x;
    const float4* W4 = (const float4*)W;
    for (int i = tid; i < 4096; i += 256) ((float4*)Ws)[i] = W4[i];
    int row0 = blockIdx.x * 128;
    int nrows = min(128, n - row0);
    const float4* A4 = (const float4*)(A + (size_t)row0 * 128);
    for (int i = tid; i < nrows * 32; i += 256) {
        int r = i >> 5, k4 = i & 31;
        float4 v = A4[i];
        float4 Aq = ((const float4*)ab)[k4];
        float4 Bq = ((const float4*)(ab + 128))[k4];
        v.x = fmaxf(0.f, v.x * Aq.x + Bq.x);
        v.y = fmaxf(0.f, v.y * Aq.y + Bq.y);
        v.z = fmaxf(0.f, v.z * Aq.z + Bq.z);
        v.w = fmaxf(0.f, v.w * Aq.w + Bq.w);
        int sw = ((r >> 2) & 7) << 2;
        int col = (k4 * 4) ^ sw;
        *(float4*)&As[r * 128 + col] = v;
    }
    __syncthreads();
    int rm = tid >> 3, cn = tid & 7;
    int r = rm * 4, c = cn * 16;
    float acc[4][16];
    #pragma unroll
    for (int i = 0; i < 4; ++i)
        #pragma unroll
        for (int j = 0; j < 16; ++j) acc[i][j] = 0.f;
    for (int k = 0; k < 128; k += 4) {
        float4 a[4];
        int sw = (rm & 7) << 2;
        #pragma unroll
        for (int rr = 0; rr < 4; ++rr)
            a[rr] = *(const float4*)&As[(r + rr) * 128 + (k ^ sw)];
        #pragma unroll
        for (int kk = 0; kk < 4; ++kk) {
            float4 w0 = *(const float4*)&Ws[(k + kk) * 128 + c];
            float4 w1 = *(const float4*)&Ws[(k + kk) * 128 + c + 4];
            float4 w2 = *(const float4*)&Ws[(k + kk) * 128 + c + 8];
            float4 w3 = *(const float4*)&Ws[(k + kk) * 128 + c + 12];
            #pragma unroll
            for (int rr = 0; rr < 4; ++rr) {
                float av = ((const float*)&a[rr])[kk];
                acc[rr][0] += av * w0.x; acc[rr][1] += av * w0.y;
                acc[rr][2] += av * w0.z; acc[rr][3] += av * w0.w;
                acc[rr][4] += av * w1.x; acc[rr][5] += av * w1.y;
                acc[rr][6] += av * w1.z; acc[rr][7] += av * w1.w;
                acc[rr][8] += av * w2.x; acc[rr][9] += av * w2.y;
                acc[rr][10] += av * w2.z; acc[rr][11] += av * w2.w;
                acc[rr][12] += av * w3.x; acc[rr][13] += av * w3.y;
                acc[rr][14] += av * w3.z; acc[rr][15] += av * w3.w;
            }
        }
    }
    #pragma unroll
    for (int rr = 0; rr < 4; ++rr) {
        int rrow = row0 + r + rr;
        if (rrow < n) {
            float s = dinv[rrow];
            union { unsigned int u[8]; uint4 q[2]; } pk;
            #pragma unroll
            for (int j = 0; j < 8; ++j) {
                __hip_bfloat162 b2 = __float22bfloat162_rn(
                    make_float2(acc[rr][2*j] * s, acc[rr][2*j+1] * s));
                pk.u[j] = *reinterpret_cast<unsigned int*>(&b2);
            }
            uint4* op = (uint4*)(C + (size_t)rrow * 128 + c);
            op[0] = pk.q[0]; op[1] = pk.q[1];
        }
    }
}

// ---------------- 128-ch aggregation: one wave per node, bf16 gathers ----------------

__global__ void k_agg128(const unsigned int* __restrict__ hb, const int* __restrict__ ss,
                         const int* __restrict__ offs, const float* __restrict__ dinv,
                         const float* __restrict__ bias, float* __restrict__ hout, int n) {
    int wid = threadIdx.x >> 6, lane = threadIdx.x & 63;
    int node = blockIdx.x * (blockDim.x >> 6) + wid;
    if (node >= n) return;
    unsigned int self = hb[(size_t)node * 64 + lane];
    float ax = __uint_as_float(self << 16);
    float ay = __uint_as_float(self & 0xffff0000u);
    int e1 = offs[node + 1];
    for (int e = offs[node]; e < e1; ++e) {
        int s = ss[e];
        unsigned int v = hb[(size_t)s * 64 + lane];
        ax += __uint_as_float(v << 16);
        ay += __uint_as_float(v & 0xffff0000u);
    }
    float dn = dinv[node];
    float2 b = ((const float2*)bias)[lane];
    float2 o; o.x = ax * dn + b.x; o.y = ay * dn + b.y;
    ((float2*)hout)[(size_t)node * 64 + lane] = o;
}

// ---------------- pooling + head ----------------

__global__ void k_zero_pool(float* __restrict__ gsum) {
    int i = blockIdx.x * blockDim.x + threadIdx.x;
    if (i < 64 * 128) gsum[i] = 0.f;
}

__global__ void k_bounds(const int* __restrict__ batch, int* __restrict__ gcnt, int n) {
    __shared__ int b[65];
    int g = threadIdx.x;  // 128 threads, only 0..64 search
    if (g <= 64) {
        int lo = 0, hi = n;
        while (lo < hi) {
            int mid = (lo + hi) >> 1;
            if (batch[mid] < g) lo = mid + 1; else hi = mid;
        }
        b[g] = lo;
    }
    __syncthreads();
    if (g < 64) gcnt[g] = b[g + 1] - b[g];
}

__global__ void k_pool(const float* __restrict__ h, const int* __restrict__ batch,
                       const float* __restrict__ ab, float* __restrict__ gsum,
                       int n, int rows_per_block) {
    int tid = threadIdx.x; int c = tid & 127; int half = tid >> 7;
    int r0 = blockIdx.x * rows_per_block;
    int r1 = min(r0 + rows_per_block, n);
    int half_len = rows_per_block >> 1;
    int rs = r0 + half * half_len;
    int re = min(rs + half_len, r1);
    float A = ab[c], B = ab[128 + c];
    float acc = 0.f; int cur = -1;
    for (int r = rs; r < re; ++r) {
        int g = batch[r];
        if (g != cur) {
            if (cur >= 0) atomicAdd(&gsum[cur * 128 + c], acc);
            acc = 0.f; cur = g;
        }
        float v = h[(size_t)r * 128 + c];
        acc += fmaxf(0.f, v * A + B);
    }
    if (cur >= 0) atomicAdd(&gsum[cur * 128 + c], acc);
}

__global__ void k_final(const float* __restrict__ gsum, const int* __restrict__ gcnt,
                        const float* __restrict__ embW, const float* __restrict__ embb,
                        float* __restrict__ out) {
    __shared__ float row[128];
    int g = blockIdx.x, j = threadIdx.x;  // 64 threads
    float invc = 1.f / fmaxf((float)gcnt[g], 1.f);
    for (int i = j; i < 128; i += 64) row[i] = gsum[g * 128 + i] * invc;
    __syncthreads();
    float acc = embb[j];
    for (int cdx = 0; cdx < 128; ++cdx) acc += row[cdx] * embW[cdx * 64 + j];
    out[g * 64 + j] = acc;
}

// ---------------- launch ----------------

extern "C" void kernel_launch(void* const* d_in, const int* in_sizes, int n_in,
                              void* d_out, int out_size, void* d_ws, size_t ws_size,
                              hipStream_t stream) {
    const float* x     = (const float*)d_in[0];
    const float* W0    = (const float*)d_in[1];
    const float* Wh    = (const float*)d_in[2];
    const float* bias  = (const float*)d_in[3];
    const float* gamma = (const float*)d_in[4];
    const float* beta  = (const float*)d_in[5];
    const float* embW  = (const float*)d_in[6];
    const float* embb  = (const float*)d_in[7];
    const int*   ei    = (const int*)d_in[8];
    const int*   batch = (const int*)d_in[9];
    int N = in_sizes[9];
    int E = in_sizes[8] / 2;
    const int* src = ei;
    const int* dst = ei + E;

    char* w = (char*)d_ws;
    size_t off = 0;
    auto carve = [&](size_t bytes) {
        char* p = w + off;
        off = (off + bytes + 255) & ~(size_t)255;
        return (void*)p;
    };
    int*   deg    = (int*)carve((size_t)N * 4);
    float* dinv   = (float*)carve((size_t)N * 4);
    int*   offs   = (int*)carve((size_t)(N + 1) * 4);
    int*   cursor = (int*)carve((size_t)N * 4);
    int*   ss     = (int*)carve((size_t)E * 4);
    float* out5   = (float*)carve((size_t)N * 5 * 4);
    float* xs     = (float*)carve((size_t)N * 5 * 4);
    float* hA     = (float*)carve((size_t)N * 128 * 4);
    __hip_bfloat16* hB = (__hip_bfloat16*)carve((size_t)N * 128 * 2);
    float* part   = (float*)carve(256 * 512 * 4);
    float* ab     = (float*)carve(256 * 4);
    float* gsum   = (float*)carve(64 * 128 * 4);
    int*   gcnt   = (int*)carve(64 * 4);
    int*   tsum   = (int*)carve(65536 * 4);
    int*   bsum   = (int*)carve(256 * 4);
    int*   bbase  = (int*)carve(257 * 4);
    (void)ws_size; (void)n_in; (void)out_size;

    int nb = (N + 255) / 256;
    int eb = (E + 255) / 256;
    int gb = (N + 127) / 128;
    int ab4 = (N + 3) / 4;
    int ct = (N + 65535) / 65536;

    k_init_deg<<<nb, 256, 0, stream>>>(deg, N);
    k_deg<<<eb, 256, 0, stream>>>(dst, deg, E);
    k_dinv<<<nb, 256, 0, stream>>>(deg, x, dinv, xs, N);
    k_scan1<<<256, 256, 0, stream>>>(deg, tsum, bsum, N, ct);
    k_scan2<<<1, 256, 0, stream>>>(bsum, bbase);
    k_scan3<<<256, 256, 0, stream>>>(deg, tsum, bbase, offs, cursor, N, ct);
    k_fill<<<eb, 256, 0, stream>>>(src, dst, cursor, ss, E);

    // layer 0: aggregate x' (5ch) then GEMM to 128 (+bias0)
    k_agg5<<<nb, 256, 0, stream>>>(xs, ss, offs, dinv, out5, N);
    k_gemm0<<<(N * 128 + 255) / 256, 256, 0, stream>>>(out5, W0, bias, hA, N);
    k_bnstats<<<256, 256, 0, stream>>>(hA, part, N);
    k_bnfinal<<<1, 128, 0, stream>>>(part, 256, gamma, beta, ab, N);

    // layer 1 (BN0+ReLU fused into A-load; output bf16 scaled by dinv)
    k_gemm128<<<gb, 256, 0, stream>>>(hA, Wh, ab, dinv, hB, N);
    k_agg128<<<ab4, 256, 0, stream>>>((const unsigned int*)hB, ss, offs, dinv, bias + 128, hA, N);
    k_bnstats<<<256, 256, 0, stream>>>(hA, part, N);
    k_bnfinal<<<1, 128, 0, stream>>>(part, 256, gamma + 128, beta + 128, ab, N);

    // layer 2
    k_gemm128<<<gb, 256, 0, stream>>>(hA, Wh + 128 * 128, ab, dinv, hB, N);
    k_agg128<<<ab4, 256, 0, stream>>>((const unsigned int*)hB, ss, offs, dinv, bias + 256, hA, N);
    k_bnstats<<<256, 256, 0, stream>>>(hA, part, N);
    k_bnfinal<<<1, 128, 0, stream>>>(part, 256, gamma + 256, beta + 256, ab, N);

    // pool (fuses layer-2 BN+ReLU) + head
    k_zero_pool<<<(64 * 128 + 255) / 256, 256, 0, stream>>>(gsum);
    k_bounds<<<1, 128, 0, stream>>>(batch, gcnt, N);
    int rpb = 512;
    k_pool<<<(N + rpb - 1) / rpb, 256, 0, stream>>>(hA, batch, ab, gsum, N, rpb);
    k_final<<<64, 64, 0, stream>>>(gsum, gcnt, embW, embb, (float*)d_out);
}

// Round 5
// 1260.214 us; speedup vs baseline: 2.0925x; 1.4027x over previous
//
#include <hip/hip_runtime.h>
#include <hip/hip_bf16.h>

constexpr float BN_EPS = 1e-5f;
// Bucketing: 256 nodes/bucket. N=100000 -> B=391 buckets (static LDS sized 512, ok for N<=131072).

// ---------------- graph preprocessing ----------------

__global__ void k_init_deg(int* __restrict__ deg, int n) {
    int i = blockIdx.x * blockDim.x + threadIdx.x;
    if (i < n) deg[i] = 1;  // self loop
}

// fused: global degree count + per-(bucket,block) histogram
__global__ void k_histdeg(const int* __restrict__ dst, int* __restrict__ deg,
                          int* __restrict__ hist, int E, int B, int chunk) {
    __shared__ int lh[512];
    int t = threadIdx.x, blk = blockIdx.x;
    for (int i = t; i < 512; i += 256) lh[i] = 0;
    __syncthreads();
    int e0 = blk * chunk, e1 = min(E, e0 + chunk);
    for (int e = e0 + t; e < e1; e += 256) {
        int d = dst[e];
        atomicAdd(&deg[d], 1);
        atomicAdd(&lh[d >> 8], 1);
    }
    __syncthreads();
    for (int b = t; b < B; b += 256) hist[b * 256 + blk] = lh[b];
}

// dinv + pre-scaled x' = x*dinv[row] + indeg = deg-1
__global__ void k_dinv(const int* __restrict__ deg, const float* __restrict__ x,
                       float* __restrict__ dinv, float* __restrict__ xs,
                       int* __restrict__ indeg, int n) {
    int i = blockIdx.x * blockDim.x + threadIdx.x;
    if (i >= n) return;
    int dg = deg[i];
    float d = rsqrtf((float)dg);
    dinv[i] = d;
    indeg[i] = dg - 1;
    const float* xr = x + (size_t)i * 5;
    float* o = xs + (size_t)i * 5;
    #pragma unroll
    for (int j = 0; j < 5; ++j) o[j] = xr[j] * d;
}

// ---- generic exclusive scan over int array: out[0..n] (out[n]=total) ----
// 65536 threads, ct elems each

__global__ void g_scan1(const int* __restrict__ in, int* __restrict__ tsum,
                        int* __restrict__ bsum, int n, int ct) {
    int t = threadIdx.x, b = blockIdx.x;
    int i = b * 256 + t;
    int s0 = i * ct, s1 = min(n, s0 + ct);
    int s = 0;
    for (int k = s0; k < s1; ++k) s += in[k];
    tsum[i] = s;
    __shared__ int red[256];
    red[t] = s; __syncthreads();
    for (int d = 128; d > 0; d >>= 1) {
        if (t < d) red[t] += red[t + d];
        __syncthreads();
    }
    if (t == 0) bsum[b] = red[0];
}

__global__ void g_scan2(const int* __restrict__ bsum, int* __restrict__ bbase) {
    int t = threadIdx.x;  // 256
    __shared__ int sh[256];
    int v = bsum[t];
    sh[t] = v; __syncthreads();
    for (int d = 1; d < 256; d <<= 1) {
        int u = (t >= d) ? sh[t - d] : 0;
        __syncthreads();
        sh[t] += u;
        __syncthreads();
    }
    bbase[t] = sh[t] - v;  // exclusive
    if (t == 255) bbase[256] = sh[255];
}

__global__ void g_scan3(const int* __restrict__ in, const int* __restrict__ tsum,
                        const int* __restrict__ bbase, int* __restrict__ out,
                        int n, int ct) {
    int t = threadIdx.x, b = blockIdx.x;
    __shared__ int sh[256];
    int v = tsum[b * 256 + t];
    sh[t] = v; __syncthreads();
    for (int d = 1; d < 256; d <<= 1) {
        int u = (t >= d) ? sh[t - d] : 0;
        __syncthreads();
        sh[t] += u;
        __syncthreads();
    }
    int run = bbase[b] + sh[t] - v;
    int i = b * 256 + t;
    int s0 = i * ct, s1 = min(n, s0 + ct);
    for (int k = s0; k < s1; ++k) {
        out[k] = run;
        run += in[k];
    }
    if (i == 65535) out[n] = bbase[256];
}

// scatter edges into bucket-grouped pairs, block-exclusive streams
__global__ void k_scatter(const int* __restrict__ src, const int* __restrict__ dst,
                          const int* __restrict__ sbase, unsigned int* __restrict__ pairs,
                          int E, int B, int chunk) {
    __shared__ int cur[512];
    int t = threadIdx.x, blk = blockIdx.x;
    for (int b = t; b < B; b += 256) cur[b] = sbase[b * 256 + blk];
    __syncthreads();
    int e0 = blk * chunk, e1 = min(E, e0 + chunk);
    for (int e = e0 + t; e < e1; e += 256) {
        int d = dst[e];
        int s = src[e];
        int p = atomicAdd(&cur[d >> 8], 1);
        pairs[p] = ((unsigned int)s << 8) | (unsigned int)(d & 255);
    }
}

// per-bucket fine CSR fill: ss region is L2-resident
__global__ void k_finecsr(const unsigned int* __restrict__ pairs, const int* __restrict__ sbase,
                          const int* __restrict__ offs, int* __restrict__ ss, int n) {
    __shared__ int cur[256];
    int t = threadIdx.x, b = blockIdx.x;
    int lo = b * 256;
    int cnt = min(256, n - lo);
    if (t < cnt) cur[t] = offs[lo + t];
    __syncthreads();
    int p0 = sbase[b * 256];
    int p1 = sbase[b * 256 + 256];
    for (int p = p0 + t; p < p1; p += 256) {
        unsigned int pk = pairs[p];
        int loc = pk & 255;
        int s = pk >> 8;
        int pos = atomicAdd(&cur[loc], 1);
        ss[pos] = s;
    }
}

// ---------------- layer 0: aggregate pre-scaled x' (5ch), then GEMM to 128 ----------------

__global__ void k_agg5(const float* __restrict__ xs, const int* __restrict__ ss,
                       const int* __restrict__ offs, const float* __restrict__ dinv,
                       float* __restrict__ out5, int n) {
    int node = blockIdx.x * blockDim.x + threadIdx.x;
    if (node >= n) return;
    const float* xr = xs + (size_t)node * 5;
    float a0 = xr[0], a1 = xr[1], a2 = xr[2], a3 = xr[3], a4 = xr[4];
    int e1 = offs[node + 1];
    for (int e = offs[node]; e < e1; ++e) {
        int s = ss[e];
        const float* p = xs + (size_t)s * 5;
        a0 += p[0]; a1 += p[1]; a2 += p[2]; a3 += p[3]; a4 += p[4];
    }
    float dn = dinv[node];
    float* o = out5 + (size_t)node * 5;
    o[0] = a0 * dn; o[1] = a1 * dn; o[2] = a2 * dn; o[3] = a3 * dn; o[4] = a4 * dn;
}

__global__ void k_gemm0(const float* __restrict__ out5, const float* __restrict__ W0,
                        const float* __restrict__ bias0, float* __restrict__ h, int n) {
    __shared__ float w[5 * 128];
    __shared__ float b[128];
    int tid = threadIdx.x;
    for (int i = tid; i < 640; i += blockDim.x) w[i] = W0[i];
    if (tid < 128) b[tid] = bias0[tid];
    __syncthreads();
    int idx = blockIdx.x * blockDim.x + tid;
    if (idx < n * 128) {
        int node = idx >> 7, c = idx & 127;
        const float* a = out5 + (size_t)node * 5;
        float r = b[c] + a[0]*w[c] + a[1]*w[128+c] + a[2]*w[256+c]
                       + a[3]*w[384+c] + a[4]*w[512+c];
        h[idx] = r;
    }
}

// ---------------- BatchNorm ----------------

__global__ void k_bnstats(const float* __restrict__ h, float* __restrict__ part, int n) {
    int tid = threadIdx.x;
    int c = tid & 127, half = tid >> 7;
    float s = 0.f, q = 0.f;
    for (int r = blockIdx.x * 2 + half; r < n; r += gridDim.x * 2) {
        float v = h[(size_t)r * 128 + c];
        s += v; q += v * v;
    }
    part[blockIdx.x * 512 + tid] = s;
    part[blockIdx.x * 512 + 256 + tid] = q;
}

__global__ void k_bnfinal(const float* __restrict__ part, int nblocks,
                          const float* __restrict__ gamma, const float* __restrict__ beta,
                          float* __restrict__ ab, int n) {
    int c = threadIdx.x;  // 128
    float s = 0.f, q = 0.f;
    for (int b = 0; b < nblocks; ++b) {
        const float* p = part + b * 512;
        s += p[c] + p[c + 128];
        q += p[256 + c] + p[256 + c + 128];
    }
    float mean = s / n;
    float var = q / n - mean * mean;
    float inv = rsqrtf(var + BN_EPS);
    float A = gamma[c] * inv;
    ab[c] = A;
    ab[128 + c] = beta[c] - mean * A;
}

// ------- 128x128 GEMM (fp32, LDS-tiled), BN+ReLU fused on A-load,
//         epilogue: scale row by dinv[row], emit bf16 -------

__global__ __launch_bounds__(256) void k_gemm128(const float* __restrict__ A,
                                                 const float* __restrict__ W,
                                                 const float* __restrict__ ab,
                                                 const float* __restrict__ dinv,
                                                 __hip_bfloat16* __restrict__ C, int n) {
    __shared__ float As[128 * 128];
    __shared__ float Ws[128 * 128];
    int tid = threadIdx.x;
    const float4* W4 = (const float4*)W;
    for (int i = tid; i < 4096; i += 256) ((float4*)Ws)[i] = W4[i];
    int row0 = blockIdx.x * 128;
    int nrows = min(128, n - row0);
    const float4* A4 = (const float4*)(A + (size_t)row0 * 128);
    for (int i = tid; i < nrows * 32; i += 256) {
        int r = i >> 5, k4 = i & 31;
        float4 v = A4[i];
        float4 Aq = ((const float4*)ab)[k4];
        float4 Bq = ((const float4*)(ab + 128))[k4];
        v.x = fmaxf(0.f, v.x * Aq.x + Bq.x);
        v.y = fmaxf(0.f, v.y * Aq.y + Bq.y);
        v.z = fmaxf(0.f, v.z * Aq.z + Bq.z);
        v.w = fmaxf(0.f, v.w * Aq.w + Bq.w);
        int sw = ((r >> 2) & 7) << 2;
        int col = (k4 * 4) ^ sw;
        *(float4*)&As[r * 128 + col] = v;
    }
    __syncthreads();
    int rm = tid >> 3, cn = tid & 7;
    int r = rm * 4, c = cn * 16;
    float acc[4][16];
    #pragma unroll
    for (int i = 0; i < 4; ++i)
        #pragma unroll
        for (int j = 0; j < 16; ++j) acc[i][j] = 0.f;
    for (int k = 0; k < 128; k += 4) {
        float4 a[4];
        int sw = (rm & 7) << 2;
        #pragma unroll
        for (int rr = 0; rr < 4; ++rr)
            a[rr] = *(const float4*)&As[(r + rr) * 128 + (k ^ sw)];
        #pragma unroll
        for (int kk = 0; kk < 4; ++kk) {
            float4 w0 = *(const float4*)&Ws[(k + kk) * 128 + c];
            float4 w1 = *(const float4*)&Ws[(k + kk) * 128 + c + 4];
            float4 w2 = *(const float4*)&Ws[(k + kk) * 128 + c + 8];
            float4 w3 = *(const float4*)&Ws[(k + kk) * 128 + c + 12];
            #pragma unroll
            for (int rr = 0; rr < 4; ++rr) {
                float av = ((const float*)&a[rr])[kk];
                acc[rr][0] += av * w0.x; acc[rr][1] += av * w0.y;
                acc[rr][2] += av * w0.z; acc[rr][3] += av * w0.w;
                acc[rr][4] += av * w1.x; acc[rr][5] += av * w1.y;
                acc[rr][6] += av * w1.z; acc[rr][7] += av * w1.w;
                acc[rr][8] += av * w2.x; acc[rr][9] += av * w2.y;
                acc[rr][10] += av * w2.z; acc[rr][11] += av * w2.w;
                acc[rr][12] += av * w3.x; acc[rr][13] += av * w3.y;
                acc[rr][14] += av * w3.z; acc[rr][15] += av * w3.w;
            }
        }
    }
    #pragma unroll
    for (int rr = 0; rr < 4; ++rr) {
        int rrow = row0 + r + rr;
        if (rrow < n) {
            float s = dinv[rrow];
            union { unsigned int u[8]; uint4 q[2]; } pk;
            #pragma unroll
            for (int j = 0; j < 8; ++j) {
                __hip_bfloat162 b2 = __float22bfloat162_rn(
                    make_float2(acc[rr][2*j] * s, acc[rr][2*j+1] * s));
                pk.u[j] = *reinterpret_cast<unsigned int*>(&b2);
            }
            uint4* op = (uint4*)(C + (size_t)rrow * 128 + c);
            op[0] = pk.q[0]; op[1] = pk.q[1];
        }
    }
}

// ---------------- 128-ch aggregation: one wave per node, bf16 gathers, 4x unroll ----------------

__global__ void k_agg128(const unsigned int* __restrict__ hb, const int* __restrict__ ss,
                         const int* __restrict__ offs, const float* __restrict__ dinv,
                         const float* __restrict__ bias, float* __restrict__ hout, int n) {
    int wid = threadIdx.x >> 6, lane = threadIdx.x & 63;
    int node = blockIdx.x * (blockDim.x >> 6) + wid;
    if (node >= n) return;
    unsigned int self = hb[(size_t)node * 64 + lane];
    float ax = __uint_as_float(self << 16);
    float ay = __uint_as_float(self & 0xffff0000u);
    int e = offs[node], e1 = offs[node + 1];
    for (; e + 4 <= e1; e += 4) {
        int s0 = ss[e], s1 = ss[e + 1], s2 = ss[e + 2], s3 = ss[e + 3];
        unsigned int v0 = hb[(size_t)s0 * 64 + lane];
        unsigned int v1 = hb[(size_t)s1 * 64 + lane];
        unsigned int v2 = hb[(size_t)s2 * 64 + lane];
        unsigned int v3 = hb[(size_t)s3 * 64 + lane];
        ax += __uint_as_float(v0 << 16); ay += __uint_as_float(v0 & 0xffff0000u);
        ax += __uint_as_float(v1 << 16); ay += __uint_as_float(v1 & 0xffff0000u);
        ax += __uint_as_float(v2 << 16); ay += __uint_as_float(v2 & 0xffff0000u);
        ax += __uint_as_float(v3 << 16); ay += __uint_as_float(v3 & 0xffff0000u);
    }
    for (; e < e1; ++e) {
        unsigned int v = hb[(size_t)ss[e] * 64 + lane];
        ax += __uint_as_float(v << 16);
        ay += __uint_as_float(v & 0xffff0000u);
    }
    float dn = dinv[node];
    float2 b = ((const float2*)bias)[lane];
    float2 o; o.x = ax * dn + b.x; o.y = ay * dn + b.y;
    ((float2*)hout)[(size_t)node * 64 + lane] = o;
}

// ---------------- pooling + head ----------------

__global__ void k_zero_pool(float* __restrict__ gsum) {
    int i = blockIdx.x * blockDim.x + threadIdx.x;
    if (i < 64 * 128) gsum[i] = 0.f;
}

__global__ void k_bounds(const int* __restrict__ batch, int* __restrict__ gcnt, int n) {
    __shared__ int b[65];
    int g = threadIdx.x;
    if (g <= 64) {
        int lo = 0, hi = n;
        while (lo < hi) {
            int mid = (lo + hi) >> 1;
            if (batch[mid] < g) lo = mid + 1; else hi = mid;
        }
        b[g] = lo;
    }
    __syncthreads();
    if (g < 64) gcnt[g] = b[g + 1] - b[g];
}

__global__ void k_pool(const float* __restrict__ h, const int* __restrict__ batch,
                       const float* __restrict__ ab, float* __restrict__ gsum,
                       int n, int rows_per_block) {
    int tid = threadIdx.x; int c = tid & 127; int half = tid >> 7;
    int r0 = blockIdx.x * rows_per_block;
    int r1 = min(r0 + rows_per_block, n);
    int half_len = rows_per_block >> 1;
    int rs = r0 + half * half_len;
    int re = min(rs + half_len, r1);
    float A = ab[c], B = ab[128 + c];
    float acc = 0.f; int cur = -1;
    for (int r = rs; r < re; ++r) {
        int g = batch[r];
        if (g != cur) {
            if (cur >= 0) atomicAdd(&gsum[cur * 128 + c], acc);
            acc = 0.f; cur = g;
        }
        float v = h[(size_t)r * 128 + c];
        acc += fmaxf(0.f, v * A + B);
    }
    if (cur >= 0) atomicAdd(&gsum[cur * 128 + c], acc);
}

__global__ void k_final(const float* __restrict__ gsum, const int* __restrict__ gcnt,
                        const float* __restrict__ embW, const float* __restrict__ embb,
                        float* __restrict__ out) {
    __shared__ float row[128];
    int g = blockIdx.x, j = threadIdx.x;  // 64 threads
    float invc = 1.f / fmaxf((float)gcnt[g], 1.f);
    for (int i = j; i < 128; i += 64) row[i] = gsum[g * 128 + i] * invc;
    __syncthreads();
    float acc = embb[j];
    for (int cdx = 0; cdx < 128; ++cdx) acc += row[cdx] * embW[cdx * 64 + j];
    out[g * 64 + j] = acc;
}

// ---------------- launch ----------------

extern "C" void kernel_launch(void* const* d_in, const int* in_sizes, int n_in,
                              void* d_out, int out_size, void* d_ws, size_t ws_size,
                              hipStream_t stream) {
    const float* x     = (const float*)d_in[0];
    const float* W0    = (const float*)d_in[1];
    const float* Wh    = (const float*)d_in[2];
    const float* bias  = (const float*)d_in[3];
    const float* gamma = (const float*)d_in[4];
    const float* beta  = (const float*)d_in[5];
    const float* embW  = (const float*)d_in[6];
    const float* embb  = (const float*)d_in[7];
    const int*   ei    = (const int*)d_in[8];
    const int*   batch = (const int*)d_in[9];
    int N = in_sizes[9];
    int E = in_sizes[8] / 2;
    const int* src = ei;
    const int* dst = ei + E;
    int B = (N + 255) >> 8;  // buckets of 256 nodes

    char* w = (char*)d_ws;
    size_t off = 0;
    auto carve = [&](size_t bytes) {
        char* p = w + off;
        off = (off + bytes + 255) & ~(size_t)255;
        return (void*)p;
    };
    int*   deg    = (int*)carve((size_t)N * 4);
    float* dinv   = (float*)carve((size_t)N * 4);
    int*   indeg  = (int*)carve((size_t)N * 4);
    int*   offs   = (int*)carve((size_t)(N + 1) * 4);
    int*   ss     = (int*)carve((size_t)E * 4);
    unsigned int* pairs = (unsigned int*)carve((size_t)E * 4);
    int*   hist   = (int*)carve((size_t)B * 256 * 4);
    int*   sbase  = (int*)carve(((size_t)B * 256 + 1) * 4);
    float* out5   = (float*)carve((size_t)N * 5 * 4);
    float* xs     = (float*)carve((size_t)N * 5 * 4);
    float* hA     = (float*)carve((size_t)N * 128 * 4);
    __hip_bfloat16* hB = (__hip_bfloat16*)carve((size_t)N * 128 * 2);
    float* part   = (float*)carve(256 * 512 * 4);
    float* ab     = (float*)carve(256 * 4);
    float* gsum   = (float*)carve(64 * 128 * 4);
    int*   gcnt   = (int*)carve(64 * 4);
    int*   tsum   = (int*)carve(65536 * 4);
    int*   bsum   = (int*)carve(256 * 4);
    int*   bbase  = (int*)carve(257 * 4);
    (void)ws_size; (void)n_in; (void)out_size;

    int nb = (N + 255) / 256;
    int gb = (N + 127) / 128;
    int ab4 = (N + 3) / 4;
    int echunk = (E + 255) / 256;
    int ctN = (N + 65535) / 65536;
    int nH = B * 256;
    int ctH = (nH + 65535) / 65536;

    // graph prep: degree + bucket histogram -> scans -> bucketed pairs -> fine CSR
    k_init_deg<<<nb, 256, 0, stream>>>(deg, N);
    k_histdeg<<<256, 256, 0, stream>>>(dst, deg, hist, E, B, echunk);
    k_dinv<<<nb, 256, 0, stream>>>(deg, x, dinv, xs, indeg, N);
    g_scan1<<<256, 256, 0, stream>>>(indeg, tsum, bsum, N, ctN);
    g_scan2<<<1, 256, 0, stream>>>(bsum, bbase);
    g_scan3<<<256, 256, 0, stream>>>(indeg, tsum, bbase, offs, N, ctN);
    g_scan1<<<256, 256, 0, stream>>>(hist, tsum, bsum, nH, ctH);
    g_scan2<<<1, 256, 0, stream>>>(bsum, bbase);
    g_scan3<<<256, 256, 0, stream>>>(hist, tsum, bbase, sbase, nH, ctH);
    k_scatter<<<256, 256, 0, stream>>>(src, dst, sbase, pairs, E, B, echunk);
    k_finecsr<<<B, 256, 0, stream>>>(pairs, sbase, offs, ss, N);

    // layer 0
    k_agg5<<<nb, 256, 0, stream>>>(xs, ss, offs, dinv, out5, N);
    k_gemm0<<<(N * 128 + 255) / 256, 256, 0, stream>>>(out5, W0, bias, hA, N);
    k_bnstats<<<256, 256, 0, stream>>>(hA, part, N);
    k_bnfinal<<<1, 128, 0, stream>>>(part, 256, gamma, beta, ab, N);

    // layer 1
    k_gemm128<<<gb, 256, 0, stream>>>(hA, Wh, ab, dinv, hB, N);
    k_agg128<<<ab4, 256, 0, stream>>>((const unsigned int*)hB, ss, offs, dinv, bias + 128, hA, N);
    k_bnstats<<<256, 256, 0, stream>>>(hA, part, N);
    k_bnfinal<<<1, 128, 0, stream>>>(part, 256, gamma + 128, beta + 128, ab, N);

    // layer 2
    k_gemm128<<<gb, 256, 0, stream>>>(hA, Wh + 128 * 128, ab, dinv, hB, N);
    k_agg128<<<ab4, 256, 0, stream>>>((const unsigned int*)hB, ss, offs, dinv, bias + 256, hA, N);
    k_bnstats<<<256, 256, 0, stream>>>(hA, part, N);
    k_bnfinal<<<1, 128, 0, stream>>>(part, 256, gamma + 256, beta + 256, ab, N);

    // pool (fuses layer-2 BN+ReLU) + head
    k_zero_pool<<<(64 * 128 + 255) / 256, 256, 0, stream>>>(gsum);
    k_bounds<<<1, 128, 0, stream>>>(batch, gcnt, N);
    int rpb = 512;
    k_pool<<<(N + rpb - 1) / rpb, 256, 0, stream>>>(hA, batch, ab, gsum, N, rpb);
    k_final<<<64, 64, 0, stream>>>(gsum, gcnt, embW, embb, (float*)d_out);
}

// Round 6
// 1145.319 us; speedup vs baseline: 2.3025x; 1.1003x over previous
//
#include <hip/hip_runtime.h>
#include <hip/hip_bf16.h>

constexpr float BN_EPS = 1e-5f;
// Bucketing: 256 nodes/bucket. N=100000 -> B=391 buckets (static LDS sized 512, ok for N<=131072).

// ---------------- graph preprocessing ----------------

// per-(bucket,block) histogram of dst (LDS atomics only, no global atomics)
__global__ void k_hist(const int* __restrict__ dst, int* __restrict__ hist,
                       int E, int B, int chunk) {
    __shared__ int lh[512];
    int t = threadIdx.x, blk = blockIdx.x;
    for (int i = t; i < 512; i += 256) lh[i] = 0;
    __syncthreads();
    int e0 = blk * chunk, e1 = min(E, e0 + chunk);
    for (int e = e0 + t; e < e1; e += 256) {
        atomicAdd(&lh[dst[e] >> 8], 1);
    }
    __syncthreads();
    for (int b = t; b < B; b += 256) hist[b * 256 + blk] = lh[b];
}

// ---- generic exclusive scan over int array: out[0..n] (out[n]=total) ----
// 65536 threads, ct elems each

__global__ void g_scan1(const int* __restrict__ in, int* __restrict__ tsum,
                        int* __restrict__ bsum, int n, int ct) {
    int t = threadIdx.x, b = blockIdx.x;
    int i = b * 256 + t;
    int s0 = i * ct, s1 = min(n, s0 + ct);
    int s = 0;
    for (int k = s0; k < s1; ++k) s += in[k];
    tsum[i] = s;
    __shared__ int red[256];
    red[t] = s; __syncthreads();
    for (int d = 128; d > 0; d >>= 1) {
        if (t < d) red[t] += red[t + d];
        __syncthreads();
    }
    if (t == 0) bsum[b] = red[0];
}

__global__ void g_scan2(const int* __restrict__ bsum, int* __restrict__ bbase) {
    int t = threadIdx.x;  // 256
    __shared__ int sh[256];
    int v = bsum[t];
    sh[t] = v; __syncthreads();
    for (int d = 1; d < 256; d <<= 1) {
        int u = (t >= d) ? sh[t - d] : 0;
        __syncthreads();
        sh[t] += u;
        __syncthreads();
    }
    bbase[t] = sh[t] - v;  // exclusive
    if (t == 255) bbase[256] = sh[255];
}

__global__ void g_scan3(const int* __restrict__ in, const int* __restrict__ tsum,
                        const int* __restrict__ bbase, int* __restrict__ out,
                        int n, int ct) {
    int t = threadIdx.x, b = blockIdx.x;
    __shared__ int sh[256];
    int v = tsum[b * 256 + t];
    sh[t] = v; __syncthreads();
    for (int d = 1; d < 256; d <<= 1) {
        int u = (t >= d) ? sh[t - d] : 0;
        __syncthreads();
        sh[t] += u;
        __syncthreads();
    }
    int run = bbase[b] + sh[t] - v;
    int i = b * 256 + t;
    int s0 = i * ct, s1 = min(n, s0 + ct);
    for (int k = s0; k < s1; ++k) {
        out[k] = run;
        run += in[k];
    }
    if (i == 65535) out[n] = bbase[256];
}

// scatter edges into bucket-grouped pairs, block-exclusive streams
__global__ void k_scatter(const int* __restrict__ src, const int* __restrict__ dst,
                          const int* __restrict__ sbase, unsigned int* __restrict__ pairs,
                          int E, int B, int chunk) {
    __shared__ int cur[512];
    int t = threadIdx.x, blk = blockIdx.x;
    for (int b = t; b < B; b += 256) cur[b] = sbase[b * 256 + blk];
    __syncthreads();
    int e0 = blk * chunk, e1 = min(E, e0 + chunk);
    for (int e = e0 + t; e < e1; e += 256) {
        int d = dst[e];
        int s = src[e];
        int p = atomicAdd(&cur[d >> 8], 1);
        pairs[p] = ((unsigned int)s << 8) | (unsigned int)(d & 255);
    }
}

// per-bucket degree count from pairs (LDS atomics) + fused dinv/xs/indeg
__global__ void k_degcnt(const unsigned int* __restrict__ pairs, const int* __restrict__ sbase,
                         const float* __restrict__ x, float* __restrict__ dinv,
                         float* __restrict__ xs, int* __restrict__ indeg, int n) {
    __shared__ int lh[256];
    int t = threadIdx.x, b = blockIdx.x;
    lh[t] = 0;
    __syncthreads();
    int p0 = sbase[b * 256];
    int p1 = sbase[b * 256 + 256];
    for (int p = p0 + t; p < p1; p += 256) {
        atomicAdd(&lh[pairs[p] & 255], 1);
    }
    __syncthreads();
    int node = b * 256 + t;
    if (node < n) {
        int cnt = lh[t];
        indeg[node] = cnt;
        float d = rsqrtf((float)(cnt + 1));  // +1 self loop
        dinv[node] = d;
        const float* xr = x + (size_t)node * 5;
        float* o = xs + (size_t)node * 5;
        #pragma unroll
        for (int j = 0; j < 5; ++j) o[j] = xr[j] * d;
    }
}

// per-bucket fine CSR fill: ss region is L2-resident
__global__ void k_finecsr(const unsigned int* __restrict__ pairs, const int* __restrict__ sbase,
                          const int* __restrict__ offs, int* __restrict__ ss, int n) {
    __shared__ int cur[256];
    int t = threadIdx.x, b = blockIdx.x;
    int lo = b * 256;
    int cnt = min(256, n - lo);
    if (t < cnt) cur[t] = offs[lo + t];
    __syncthreads();
    int p0 = sbase[b * 256];
    int p1 = sbase[b * 256 + 256];
    for (int p = p0 + t; p < p1; p += 256) {
        unsigned int pk = pairs[p];
        int loc = pk & 255;
        int s = pk >> 8;
        int pos = atomicAdd(&cur[loc], 1);
        ss[pos] = s;
    }
}

// ---------------- layer 0: aggregate pre-scaled x' (5ch), then GEMM to 128 ----------------

__global__ void k_agg5(const float* __restrict__ xs, const int* __restrict__ ss,
                       const int* __restrict__ offs, const float* __restrict__ dinv,
                       float* __restrict__ out5, int n) {
    int node = blockIdx.x * blockDim.x + threadIdx.x;
    if (node >= n) return;
    const float* xr = xs + (size_t)node * 5;
    float a0 = xr[0], a1 = xr[1], a2 = xr[2], a3 = xr[3], a4 = xr[4];
    int e1 = offs[node + 1];
    for (int e = offs[node]; e < e1; ++e) {
        int s = ss[e];
        const float* p = xs + (size_t)s * 5;
        a0 += p[0]; a1 += p[1]; a2 += p[2]; a3 += p[3]; a4 += p[4];
    }
    float dn = dinv[node];
    float* o = out5 + (size_t)node * 5;
    o[0] = a0 * dn; o[1] = a1 * dn; o[2] = a2 * dn; o[3] = a3 * dn; o[4] = a4 * dn;
}

__global__ void k_gemm0(const float* __restrict__ out5, const float* __restrict__ W0,
                        const float* __restrict__ bias0, float* __restrict__ h, int n) {
    __shared__ float w[5 * 128];
    __shared__ float b[128];
    int tid = threadIdx.x;
    for (int i = tid; i < 640; i += blockDim.x) w[i] = W0[i];
    if (tid < 128) b[tid] = bias0[tid];
    __syncthreads();
    int idx = blockIdx.x * blockDim.x + tid;
    if (idx < n * 128) {
        int node = idx >> 7, c = idx & 127;
        const float* a = out5 + (size_t)node * 5;
        float r = b[c] + a[0]*w[c] + a[1]*w[128+c] + a[2]*w[256+c]
                       + a[3]*w[384+c] + a[4]*w[512+c];
        h[idx] = r;
    }
}

// ---------------- BatchNorm ----------------

__global__ void k_bnstats(const float* __restrict__ h, float* __restrict__ part, int n) {
    int tid = threadIdx.x;
    int c = tid & 127, half = tid >> 7;
    float s = 0.f, q = 0.f;
    for (int r = blockIdx.x * 2 + half; r < n; r += gridDim.x * 2) {
        float v = h[(size_t)r * 128 + c];
        s += v; q += v * v;
    }
    part[blockIdx.x * 512 + tid] = s;
    part[blockIdx.x * 512 + 256 + tid] = q;
}

__global__ void k_bnfinal(const float* __restrict__ part, int nblocks,
                          const float* __restrict__ gamma, const float* __restrict__ beta,
                          float* __restrict__ ab, int n) {
    int c = threadIdx.x;  // 128
    float s = 0.f, q = 0.f;
    for (int b = 0; b < nblocks; ++b) {
        const float* p = part + b * 512;
        s += p[c] + p[c + 128];
        q += p[256 + c] + p[256 + c + 128];
    }
    float mean = s / n;
    float var = q / n - mean * mean;
    float inv = rsqrtf(var + BN_EPS);
    float A = gamma[c] * inv;
    ab[c] = A;
    ab[128 + c] = beta[c] - mean * A;
}

// ------- 128x128 GEMM (fp32, LDS-tiled), BN+ReLU fused on A-load,
//         epilogue: scale row by dinv[row], emit bf16 -------

__global__ __launch_bounds__(256) void k_gemm128(const float* __restrict__ A,
                                                 const float* __restrict__ W,
                                                 const float* __restrict__ ab,
                                                 const float* __restrict__ dinv,
                                                 __hip_bfloat16* __restrict__ C, int n) {
    __shared__ float As[128 * 128];
    __shared__ float Ws[128 * 128];
    int tid = threadIdx.x;
    const float4* W4 = (const float4*)W;
    for (int i = tid; i < 4096; i += 256) ((float4*)Ws)[i] = W4[i];
    int row0 = blockIdx.x * 128;
    int nrows = min(128, n - row0);
    const float4* A4 = (const float4*)(A + (size_t)row0 * 128);
    for (int i = tid; i < nrows * 32; i += 256) {
        int r = i >> 5, k4 = i & 31;
        float4 v = A4[i];
        float4 Aq = ((const float4*)ab)[k4];
        float4 Bq = ((const float4*)(ab + 128))[k4];
        v.x = fmaxf(0.f, v.x * Aq.x + Bq.x);
        v.y = fmaxf(0.f, v.y * Aq.y + Bq.y);
        v.z = fmaxf(0.f, v.z * Aq.z + Bq.z);
        v.w = fmaxf(0.f, v.w * Aq.w + Bq.w);
        int sw = ((r >> 2) & 7) << 2;
        int col = (k4 * 4) ^ sw;
        *(float4*)&As[r * 128 + col] = v;
    }
    __syncthreads();
    int rm = tid >> 3, cn = tid & 7;
    int r = rm * 4, c = cn * 16;
    float acc[4][16];
    #pragma unroll
    for (int i = 0; i < 4; ++i)
        #pragma unroll
        for (int j = 0; j < 16; ++j) acc[i][j] = 0.f;
    for (int k = 0; k < 128; k += 4) {
        float4 a[4];
        int sw = (rm & 7) << 2;
        #pragma unroll
        for (int rr = 0; rr < 4; ++rr)
            a[rr] = *(const float4*)&As[(r + rr) * 128 + (k ^ sw)];
        #pragma unroll
        for (int kk = 0; kk < 4; ++kk) {
            float4 w0 = *(const float4*)&Ws[(k + kk) * 128 + c];
            float4 w1 = *(const float4*)&Ws[(k + kk) * 128 + c + 4];
            float4 w2 = *(const float4*)&Ws[(k + kk) * 128 + c + 8];
            float4 w3 = *(const float4*)&Ws[(k + kk) * 128 + c + 12];
            #pragma unroll
            for (int rr = 0; rr < 4; ++rr) {
                float av = ((const float*)&a[rr])[kk];
                acc[rr][0] += av * w0.x; acc[rr][1] += av * w0.y;
                acc[rr][2] += av * w0.z; acc[rr][3] += av * w0.w;
                acc[rr][4] += av * w1.x; acc[rr][5] += av * w1.y;
                acc[rr][6] += av * w1.z; acc[rr][7] += av * w1.w;
                acc[rr][8] += av * w2.x; acc[rr][9] += av * w2.y;
                acc[rr][10] += av * w2.z; acc[rr][11] += av * w2.w;
                acc[rr][12] += av * w3.x; acc[rr][13] += av * w3.y;
                acc[rr][14] += av * w3.z; acc[rr][15] += av * w3.w;
            }
        }
    }
    #pragma unroll
    for (int rr = 0; rr < 4; ++rr) {
        int rrow = row0 + r + rr;
        if (rrow < n) {
            float s = dinv[rrow];
            union { unsigned int u[8]; uint4 q[2]; } pk;
            #pragma unroll
            for (int j = 0; j < 8; ++j) {
                __hip_bfloat162 b2 = __float22bfloat162_rn(
                    make_float2(acc[rr][2*j] * s, acc[rr][2*j+1] * s));
                pk.u[j] = *reinterpret_cast<unsigned int*>(&b2);
            }
            uint4* op = (uint4*)(C + (size_t)rrow * 128 + c);
            op[0] = pk.q[0]; op[1] = pk.q[1];
        }
    }
}

// ---------------- 128-ch aggregation: one wave per node, bf16 gathers, 4x unroll ----------------

__global__ void k_agg128(const unsigned int* __restrict__ hb, const int* __restrict__ ss,
                         const int* __restrict__ offs, const float* __restrict__ dinv,
                         const float* __restrict__ bias, float* __restrict__ hout, int n) {
    int wid = threadIdx.x >> 6, lane = threadIdx.x & 63;
    int node = blockIdx.x * (blockDim.x >> 6) + wid;
    if (node >= n) return;
    unsigned int self = hb[(size_t)node * 64 + lane];
    float ax = __uint_as_float(self << 16);
    float ay = __uint_as_float(self & 0xffff0000u);
    int e = offs[node], e1 = offs[node + 1];
    for (; e + 4 <= e1; e += 4) {
        int s0 = ss[e], s1 = ss[e + 1], s2 = ss[e + 2], s3 = ss[e + 3];
        unsigned int v0 = hb[(size_t)s0 * 64 + lane];
        unsigned int v1 = hb[(size_t)s1 * 64 + lane];
        unsigned int v2 = hb[(size_t)s2 * 64 + lane];
        unsigned int v3 = hb[(size_t)s3 * 64 + lane];
        ax += __uint_as_float(v0 << 16); ay += __uint_as_float(v0 & 0xffff0000u);
        ax += __uint_as_float(v1 << 16); ay += __uint_as_float(v1 & 0xffff0000u);
        ax += __uint_as_float(v2 << 16); ay += __uint_as_float(v2 & 0xffff0000u);
        ax += __uint_as_float(v3 << 16); ay += __uint_as_float(v3 & 0xffff0000u);
    }
    for (; e < e1; ++e) {
        unsigned int v = hb[(size_t)ss[e] * 64 + lane];
        ax += __uint_as_float(v << 16);
        ay += __uint_as_float(v & 0xffff0000u);
    }
    float dn = dinv[node];
    float2 b = ((const float2*)bias)[lane];
    float2 o; o.x = ax * dn + b.x; o.y = ay * dn + b.y;
    ((float2*)hout)[(size_t)node * 64 + lane] = o;
}

// ---------------- pooling + head ----------------

__global__ void k_zero_pool(float* __restrict__ gsum) {
    int i = blockIdx.x * blockDim.x + threadIdx.x;
    if (i < 64 * 128) gsum[i] = 0.f;
}

__global__ void k_bounds(const int* __restrict__ batch, int* __restrict__ gcnt, int n) {
    __shared__ int b[65];
    int g = threadIdx.x;
    if (g <= 64) {
        int lo = 0, hi = n;
        while (lo < hi) {
            int mid = (lo + hi) >> 1;
            if (batch[mid] < g) lo = mid + 1; else hi = mid;
        }
        b[g] = lo;
    }
    __syncthreads();
    if (g < 64) gcnt[g] = b[g + 1] - b[g];
}

__global__ void k_pool(const float* __restrict__ h, const int* __restrict__ batch,
                       const float* __restrict__ ab, float* __restrict__ gsum,
                       int n, int rows_per_block) {
    int tid = threadIdx.x; int c = tid & 127; int half = tid >> 7;
    int r0 = blockIdx.x * rows_per_block;
    int r1 = min(r0 + rows_per_block, n);
    int half_len = rows_per_block >> 1;
    int rs = r0 + half * half_len;
    int re = min(rs + half_len, r1);
    float A = ab[c], B = ab[128 + c];
    float acc = 0.f; int cur = -1;
    for (int r = rs; r < re; ++r) {
        int g = batch[r];
        if (g != cur) {
            if (cur >= 0) atomicAdd(&gsum[cur * 128 + c], acc);
            acc = 0.f; cur = g;
        }
        float v = h[(size_t)r * 128 + c];
        acc += fmaxf(0.f, v * A + B);
    }
    if (cur >= 0) atomicAdd(&gsum[cur * 128 + c], acc);
}

__global__ void k_final(const float* __restrict__ gsum, const int* __restrict__ gcnt,
                        const float* __restrict__ embW, const float* __restrict__ embb,
                        float* __restrict__ out) {
    __shared__ float row[128];
    int g = blockIdx.x, j = threadIdx.x;  // 64 threads
    float invc = 1.f / fmaxf((float)gcnt[g], 1.f);
    for (int i = j; i < 128; i += 64) row[i] = gsum[g * 128 + i] * invc;
    __syncthreads();
    float acc = embb[j];
    for (int cdx = 0; cdx < 128; ++cdx) acc += row[cdx] * embW[cdx * 64 + j];
    out[g * 64 + j] = acc;
}

// ---------------- launch ----------------

extern "C" void kernel_launch(void* const* d_in, const int* in_sizes, int n_in,
                              void* d_out, int out_size, void* d_ws, size_t ws_size,
                              hipStream_t stream) {
    const float* x     = (const float*)d_in[0];
    const float* W0    = (const float*)d_in[1];
    const float* Wh    = (const float*)d_in[2];
    const float* bias  = (const float*)d_in[3];
    const float* gamma = (const float*)d_in[4];
    const float* beta  = (const float*)d_in[5];
    const float* embW  = (const float*)d_in[6];
    const float* embb  = (const float*)d_in[7];
    const int*   ei    = (const int*)d_in[8];
    const int*   batch = (const int*)d_in[9];
    int N = in_sizes[9];
    int E = in_sizes[8] / 2;
    const int* src = ei;
    const int* dst = ei + E;
    int B = (N + 255) >> 8;  // buckets of 256 nodes

    char* w = (char*)d_ws;
    size_t off = 0;
    auto carve = [&](size_t bytes) {
        char* p = w + off;
        off = (off + bytes + 255) & ~(size_t)255;
        return (void*)p;
    };
    float* dinv   = (float*)carve((size_t)N * 4);
    int*   indeg  = (int*)carve((size_t)N * 4);
    int*   offs   = (int*)carve((size_t)(N + 1) * 4);
    int*   ss     = (int*)carve((size_t)E * 4);
    unsigned int* pairs = (unsigned int*)carve((size_t)E * 4);
    int*   hist   = (int*)carve((size_t)B * 256 * 4);
    int*   sbase  = (int*)carve(((size_t)B * 256 + 1) * 4);
    float* out5   = (float*)carve((size_t)N * 5 * 4);
    float* xs     = (float*)carve((size_t)N * 5 * 4);
    float* hA     = (float*)carve((size_t)N * 128 * 4);
    __hip_bfloat16* hB = (__hip_bfloat16*)carve((size_t)N * 128 * 2);
    float* part   = (float*)carve(256 * 512 * 4);
    float* ab     = (float*)carve(256 * 4);
    float* gsum   = (float*)carve(64 * 128 * 4);
    int*   gcnt   = (int*)carve(64 * 4);
    int*   tsum   = (int*)carve(65536 * 4);
    int*   bsum   = (int*)carve(256 * 4);
    int*   bbase  = (int*)carve(257 * 4);
    (void)ws_size; (void)n_in; (void)out_size;

    int nb = (N + 255) / 256;
    int gb = (N + 127) / 128;
    int ab4 = (N + 3) / 4;
    int echunk = (E + 255) / 256;
    int ctN = (N + 65535) / 65536;
    int nH = B * 256;
    int ctH = (nH + 65535) / 65536;

    // graph prep: bucket histogram -> scan -> scatter pairs -> degrees -> offs -> fine CSR
    k_hist<<<256, 256, 0, stream>>>(dst, hist, E, B, echunk);
    g_scan1<<<256, 256, 0, stream>>>(hist, tsum, bsum, nH, ctH);
    g_scan2<<<1, 256, 0, stream>>>(bsum, bbase);
    g_scan3<<<256, 256, 0, stream>>>(hist, tsum, bbase, sbase, nH, ctH);
    k_scatter<<<256, 256, 0, stream>>>(src, dst, sbase, pairs, E, B, echunk);
    k_degcnt<<<B, 256, 0, stream>>>(pairs, sbase, x, dinv, xs, indeg, N);
    g_scan1<<<256, 256, 0, stream>>>(indeg, tsum, bsum, N, ctN);
    g_scan2<<<1, 256, 0, stream>>>(bsum, bbase);
    g_scan3<<<256, 256, 0, stream>>>(indeg, tsum, bbase, offs, N, ctN);
    k_finecsr<<<B, 256, 0, stream>>>(pairs, sbase, offs, ss, N);

    // layer 0
    k_agg5<<<nb, 256, 0, stream>>>(xs, ss, offs, dinv, out5, N);
    k_gemm0<<<(N * 128 + 255) / 256, 256, 0, stream>>>(out5, W0, bias, hA, N);
    k_bnstats<<<256, 256, 0, stream>>>(hA, part, N);
    k_bnfinal<<<1, 128, 0, stream>>>(part, 256, gamma, beta, ab, N);

    // layer 1
    k_gemm128<<<gb, 256, 0, stream>>>(hA, Wh, ab, dinv, hB, N);
    k_agg128<<<ab4, 256, 0, stream>>>((const unsigned int*)hB, ss, offs, dinv, bias + 128, hA, N);
    k_bnstats<<<256, 256, 0, stream>>>(hA, part, N);
    k_bnfinal<<<1, 128, 0, stream>>>(part, 256, gamma + 128, beta + 128, ab, N);

    // layer 2
    k_gemm128<<<gb, 256, 0, stream>>>(hA, Wh + 128 * 128, ab, dinv, hB, N);
    k_agg128<<<ab4, 256, 0, stream>>>((const unsigned int*)hB, ss, offs, dinv, bias + 256, hA, N);
    k_bnstats<<<256, 256, 0, stream>>>(hA, part, N);
    k_bnfinal<<<1, 128, 0, stream>>>(part, 256, gamma + 256, beta + 256, ab, N);

    // pool (fuses layer-2 BN+ReLU) + head
    k_zero_pool<<<(64 * 128 + 255) / 256, 256, 0, stream>>>(gsum);
    k_bounds<<<1, 128, 0, stream>>>(batch, gcnt, N);
    int rpb = 512;
    k_pool<<<(N + rpb - 1) / rpb, 256, 0, stream>>>(hA, batch, ab, gsum, N, rpb);
    k_final<<<64, 64, 0, stream>>>(gsum, gcnt, embW, embb, (float*)d_out);
}

// Round 7
// 1025.784 us; speedup vs baseline: 2.5708x; 1.1165x over previous
//
#include <hip/hip_runtime.h>
#include <hip/hip_bf16.h>

constexpr float BN_EPS = 1e-5f;
typedef __attribute__((ext_vector_type(8))) short short8;
typedef __attribute__((ext_vector_type(4))) float f32x4;

// ---------------- graph preprocessing ----------------

// per-(bucket,block) histogram of dst (LDS atomics only, no global atomics)
__global__ void k_hist(const int* __restrict__ dst, int* __restrict__ hist,
                       int E, int B, int chunk) {
    __shared__ int lh[512];
    int t = threadIdx.x, blk = blockIdx.x;
    for (int i = t; i < 512; i += 256) lh[i] = 0;
    __syncthreads();
    int e0 = blk * chunk, e1 = min(E, e0 + chunk);
    for (int e = e0 + t; e < e1; e += 256) {
        atomicAdd(&lh[dst[e] >> 8], 1);
    }
    __syncthreads();
    for (int b = t; b < B; b += 256) hist[b * 256 + blk] = lh[b];
}

// ---- generic exclusive scan over int array ----

__global__ void g_scan1(const int* __restrict__ in, int* __restrict__ tsum,
                        int* __restrict__ bsum, int n, int ct) {
    int t = threadIdx.x, b = blockIdx.x;
    int i = b * 256 + t;
    int s0 = i * ct, s1 = min(n, s0 + ct);
    int s = 0;
    for (int k = s0; k < s1; ++k) s += in[k];
    tsum[i] = s;
    __shared__ int red[256];
    red[t] = s; __syncthreads();
    for (int d = 128; d > 0; d >>= 1) {
        if (t < d) red[t] += red[t + d];
        __syncthreads();
    }
    if (t == 0) bsum[b] = red[0];
}

__global__ void g_scan2(const int* __restrict__ bsum, int* __restrict__ bbase) {
    int t = threadIdx.x;  // 256
    __shared__ int sh[256];
    int v = bsum[t];
    sh[t] = v; __syncthreads();
    for (int d = 1; d < 256; d <<= 1) {
        int u = (t >= d) ? sh[t - d] : 0;
        __syncthreads();
        sh[t] += u;
        __syncthreads();
    }
    bbase[t] = sh[t] - v;  // exclusive
    if (t == 255) bbase[256] = sh[255];
}

__global__ void g_scan3(const int* __restrict__ in, const int* __restrict__ tsum,
                        const int* __restrict__ bbase, int* __restrict__ out,
                        int n, int ct) {
    int t = threadIdx.x, b = blockIdx.x;
    __shared__ int sh[256];
    int v = tsum[b * 256 + t];
    sh[t] = v; __syncthreads();
    for (int d = 1; d < 256; d <<= 1) {
        int u = (t >= d) ? sh[t - d] : 0;
        __syncthreads();
        sh[t] += u;
        __syncthreads();
    }
    int run = bbase[b] + sh[t] - v;
    int i = b * 256 + t;
    int s0 = i * ct, s1 = min(n, s0 + ct);
    for (int k = s0; k < s1; ++k) {
        out[k] = run;
        run += in[k];
    }
    if (i == 65535) out[n] = bbase[256];
}

// scatter edges into bucket-grouped pairs, block-exclusive streams
__global__ void k_scatter(const int* __restrict__ src, const int* __restrict__ dst,
                          const int* __restrict__ sbase, unsigned int* __restrict__ pairs,
                          int E, int B, int chunk) {
    __shared__ int cur[512];
    int t = threadIdx.x, blk = blockIdx.x;
    for (int b = t; b < B; b += 256) cur[b] = sbase[b * 256 + blk];
    __syncthreads();
    int e0 = blk * chunk, e1 = min(E, e0 + chunk);
    for (int e = e0 + t; e < e1; e += 256) {
        int d = dst[e];
        int s = src[e];
        int p = atomicAdd(&cur[d >> 8], 1);
        pairs[p] = ((unsigned int)s << 8) | (unsigned int)(d & 255);
    }
}

// per-bucket degree count from pairs (LDS atomics) + fused dinv/xs/indeg
__global__ void k_degcnt(const unsigned int* __restrict__ pairs, const int* __restrict__ sbase,
                         const float* __restrict__ x, float* __restrict__ dinv,
                         float* __restrict__ xs, int* __restrict__ indeg, int n) {
    __shared__ int lh[256];
    int t = threadIdx.x, b = blockIdx.x;
    lh[t] = 0;
    __syncthreads();
    int p0 = sbase[b * 256];
    int p1 = sbase[b * 256 + 256];
    for (int p = p0 + t; p < p1; p += 256) {
        atomicAdd(&lh[pairs[p] & 255], 1);
    }
    __syncthreads();
    int node = b * 256 + t;
    if (node < n) {
        int cnt = lh[t];
        indeg[node] = cnt;
        float d = rsqrtf((float)(cnt + 1));  // +1 self loop
        dinv[node] = d;
        const float* xr = x + (size_t)node * 5;
        float* o = xs + (size_t)node * 5;
        #pragma unroll
        for (int j = 0; j < 5; ++j) o[j] = xr[j] * d;
    }
}

// per-bucket fine CSR fill: ss region is L2-resident
__global__ void k_finecsr(const unsigned int* __restrict__ pairs, const int* __restrict__ sbase,
                          const int* __restrict__ offs, int* __restrict__ ss, int n) {
    __shared__ int cur[256];
    int t = threadIdx.x, b = blockIdx.x;
    int lo = b * 256;
    int cnt = min(256, n - lo);
    if (t < cnt) cur[t] = offs[lo + t];
    __syncthreads();
    int p0 = sbase[b * 256];
    int p1 = sbase[b * 256 + 256];
    for (int p = p0 + t; p < p1; p += 256) {
        unsigned int pk = pairs[p];
        int loc = pk & 255;
        int s = pk >> 8;
        int pos = atomicAdd(&cur[loc], 1);
        ss[pos] = s;
    }
}

// ---------------- layer 0: aggregate pre-scaled x' (5ch), then GEMM to 128 ----------------

__global__ void k_agg5(const float* __restrict__ xs, const int* __restrict__ ss,
                       const int* __restrict__ offs, const float* __restrict__ dinv,
                       float* __restrict__ out5, int n) {
    int node = blockIdx.x * blockDim.x + threadIdx.x;
    if (node >= n) return;
    const float* xr = xs + (size_t)node * 5;
    float a0 = xr[0], a1 = xr[1], a2 = xr[2], a3 = xr[3], a4 = xr[4];
    int e1 = offs[node + 1];
    for (int e = offs[node]; e < e1; ++e) {
        int s = ss[e];
        const float* p = xs + (size_t)s * 5;
        a0 += p[0]; a1 += p[1]; a2 += p[2]; a3 += p[3]; a4 += p[4];
    }
    float dn = dinv[node];
    float* o = out5 + (size_t)node * 5;
    o[0] = a0 * dn; o[1] = a1 * dn; o[2] = a2 * dn; o[3] = a3 * dn; o[4] = a4 * dn;
}

__global__ void k_gemm0(const float* __restrict__ out5, const float* __restrict__ W0,
                        const float* __restrict__ bias0, float* __restrict__ h, int n) {
    __shared__ float w[5 * 128];
    __shared__ float b[128];
    int tid = threadIdx.x;
    for (int i = tid; i < 640; i += blockDim.x) w[i] = W0[i];
    if (tid < 128) b[tid] = bias0[tid];
    __syncthreads();
    int idx = blockIdx.x * blockDim.x + tid;
    if (idx < n * 128) {
        int node = idx >> 7, c = idx & 127;
        const float* a = out5 + (size_t)node * 5;
        float r = b[c] + a[0]*w[c] + a[1]*w[128+c] + a[2]*w[256+c]
                       + a[3]*w[384+c] + a[4]*w[512+c];
        h[idx] = r;
    }
}

// ---------------- BatchNorm ----------------

__global__ void k_bnstats(const float* __restrict__ h, float* __restrict__ part, int n) {
    int tid = threadIdx.x;
    int c = tid & 127, half = tid >> 7;
    float s = 0.f, q = 0.f;
    for (int r = blockIdx.x * 2 + half; r < n; r += gridDim.x * 2) {
        float v = h[(size_t)r * 128 + c];
        s += v; q += v * v;
    }
    part[blockIdx.x * 512 + tid] = s;
    part[blockIdx.x * 512 + 256 + tid] = q;
}

__global__ void k_bnfinal(const float* __restrict__ part, int nblocks,
                          const float* __restrict__ gamma, const float* __restrict__ beta,
                          float* __restrict__ ab, int n) {
    int c = threadIdx.x;  // 128
    float s = 0.f, q = 0.f;
    for (int b = 0; b < nblocks; ++b) {
        const float* p = part + b * 512;
        s += p[c] + p[c + 128];
        q += p[256 + c] + p[256 + c + 128];
    }
    float mean = s / n;
    float var = q / n - mean * mean;
    float inv = rsqrtf(var + BN_EPS);
    float A = gamma[c] * inv;
    ab[c] = A;
    ab[128 + c] = beta[c] - mean * A;
}

// ------- MFMA bf16 GEMM: [n x 128] @ [128 x 128], BN+ReLU fused on A-load,
//         epilogue: scale row by dinv[row], emit bf16.
//         LDS: A bf16 swizzled [row][k] 32KB + W^T bf16 swizzled [col][k] 32KB -------

__global__ __launch_bounds__(256) void k_gemm128(const float* __restrict__ A,
                                                 const float* __restrict__ W,
                                                 const float* __restrict__ ab,
                                                 const float* __restrict__ dinv,
                                                 __hip_bfloat16* __restrict__ C, int n) {
    __shared__ uint4 AsU[2048];   // 32 KiB: As[row][k] bf16, byte ^= (row&7)<<4
    __shared__ uint4 WsU[2048];   // 32 KiB: Wt[col][k] bf16, byte ^= (col&7)<<4
    char* Asb = (char*)AsU;
    char* Wsb = (char*)WsU;
    int tid = threadIdx.x;
    int row0 = blockIdx.x * 128;

    // stage W -> W^T bf16 (coalesced read, scalar transposed LDS writes)
    const float4* W4 = (const float4*)W;
    for (int i = tid; i < 4096; i += 256) {
        float4 wv = W4[i];
        int k = i >> 5;
        int colq = (i & 31) << 2;
        #pragma unroll
        for (int j = 0; j < 4; ++j) {
            int col = colq + j;
            int byte = col * 256 + ((((k & ~7) * 2) ^ ((col & 7) << 4)) | ((k & 7) * 2));
            *(__hip_bfloat16*)(Wsb + byte) = __float2bfloat16((&wv.x)[j]);
        }
    }
    // stage A with BN+ReLU -> bf16 swizzled (16B granules)
    const float4* ab4 = (const float4*)ab;
    for (int g = tid; g < 2048; g += 256) {
        int r = g >> 4, kg = g & 15;
        int grow = row0 + r;
        uint4 pack = make_uint4(0, 0, 0, 0);
        if (grow < n) {
            const float4* Arow = (const float4*)(A + (size_t)grow * 128);
            float4 v0 = Arow[kg * 2], v1 = Arow[kg * 2 + 1];
            float4 A0 = ab4[kg * 2], A1 = ab4[kg * 2 + 1];
            float4 B0 = ab4[32 + kg * 2], B1 = ab4[32 + kg * 2 + 1];
            float f[8];
            f[0] = fmaxf(0.f, v0.x * A0.x + B0.x);
            f[1] = fmaxf(0.f, v0.y * A0.y + B0.y);
            f[2] = fmaxf(0.f, v0.z * A0.z + B0.z);
            f[3] = fmaxf(0.f, v0.w * A0.w + B0.w);
            f[4] = fmaxf(0.f, v1.x * A1.x + B1.x);
            f[5] = fmaxf(0.f, v1.y * A1.y + B1.y);
            f[6] = fmaxf(0.f, v1.z * A1.z + B1.z);
            f[7] = fmaxf(0.f, v1.w * A1.w + B1.w);
            unsigned int* pu = (unsigned int*)&pack;
            #pragma unroll
            for (int j = 0; j < 4; ++j) {
                __hip_bfloat162 b2 = __float22bfloat162_rn(make_float2(f[2 * j], f[2 * j + 1]));
                pu[j] = *reinterpret_cast<unsigned int*>(&b2);
            }
        }
        int byte = r * 256 + ((kg << 4) ^ ((r & 7) << 4));
        *(uint4*)(Asb + byte) = pack;
    }
    __syncthreads();

    int wv_ = tid >> 6, lane = tid & 63;
    int wr = wv_ * 32;                 // wave's 32-row slice
    int lrow = lane & 15, lk = lane >> 4;
    f32x4 acc[2][8];
    #pragma unroll
    for (int m = 0; m < 2; ++m)
        #pragma unroll
        for (int nf = 0; nf < 8; ++nf) acc[m][nf] = (f32x4)(0.f);

    #pragma unroll
    for (int kk = 0; kk < 4; ++kk) {
        int k0 = kk * 32 + lk * 8;
        int ra = wr + lrow;
        int rb = wr + 16 + lrow;
        short8 a0 = *(short8*)(Asb + ra * 256 + ((k0 * 2) ^ ((ra & 7) << 4)));
        short8 a1 = *(short8*)(Asb + rb * 256 + ((k0 * 2) ^ ((rb & 7) << 4)));
        #pragma unroll
        for (int nf = 0; nf < 8; ++nf) {
            int col = nf * 16 + lrow;
            short8 b = *(short8*)(Wsb + col * 256 + ((k0 * 2) ^ ((col & 7) << 4)));
            acc[0][nf] = __builtin_amdgcn_mfma_f32_16x16x32_bf16(a0, b, acc[0][nf], 0, 0, 0);
            acc[1][nf] = __builtin_amdgcn_mfma_f32_16x16x32_bf16(a1, b, acc[1][nf], 0, 0, 0);
        }
    }

    // epilogue: C[row][col], row = row0+wr+m*16+(lane>>4)*4+r, col = nf*16+(lane&15)
    #pragma unroll
    for (int m = 0; m < 2; ++m) {
        #pragma unroll
        for (int r = 0; r < 4; ++r) {
            int grow = row0 + wr + m * 16 + lk * 4 + r;
            if (grow < n) {
                float dv = dinv[grow];
                __hip_bfloat16* crow = C + (size_t)grow * 128 + lrow;
                #pragma unroll
                for (int nf = 0; nf < 8; ++nf) {
                    crow[nf * 16] = __float2bfloat16(acc[m][nf][r] * dv);
                }
            }
        }
    }
}

// ---------------- 128-ch aggregation: one wave per node, bf16 gathers, 4x unroll ----------------

__global__ void k_agg128(const unsigned int* __restrict__ hb, const int* __restrict__ ss,
                         const int* __restrict__ offs, const float* __restrict__ dinv,
                         const float* __restrict__ bias, float* __restrict__ hout, int n) {
    int wid = threadIdx.x >> 6, lane = threadIdx.x & 63;
    int node = blockIdx.x * (blockDim.x >> 6) + wid;
    if (node >= n) return;
    unsigned int self = hb[(size_t)node * 64 + lane];
    float ax = __uint_as_float(self << 16);
    float ay = __uint_as_float(self & 0xffff0000u);
    int e = offs[node], e1 = offs[node + 1];
    for (; e + 4 <= e1; e += 4) {
        int s0 = ss[e], s1 = ss[e + 1], s2 = ss[e + 2], s3 = ss[e + 3];
        unsigned int v0 = hb[(size_t)s0 * 64 + lane];
        unsigned int v1 = hb[(size_t)s1 * 64 + lane];
        unsigned int v2 = hb[(size_t)s2 * 64 + lane];
        unsigned int v3 = hb[(size_t)s3 * 64 + lane];
        ax += __uint_as_float(v0 << 16); ay += __uint_as_float(v0 & 0xffff0000u);
        ax += __uint_as_float(v1 << 16); ay += __uint_as_float(v1 & 0xffff0000u);
        ax += __uint_as_float(v2 << 16); ay += __uint_as_float(v2 & 0xffff0000u);
        ax += __uint_as_float(v3 << 16); ay += __uint_as_float(v3 & 0xffff0000u);
    }
    for (; e < e1; ++e) {
        unsigned int v = hb[(size_t)ss[e] * 64 + lane];
        ax += __uint_as_float(v << 16);
        ay += __uint_as_float(v & 0xffff0000u);
    }
    float dn = dinv[node];
    float2 b = ((const float2*)bias)[lane];
    float2 o; o.x = ax * dn + b.x; o.y = ay * dn + b.y;
    ((float2*)hout)[(size_t)node * 64 + lane] = o;
}

// ---------------- pooling + head ----------------

__global__ void k_zero_pool(float* __restrict__ gsum) {
    int i = blockIdx.x * blockDim.x + threadIdx.x;
    if (i < 64 * 128) gsum[i] = 0.f;
}

__global__ void k_bounds(const int* __restrict__ batch, int* __restrict__ gcnt, int n) {
    __shared__ int b[65];
    int g = threadIdx.x;
    if (g <= 64) {
        int lo = 0, hi = n;
        while (lo < hi) {
            int mid = (lo + hi) >> 1;
            if (batch[mid] < g) lo = mid + 1; else hi = mid;
        }
        b[g] = lo;
    }
    __syncthreads();
    if (g < 64) gcnt[g] = b[g + 1] - b[g];
}

__global__ void k_pool(const float* __restrict__ h, const int* __restrict__ batch,
                       const float* __restrict__ ab, float* __restrict__ gsum,
                       int n, int rows_per_block) {
    int tid = threadIdx.x; int c = tid & 127; int half = tid >> 7;
    int r0 = blockIdx.x * rows_per_block;
    int r1 = min(r0 + rows_per_block, n);
    int half_len = rows_per_block >> 1;
    int rs = r0 + half * half_len;
    int re = min(rs + half_len, r1);
    float A = ab[c], B = ab[128 + c];
    float acc = 0.f; int cur = -1;
    for (int r = rs; r < re; ++r) {
        int g = batch[r];
        if (g != cur) {
            if (cur >= 0) atomicAdd(&gsum[cur * 128 + c], acc);
            acc = 0.f; cur = g;
        }
        float v = h[(size_t)r * 128 + c];
        acc += fmaxf(0.f, v * A + B);
    }
    if (cur >= 0) atomicAdd(&gsum[cur * 128 + c], acc);
}

__global__ void k_final(const float* __restrict__ gsum, const int* __restrict__ gcnt,
                        const float* __restrict__ embW, const float* __restrict__ embb,
                        float* __restrict__ out) {
    __shared__ float row[128];
    int g = blockIdx.x, j = threadIdx.x;  // 64 threads
    float invc = 1.f / fmaxf((float)gcnt[g], 1.f);
    for (int i = j; i < 128; i += 64) row[i] = gsum[g * 128 + i] * invc;
    __syncthreads();
    float acc = embb[j];
    for (int cdx = 0; cdx < 128; ++cdx) acc += row[cdx] * embW[cdx * 64 + j];
    out[g * 64 + j] = acc;
}

// ---------------- launch ----------------

extern "C" void kernel_launch(void* const* d_in, const int* in_sizes, int n_in,
                              void* d_out, int out_size, void* d_ws, size_t ws_size,
                              hipStream_t stream) {
    const float* x     = (const float*)d_in[0];
    const float* W0    = (const float*)d_in[1];
    const float* Wh    = (const float*)d_in[2];
    const float* bias  = (const float*)d_in[3];
    const float* gamma = (const float*)d_in[4];
    const float* beta  = (const float*)d_in[5];
    const float* embW  = (const float*)d_in[6];
    const float* embb  = (const float*)d_in[7];
    const int*   ei    = (const int*)d_in[8];
    const int*   batch = (const int*)d_in[9];
    int N = in_sizes[9];
    int E = in_sizes[8] / 2;
    const int* src = ei;
    const int* dst = ei + E;
    int B = (N + 255) >> 8;  // buckets of 256 nodes

    char* w = (char*)d_ws;
    size_t off = 0;
    auto carve = [&](size_t bytes) {
        char* p = w + off;
        off = (off + bytes + 255) & ~(size_t)255;
        return (void*)p;
    };
    float* dinv   = (float*)carve((size_t)N * 4);
    int*   indeg  = (int*)carve((size_t)N * 4);
    int*   offs   = (int*)carve((size_t)(N + 1) * 4);
    int*   ss     = (int*)carve((size_t)E * 4);
    unsigned int* pairs = (unsigned int*)carve((size_t)E * 4);
    int*   hist   = (int*)carve((size_t)B * 256 * 4);
    int*   sbase  = (int*)carve(((size_t)B * 256 + 1) * 4);
    float* out5   = (float*)carve((size_t)N * 5 * 4);
    float* xs     = (float*)carve((size_t)N * 5 * 4);
    float* hA     = (float*)carve((size_t)N * 128 * 4);
    __hip_bfloat16* hB = (__hip_bfloat16*)carve((size_t)N * 128 * 2);
    float* part   = (float*)carve(256 * 512 * 4);
    float* ab     = (float*)carve(256 * 4);
    float* gsum   = (float*)carve(64 * 128 * 4);
    int*   gcnt   = (int*)carve(64 * 4);
    int*   tsum   = (int*)carve(65536 * 4);
    int*   bsum   = (int*)carve(256 * 4);
    int*   bbase  = (int*)carve(257 * 4);
    (void)ws_size; (void)n_in; (void)out_size;

    int nb = (N + 255) / 256;
    int gb = (N + 127) / 128;
    int ab4 = (N + 3) / 4;
    int echunk = (E + 255) / 256;
    int ctN = (N + 65535) / 65536;
    int nH = B * 256;
    int ctH = (nH + 65535) / 65536;

    // graph prep: bucket histogram -> scan -> scatter pairs -> degrees -> offs -> fine CSR
    k_hist<<<256, 256, 0, stream>>>(dst, hist, E, B, echunk);
    g_scan1<<<256, 256, 0, stream>>>(hist, tsum, bsum, nH, ctH);
    g_scan2<<<1, 256, 0, stream>>>(bsum, bbase);
    g_scan3<<<256, 256, 0, stream>>>(hist, tsum, bbase, sbase, nH, ctH);
    k_scatter<<<256, 256, 0, stream>>>(src, dst, sbase, pairs, E, B, echunk);
    k_degcnt<<<B, 256, 0, stream>>>(pairs, sbase, x, dinv, xs, indeg, N);
    g_scan1<<<256, 256, 0, stream>>>(indeg, tsum, bsum, N, ctN);
    g_scan2<<<1, 256, 0, stream>>>(bsum, bbase);
    g_scan3<<<256, 256, 0, stream>>>(indeg, tsum, bbase, offs, N, ctN);
    k_finecsr<<<B, 256, 0, stream>>>(pairs, sbase, offs, ss, N);

    // layer 0
    k_agg5<<<nb, 256, 0, stream>>>(xs, ss, offs, dinv, out5, N);
    k_gemm0<<<(N * 128 + 255) / 256, 256, 0, stream>>>(out5, W0, bias, hA, N);
    k_bnstats<<<256, 256, 0, stream>>>(hA, part, N);
    k_bnfinal<<<1, 128, 0, stream>>>(part, 256, gamma, beta, ab, N);

    // layer 1
    k_gemm128<<<gb, 256, 0, stream>>>(hA, Wh, ab, dinv, hB, N);
    k_agg128<<<ab4, 256, 0, stream>>>((const unsigned int*)hB, ss, offs, dinv, bias + 128, hA, N);
    k_bnstats<<<256, 256, 0, stream>>>(hA, part, N);
    k_bnfinal<<<1, 128, 0, stream>>>(part, 256, gamma + 128, beta + 128, ab, N);

    // layer 2
    k_gemm128<<<gb, 256, 0, stream>>>(hA, Wh + 128 * 128, ab, dinv, hB, N);
    k_agg128<<<ab4, 256, 0, stream>>>((const unsigned int*)hB, ss, offs, dinv, bias + 256, hA, N);
    k_bnstats<<<256, 256, 0, stream>>>(hA, part, N);
    k_bnfinal<<<1, 128, 0, stream>>>(part, 256, gamma + 256, beta + 256, ab, N);

    // pool (fuses layer-2 BN+ReLU) + head
    k_zero_pool<<<(64 * 128 + 255) / 256, 256, 0, stream>>>(gsum);
    k_bounds<<<1, 128, 0, stream>>>(batch, gcnt, N);
    int rpb = 512;
    k_pool<<<(N + rpb - 1) / rpb, 256, 0, stream>>>(hA, batch, ab, gsum, N, rpb);
    k_final<<<64, 64, 0, stream>>>(gsum, gcnt, embW, embb, (float*)d_out);
}

// Round 8
// 982.045 us; speedup vs baseline: 2.6853x; 1.0445x over previous
//
#include <hip/hip_runtime.h>
#include <hip/hip_bf16.h>

constexpr float BN_EPS = 1e-5f;
typedef __attribute__((ext_vector_type(8))) short short8;
typedef __attribute__((ext_vector_type(4))) float f32x4;

// ---------------- graph preprocessing ----------------

// per-(bucket,block) histogram of dst (LDS atomics only, no global atomics)
__global__ void k_hist(const int* __restrict__ dst, int* __restrict__ hist,
                       int E, int B, int chunk) {
    __shared__ int lh[512];
    int t = threadIdx.x, blk = blockIdx.x;
    for (int i = t; i < 512; i += 256) lh[i] = 0;
    __syncthreads();
    int e0 = blk * chunk, e1 = min(E, e0 + chunk);
    for (int e = e0 + t; e < e1; e += 256) {
        atomicAdd(&lh[dst[e] >> 8], 1);
    }
    __syncthreads();
    for (int b = t; b < B; b += 256) hist[b * 256 + blk] = lh[b];
}

// ---- generic exclusive scan over int array (used for the (bucket,block) hist) ----

__global__ void g_scan1(const int* __restrict__ in, int* __restrict__ tsum,
                        int* __restrict__ bsum, int n, int ct) {
    int t = threadIdx.x, b = blockIdx.x;
    int i = b * 256 + t;
    int s0 = i * ct, s1 = min(n, s0 + ct);
    int s = 0;
    for (int k = s0; k < s1; ++k) s += in[k];
    tsum[i] = s;
    __shared__ int red[256];
    red[t] = s; __syncthreads();
    for (int d = 128; d > 0; d >>= 1) {
        if (t < d) red[t] += red[t + d];
        __syncthreads();
    }
    if (t == 0) bsum[b] = red[0];
}

__global__ void g_scan2(const int* __restrict__ bsum, int* __restrict__ bbase) {
    int t = threadIdx.x;  // 256
    __shared__ int sh[256];
    int v = bsum[t];
    sh[t] = v; __syncthreads();
    for (int d = 1; d < 256; d <<= 1) {
        int u = (t >= d) ? sh[t - d] : 0;
        __syncthreads();
        sh[t] += u;
        __syncthreads();
    }
    bbase[t] = sh[t] - v;  // exclusive
    if (t == 255) bbase[256] = sh[255];
}

__global__ void g_scan3(const int* __restrict__ in, const int* __restrict__ tsum,
                        const int* __restrict__ bbase, int* __restrict__ out,
                        int n, int ct) {
    int t = threadIdx.x, b = blockIdx.x;
    __shared__ int sh[256];
    int v = tsum[b * 256 + t];
    sh[t] = v; __syncthreads();
    for (int d = 1; d < 256; d <<= 1) {
        int u = (t >= d) ? sh[t - d] : 0;
        __syncthreads();
        sh[t] += u;
        __syncthreads();
    }
    int run = bbase[b] + sh[t] - v;
    int i = b * 256 + t;
    int s0 = i * ct, s1 = min(n, s0 + ct);
    for (int k = s0; k < s1; ++k) {
        out[k] = run;
        run += in[k];
    }
    if (i == 65535) out[n] = bbase[256];
}

// scatter edges into bucket-grouped pairs, block-exclusive streams
__global__ void k_scatter(const int* __restrict__ src, const int* __restrict__ dst,
                          const int* __restrict__ sbase, unsigned int* __restrict__ pairs,
                          int E, int B, int chunk) {
    __shared__ int cur[512];
    int t = threadIdx.x, blk = blockIdx.x;
    for (int b = t; b < B; b += 256) cur[b] = sbase[b * 256 + blk];
    __syncthreads();
    int e0 = blk * chunk, e1 = min(E, e0 + chunk);
    for (int e = e0 + t; e < e1; e += 256) {
        int d = dst[e];
        int s = src[e];
        int p = atomicAdd(&cur[d >> 8], 1);
        pairs[p] = ((unsigned int)s << 8) | (unsigned int)(d & 255);
    }
}

// one block per bucket: local degrees (LDS hist) -> LDS scan -> offs/dinv/xs(+pad8)
// then fill ss from pairs (second pass hits warm L2)
__global__ void k_bucket(const unsigned int* __restrict__ pairs, const int* __restrict__ sbase,
                         const float* __restrict__ x, float* __restrict__ dinv,
                         float* __restrict__ xs, int* __restrict__ offs,
                         int* __restrict__ ss, int n) {
    __shared__ int sh[256];
    __shared__ int cur[256];
    int t = threadIdx.x, b = blockIdx.x;
    int p0 = sbase[b * 256];
    int p1 = sbase[b * 256 + 256];
    sh[t] = 0;
    __syncthreads();
    for (int p = p0 + t; p < p1; p += 256) {
        atomicAdd(&sh[pairs[p] & 255], 1);
    }
    __syncthreads();
    int cnt = sh[t];
    __syncthreads();
    sh[t] = cnt; __syncthreads();
    for (int d = 1; d < 256; d <<= 1) {
        int u = (t >= d) ? sh[t - d] : 0;
        __syncthreads();
        sh[t] += u;
        __syncthreads();
    }
    int excl = sh[t] - cnt;
    int node = b * 256 + t;
    if (node < n) {
        offs[node] = p0 + excl;
        if (node == n - 1) offs[n] = p0 + excl + cnt;
        float d = rsqrtf((float)(cnt + 1));  // +1 self loop
        dinv[node] = d;
        const float* xr = x + (size_t)node * 5;
        float* o = xs + (size_t)node * 8;
        #pragma unroll
        for (int j = 0; j < 5; ++j) o[j] = xr[j] * d;
        o[5] = 0.f; o[6] = 0.f; o[7] = 0.f;
    }
    cur[t] = p0 + excl;
    __syncthreads();
    for (int p = p0 + t; p < p1; p += 256) {
        unsigned int pk = pairs[p];
        int pos = atomicAdd(&cur[pk & 255], 1);
        ss[pos] = pk >> 8;
    }
}

// ---------------- layer 0: aggregate pre-scaled x' (5ch, padded to 8), GEMM to 128 ----------------

__global__ void k_agg5(const float* __restrict__ xs, const int* __restrict__ ss,
                       const int* __restrict__ offs, const float* __restrict__ dinv,
                       float* __restrict__ out5, int n) {
    int node = blockIdx.x * blockDim.x + threadIdx.x;
    if (node >= n) return;
    const float* xr = xs + (size_t)node * 8;
    float a0 = xr[0], a1 = xr[1], a2 = xr[2], a3 = xr[3], a4 = xr[4];
    int e = offs[node], e1 = offs[node + 1];
    for (; e + 2 <= e1; e += 2) {
        int s0 = ss[e], s1 = ss[e + 1];
        const float4* q0 = (const float4*)(xs + (size_t)s0 * 8);
        const float4* q1 = (const float4*)(xs + (size_t)s1 * 8);
        float4 v0 = q0[0]; float w0 = xs[(size_t)s0 * 8 + 4];
        float4 v1 = q1[0]; float w1 = xs[(size_t)s1 * 8 + 4];
        a0 += v0.x + v1.x; a1 += v0.y + v1.y; a2 += v0.z + v1.z;
        a3 += v0.w + v1.w; a4 += w0 + w1;
    }
    for (; e < e1; ++e) {
        int s = ss[e];
        const float4* q = (const float4*)(xs + (size_t)s * 8);
        float4 v = q[0];
        a0 += v.x; a1 += v.y; a2 += v.z; a3 += v.w; a4 += xs[(size_t)s * 8 + 4];
    }
    float dn = dinv[node];
    float* o = out5 + (size_t)node * 5;
    o[0] = a0 * dn; o[1] = a1 * dn; o[2] = a2 * dn; o[3] = a3 * dn; o[4] = a4 * dn;
}

__global__ void k_gemm0(const float* __restrict__ out5, const float* __restrict__ W0,
                        const float* __restrict__ bias0, float* __restrict__ h, int n) {
    __shared__ float w[5 * 128];
    __shared__ float b[128];
    int tid = threadIdx.x;
    for (int i = tid; i < 640; i += blockDim.x) w[i] = W0[i];
    if (tid < 128) b[tid] = bias0[tid];
    __syncthreads();
    int idx = blockIdx.x * blockDim.x + tid;
    if (idx < n * 128) {
        int node = idx >> 7, c = idx & 127;
        const float* a = out5 + (size_t)node * 5;
        float r = b[c] + a[0]*w[c] + a[1]*w[128+c] + a[2]*w[256+c]
                       + a[3]*w[384+c] + a[4]*w[512+c];
        h[idx] = r;
    }
}

// ---------------- BatchNorm ----------------

__global__ void k_bnstats(const float* __restrict__ h, float* __restrict__ part, int n) {
    int tid = threadIdx.x;
    int c = tid & 127, half = tid >> 7;
    float s = 0.f, q = 0.f;
    for (int r = blockIdx.x * 2 + half; r < n; r += gridDim.x * 2) {
        float v = h[(size_t)r * 128 + c];
        s += v; q += v * v;
    }
    part[blockIdx.x * 512 + tid] = s;
    part[blockIdx.x * 512 + 256 + tid] = q;
}

__global__ void k_bnfinal(const float* __restrict__ part, int nblocks,
                          const float* __restrict__ gamma, const float* __restrict__ beta,
                          float* __restrict__ ab, int n) {
    int c = threadIdx.x;  // 128
    float s = 0.f, q = 0.f;
    for (int b = 0; b < nblocks; ++b) {
        const float* p = part + b * 512;
        s += p[c] + p[c + 128];
        q += p[256 + c] + p[256 + c + 128];
    }
    float mean = s / n;
    float var = q / n - mean * mean;
    float inv = rsqrtf(var + BN_EPS);
    float A = gamma[c] * inv;
    ab[c] = A;
    ab[128 + c] = beta[c] - mean * A;
}

// ------- MFMA bf16 GEMM: [n x 128] @ [128 x 128], BN+ReLU fused on A-load,
//         epilogue: scale row by dinv[row], emit bf16 -------

__global__ __launch_bounds__(256) void k_gemm128(const float* __restrict__ A,
                                                 const float* __restrict__ W,
                                                 const float* __restrict__ ab,
                                                 const float* __restrict__ dinv,
                                                 __hip_bfloat16* __restrict__ C, int n) {
    __shared__ uint4 AsU[2048];   // 32 KiB: As[row][k] bf16, byte ^= (row&7)<<4
    __shared__ uint4 WsU[2048];   // 32 KiB: Wt[col][k] bf16, byte ^= (col&7)<<4
    char* Asb = (char*)AsU;
    char* Wsb = (char*)WsU;
    int tid = threadIdx.x;
    int row0 = blockIdx.x * 128;

    const float4* W4 = (const float4*)W;
    for (int i = tid; i < 4096; i += 256) {
        float4 wv = W4[i];
        int k = i >> 5;
        int colq = (i & 31) << 2;
        #pragma unroll
        for (int j = 0; j < 4; ++j) {
            int col = colq + j;
            int byte = col * 256 + ((((k & ~7) * 2) ^ ((col & 7) << 4)) | ((k & 7) * 2));
            *(__hip_bfloat16*)(Wsb + byte) = __float2bfloat16((&wv.x)[j]);
        }
    }
    const float4* ab4 = (const float4*)ab;
    for (int g = tid; g < 2048; g += 256) {
        int r = g >> 4, kg = g & 15;
        int grow = row0 + r;
        uint4 pack = make_uint4(0, 0, 0, 0);
        if (grow < n) {
            const float4* Arow = (const float4*)(A + (size_t)grow * 128);
            float4 v0 = Arow[kg * 2], v1 = Arow[kg * 2 + 1];
            float4 A0 = ab4[kg * 2], A1 = ab4[kg * 2 + 1];
            float4 B0 = ab4[32 + kg * 2], B1 = ab4[32 + kg * 2 + 1];
            float f[8];
            f[0] = fmaxf(0.f, v0.x * A0.x + B0.x);
            f[1] = fmaxf(0.f, v0.y * A0.y + B0.y);
            f[2] = fmaxf(0.f, v0.z * A0.z + B0.z);
            f[3] = fmaxf(0.f, v0.w * A0.w + B0.w);
            f[4] = fmaxf(0.f, v1.x * A1.x + B1.x);
            f[5] = fmaxf(0.f, v1.y * A1.y + B1.y);
            f[6] = fmaxf(0.f, v1.z * A1.z + B1.z);
            f[7] = fmaxf(0.f, v1.w * A1.w + B1.w);
            unsigned int* pu = (unsigned int*)&pack;
            #pragma unroll
            for (int j = 0; j < 4; ++j) {
                __hip_bfloat162 b2 = __float22bfloat162_rn(make_float2(f[2 * j], f[2 * j + 1]));
                pu[j] = *reinterpret_cast<unsigned int*>(&b2);
            }
        }
        int byte = r * 256 + ((kg << 4) ^ ((r & 7) << 4));
        *(uint4*)(Asb + byte) = pack;
    }
    __syncthreads();

    int wv_ = tid >> 6, lane = tid & 63;
    int wr = wv_ * 32;
    int lrow = lane & 15, lk = lane >> 4;
    f32x4 acc[2][8];
    #pragma unroll
    for (int m = 0; m < 2; ++m)
        #pragma unroll
        for (int nf = 0; nf < 8; ++nf) acc[m][nf] = (f32x4)(0.f);

    #pragma unroll
    for (int kk = 0; kk < 4; ++kk) {
        int k0 = kk * 32 + lk * 8;
        int ra = wr + lrow;
        int rb = wr + 16 + lrow;
        short8 a0 = *(short8*)(Asb + ra * 256 + ((k0 * 2) ^ ((ra & 7) << 4)));
        short8 a1 = *(short8*)(Asb + rb * 256 + ((k0 * 2) ^ ((rb & 7) << 4)));
        #pragma unroll
        for (int nf = 0; nf < 8; ++nf) {
            int col = nf * 16 + lrow;
            short8 b = *(short8*)(Wsb + col * 256 + ((k0 * 2) ^ ((col & 7) << 4)));
            acc[0][nf] = __builtin_amdgcn_mfma_f32_16x16x32_bf16(a0, b, acc[0][nf], 0, 0, 0);
            acc[1][nf] = __builtin_amdgcn_mfma_f32_16x16x32_bf16(a1, b, acc[1][nf], 0, 0, 0);
        }
    }

    #pragma unroll
    for (int m = 0; m < 2; ++m) {
        #pragma unroll
        for (int r = 0; r < 4; ++r) {
            int grow = row0 + wr + m * 16 + lk * 4 + r;
            if (grow < n) {
                float dv = dinv[grow];
                __hip_bfloat16* crow = C + (size_t)grow * 128 + lrow;
                #pragma unroll
                for (int nf = 0; nf < 8; ++nf) {
                    crow[nf * 16] = __float2bfloat16(acc[m][nf][r] * dv);
                }
            }
        }
    }
}

// ---------------- 128-ch aggregation: one wave per node, bf16 gathers, 8x unroll ----------------

__global__ void k_agg128(const unsigned int* __restrict__ hb, const int* __restrict__ ss,
                         const int* __restrict__ offs, const float* __restrict__ dinv,
                         const float* __restrict__ bias, float* __restrict__ hout, int n) {
    int wid = threadIdx.x >> 6, lane = threadIdx.x & 63;
    int node = blockIdx.x * (blockDim.x >> 6) + wid;
    if (node >= n) return;
    unsigned int self = hb[(size_t)node * 64 + lane];
    float ax = __uint_as_float(self << 16);
    float ay = __uint_as_float(self & 0xffff0000u);
    int e = offs[node], e1 = offs[node + 1];
    for (; e + 8 <= e1; e += 8) {
        int s0 = ss[e], s1 = ss[e+1], s2 = ss[e+2], s3 = ss[e+3];
        int s4 = ss[e+4], s5 = ss[e+5], s6 = ss[e+6], s7 = ss[e+7];
        unsigned int v0 = hb[(size_t)s0 * 64 + lane];
        unsigned int v1 = hb[(size_t)s1 * 64 + lane];
        unsigned int v2 = hb[(size_t)s2 * 64 + lane];
        unsigned int v3 = hb[(size_t)s3 * 64 + lane];
        unsigned int v4 = hb[(size_t)s4 * 64 + lane];
        unsigned int v5 = hb[(size_t)s5 * 64 + lane];
        unsigned int v6 = hb[(size_t)s6 * 64 + lane];
        unsigned int v7 = hb[(size_t)s7 * 64 + lane];
        ax += __uint_as_float(v0 << 16); ay += __uint_as_float(v0 & 0xffff0000u);
        ax += __uint_as_float(v1 << 16); ay += __uint_as_float(v1 & 0xffff0000u);
        ax += __uint_as_float(v2 << 16); ay += __uint_as_float(v2 & 0xffff0000u);
        ax += __uint_as_float(v3 << 16); ay += __uint_as_float(v3 & 0xffff0000u);
        ax += __uint_as_float(v4 << 16); ay += __uint_as_float(v4 & 0xffff0000u);
        ax += __uint_as_float(v5 << 16); ay += __uint_as_float(v5 & 0xffff0000u);
        ax += __uint_as_float(v6 << 16); ay += __uint_as_float(v6 & 0xffff0000u);
        ax += __uint_as_float(v7 << 16); ay += __uint_as_float(v7 & 0xffff0000u);
    }
    for (; e + 4 <= e1; e += 4) {
        int s0 = ss[e], s1 = ss[e+1], s2 = ss[e+2], s3 = ss[e+3];
        unsigned int v0 = hb[(size_t)s0 * 64 + lane];
        unsigned int v1 = hb[(size_t)s1 * 64 + lane];
        unsigned int v2 = hb[(size_t)s2 * 64 + lane];
        unsigned int v3 = hb[(size_t)s3 * 64 + lane];
        ax += __uint_as_float(v0 << 16); ay += __uint_as_float(v0 & 0xffff0000u);
        ax += __uint_as_float(v1 << 16); ay += __uint_as_float(v1 & 0xffff0000u);
        ax += __uint_as_float(v2 << 16); ay += __uint_as_float(v2 & 0xffff0000u);
        ax += __uint_as_float(v3 << 16); ay += __uint_as_float(v3 & 0xffff0000u);
    }
    for (; e < e1; ++e) {
        unsigned int v = hb[(size_t)ss[e] * 64 + lane];
        ax += __uint_as_float(v << 16);
        ay += __uint_as_float(v & 0xffff0000u);
    }
    float dn = dinv[node];
    float2 b = ((const float2*)bias)[lane];
    float2 o; o.x = ax * dn + b.x; o.y = ay * dn + b.y;
    ((float2*)hout)[(size_t)node * 64 + lane] = o;
}

// ---------------- pooling + head ----------------

__global__ void k_zero_pool(float* __restrict__ gsum) {
    int i = blockIdx.x * blockDim.x + threadIdx.x;
    if (i < 64 * 128) gsum[i] = 0.f;
}

__global__ void k_bounds(const int* __restrict__ batch, int* __restrict__ gcnt, int n) {
    __shared__ int b[65];
    int g = threadIdx.x;
    if (g <= 64) {
        int lo = 0, hi = n;
        while (lo < hi) {
            int mid = (lo + hi) >> 1;
            if (batch[mid] < g) lo = mid + 1; else hi = mid;
        }
        b[g] = lo;
    }
    __syncthreads();
    if (g < 64) gcnt[g] = b[g + 1] - b[g];
}

__global__ void k_pool(const float* __restrict__ h, const int* __restrict__ batch,
                       const float* __restrict__ ab, float* __restrict__ gsum,
                       int n, int rows_per_block) {
    int tid = threadIdx.x; int c = tid & 127; int half = tid >> 7;
    int r0 = blockIdx.x * rows_per_block;
    int r1 = min(r0 + rows_per_block, n);
    int half_len = rows_per_block >> 1;
    int rs = r0 + half * half_len;
    int re = min(rs + half_len, r1);
    float A = ab[c], B = ab[128 + c];
    float acc = 0.f; int cur = -1;
    for (int r = rs; r < re; ++r) {
        int g = batch[r];
        if (g != cur) {
            if (cur >= 0) atomicAdd(&gsum[cur * 128 + c], acc);
            acc = 0.f; cur = g;
        }
        float v = h[(size_t)r * 128 + c];
        acc += fmaxf(0.f, v * A + B);
    }
    if (cur >= 0) atomicAdd(&gsum[cur * 128 + c], acc);
}

__global__ void k_final(const float* __restrict__ gsum, const int* __restrict__ gcnt,
                        const float* __restrict__ embW, const float* __restrict__ embb,
                        float* __restrict__ out) {
    __shared__ float row[128];
    int g = blockIdx.x, j = threadIdx.x;  // 64 threads
    float invc = 1.f / fmaxf((float)gcnt[g], 1.f);
    for (int i = j; i < 128; i += 64) row[i] = gsum[g * 128 + i] * invc;
    __syncthreads();
    float acc = embb[j];
    for (int cdx = 0; cdx < 128; ++cdx) acc += row[cdx] * embW[cdx * 64 + j];
    out[g * 64 + j] = acc;
}

// ---------------- launch ----------------

extern "C" void kernel_launch(void* const* d_in, const int* in_sizes, int n_in,
                              void* d_out, int out_size, void* d_ws, size_t ws_size,
                              hipStream_t stream) {
    const float* x     = (const float*)d_in[0];
    const float* W0    = (const float*)d_in[1];
    const float* Wh    = (const float*)d_in[2];
    const float* bias  = (const float*)d_in[3];
    const float* gamma = (const float*)d_in[4];
    const float* beta  = (const float*)d_in[5];
    const float* embW  = (const float*)d_in[6];
    const float* embb  = (const float*)d_in[7];
    const int*   ei    = (const int*)d_in[8];
    const int*   batch = (const int*)d_in[9];
    int N = in_sizes[9];
    int E = in_sizes[8] / 2;
    const int* src = ei;
    const int* dst = ei + E;
    int B = (N + 255) >> 8;  // buckets of 256 nodes

    char* w = (char*)d_ws;
    size_t off = 0;
    auto carve = [&](size_t bytes) {
        char* p = w + off;
        off = (off + bytes + 255) & ~(size_t)255;
        return (void*)p;
    };
    float* dinv   = (float*)carve((size_t)N * 4);
    int*   offs   = (int*)carve((size_t)(N + 1) * 4);
    int*   ss     = (int*)carve((size_t)E * 4);
    unsigned int* pairs = (unsigned int*)carve((size_t)E * 4);
    int*   hist   = (int*)carve((size_t)B * 256 * 4);
    int*   sbase  = (int*)carve(((size_t)B * 256 + 1) * 4);
    float* out5   = (float*)carve((size_t)N * 5 * 4);
    float* xs     = (float*)carve((size_t)N * 8 * 4);
    float* hA     = (float*)carve((size_t)N * 128 * 4);
    __hip_bfloat16* hB = (__hip_bfloat16*)carve((size_t)N * 128 * 2);
    float* part   = (float*)carve(256 * 512 * 4);
    float* ab     = (float*)carve(256 * 4);
    float* gsum   = (float*)carve(64 * 128 * 4);
    int*   gcnt   = (int*)carve(64 * 4);
    int*   tsum   = (int*)carve(65536 * 4);
    int*   bsum   = (int*)carve(256 * 4);
    int*   bbase  = (int*)carve(257 * 4);
    (void)ws_size; (void)n_in; (void)out_size;

    int nb = (N + 255) / 256;
    int gb = (N + 127) / 128;
    int ab4 = (N + 3) / 4;
    int echunk = (E + 255) / 256;
    int nH = B * 256;
    int ctH = (nH + 65535) / 65536;

    // graph prep: bucket histogram -> scan -> scatter pairs -> per-bucket CSR (+dinv/xs)
    k_hist<<<256, 256, 0, stream>>>(dst, hist, E, B, echunk);
    g_scan1<<<256, 256, 0, stream>>>(hist, tsum, bsum, nH, ctH);
    g_scan2<<<1, 256, 0, stream>>>(bsum, bbase);
    g_scan3<<<256, 256, 0, stream>>>(hist, tsum, bbase, sbase, nH, ctH);
    k_scatter<<<256, 256, 0, stream>>>(src, dst, sbase, pairs, E, B, echunk);
    k_bucket<<<B, 256, 0, stream>>>(pairs, sbase, x, dinv, xs, offs, ss, N);

    // layer 0
    k_agg5<<<nb, 256, 0, stream>>>(xs, ss, offs, dinv, out5, N);
    k_gemm0<<<(N * 128 + 255) / 256, 256, 0, stream>>>(out5, W0, bias, hA, N);
    k_bnstats<<<256, 256, 0, stream>>>(hA, part, N);
    k_bnfinal<<<1, 128, 0, stream>>>(part, 256, gamma, beta, ab, N);

    // layer 1
    k_gemm128<<<gb, 256, 0, stream>>>(hA, Wh, ab, dinv, hB, N);
    k_agg128<<<ab4, 256, 0, stream>>>((const unsigned int*)hB, ss, offs, dinv, bias + 128, hA, N);
    k_bnstats<<<256, 256, 0, stream>>>(hA, part, N);
    k_bnfinal<<<1, 128, 0, stream>>>(part, 256, gamma + 128, beta + 128, ab, N);

    // layer 2
    k_gemm128<<<gb, 256, 0, stream>>>(hA, Wh + 128 * 128, ab, dinv, hB, N);
    k_agg128<<<ab4, 256, 0, stream>>>((const unsigned int*)hB, ss, offs, dinv, bias + 256, hA, N);
    k_bnstats<<<256, 256, 0, stream>>>(hA, part, N);
    k_bnfinal<<<1, 128, 0, stream>>>(part, 256, gamma + 256, beta + 256, ab, N);

    // pool (fuses layer-2 BN+ReLU) + head
    k_zero_pool<<<(64 * 128 + 255) / 256, 256, 0, stream>>>(gsum);
    k_bounds<<<1, 128, 0, stream>>>(batch, gcnt, N);
    int rpb = 512;
    k_pool<<<(N + rpb - 1) / rpb, 256, 0, stream>>>(hA, batch, ab, gsum, N, rpb);
    k_final<<<64, 64, 0, stream>>>(gsum, gcnt, embW, embb, (float*)d_out);
}

// Round 9
// 925.966 us; speedup vs baseline: 2.8479x; 1.0606x over previous
//
#include <hip/hip_runtime.h>
#include <hip/hip_bf16.h>

constexpr float BN_EPS = 1e-5f;
typedef __attribute__((ext_vector_type(8))) short short8;
typedef __attribute__((ext_vector_type(4))) float f32x4;

// ---------------- graph preprocessing ----------------

// per-(bucket,block) histogram of dst (LDS atomics only)
__global__ void k_hist(const int* __restrict__ dst, int* __restrict__ hist,
                       int E, int B, int chunk) {
    __shared__ int lh[512];
    int t = threadIdx.x, blk = blockIdx.x;
    for (int i = t; i < 512; i += 256) lh[i] = 0;
    __syncthreads();
    int e0 = blk * chunk, e1 = min(E, e0 + chunk);
    for (int e = e0 + t; e < e1; e += 256) {
        atomicAdd(&lh[dst[e] >> 8], 1);
    }
    __syncthreads();
    for (int b = t; b < B; b += 256) hist[b * 256 + blk] = lh[b];
}

// ---- generic exclusive scan over int array ----

__global__ void g_scan1(const int* __restrict__ in, int* __restrict__ tsum,
                        int* __restrict__ bsum, int n, int ct) {
    int t = threadIdx.x, b = blockIdx.x;
    int i = b * 256 + t;
    int s0 = i * ct, s1 = min(n, s0 + ct);
    int s = 0;
    for (int k = s0; k < s1; ++k) s += in[k];
    tsum[i] = s;
    __shared__ int red[256];
    red[t] = s; __syncthreads();
    for (int d = 128; d > 0; d >>= 1) {
        if (t < d) red[t] += red[t + d];
        __syncthreads();
    }
    if (t == 0) bsum[b] = red[0];
}

__global__ void g_scan2(const int* __restrict__ bsum, int* __restrict__ bbase) {
    int t = threadIdx.x;  // 256
    __shared__ int sh[256];
    int v = bsum[t];
    sh[t] = v; __syncthreads();
    for (int d = 1; d < 256; d <<= 1) {
        int u = (t >= d) ? sh[t - d] : 0;
        __syncthreads();
        sh[t] += u;
        __syncthreads();
    }
    bbase[t] = sh[t] - v;  // exclusive
    if (t == 255) bbase[256] = sh[255];
}

__global__ void g_scan3(const int* __restrict__ in, const int* __restrict__ tsum,
                        const int* __restrict__ bbase, int* __restrict__ out,
                        int n, int ct) {
    int t = threadIdx.x, b = blockIdx.x;
    __shared__ int sh[256];
    int v = tsum[b * 256 + t];
    sh[t] = v; __syncthreads();
    for (int d = 1; d < 256; d <<= 1) {
        int u = (t >= d) ? sh[t - d] : 0;
        __syncthreads();
        sh[t] += u;
        __syncthreads();
    }
    int run = bbase[b] + sh[t] - v;
    int i = b * 256 + t;
    int s0 = i * ct, s1 = min(n, s0 + ct);
    for (int k = s0; k < s1; ++k) {
        out[k] = run;
        run += in[k];
    }
    if (i == 65535) out[n] = bbase[256];
}

// scatter edges into bucket-grouped pairs, block-exclusive streams
__global__ void k_scatter(const int* __restrict__ src, const int* __restrict__ dst,
                          const int* __restrict__ sbase, unsigned int* __restrict__ pairs,
                          int E, int B, int chunk) {
    __shared__ int cur[512];
    int t = threadIdx.x, blk = blockIdx.x;
    for (int b = t; b < B; b += 256) cur[b] = sbase[b * 256 + blk];
    __syncthreads();
    int e0 = blk * chunk, e1 = min(E, e0 + chunk);
    for (int e = e0 + t; e < e1; e += 256) {
        int d = dst[e];
        int s = src[e];
        int p = atomicAdd(&cur[d >> 8], 1);
        pairs[p] = ((unsigned int)s << 8) | (unsigned int)(d & 255);
    }
}

// one block per bucket: local degrees (LDS hist) -> LDS scan -> offs/dinv/xs(+pad8)
// then fill ss from pairs (second pass hits warm L2)
__global__ void k_bucket(const unsigned int* __restrict__ pairs, const int* __restrict__ sbase,
                         const float* __restrict__ x, float* __restrict__ dinv,
                         float* __restrict__ xs, int* __restrict__ offs,
                         int* __restrict__ ss, int n) {
    __shared__ int sh[256];
    __shared__ int cur[256];
    int t = threadIdx.x, b = blockIdx.x;
    int p0 = sbase[b * 256];
    int p1 = sbase[b * 256 + 256];
    sh[t] = 0;
    __syncthreads();
    for (int p = p0 + t; p < p1; p += 256) {
        atomicAdd(&sh[pairs[p] & 255], 1);
    }
    __syncthreads();
    int cnt = sh[t];
    __syncthreads();
    sh[t] = cnt; __syncthreads();
    for (int d = 1; d < 256; d <<= 1) {
        int u = (t >= d) ? sh[t - d] : 0;
        __syncthreads();
        sh[t] += u;
        __syncthreads();
    }
    int excl = sh[t] - cnt;
    int node = b * 256 + t;
    if (node < n) {
        offs[node] = p0 + excl;
        if (node == n - 1) offs[n] = p0 + excl + cnt;
        float d = rsqrtf((float)(cnt + 1));  // +1 self loop
        dinv[node] = d;
        const float* xr = x + (size_t)node * 5;
        float* o = xs + (size_t)node * 8;
        #pragma unroll
        for (int j = 0; j < 5; ++j) o[j] = xr[j] * d;
        o[5] = 0.f; o[6] = 0.f; o[7] = 0.f;
    }
    cur[t] = p0 + excl;
    __syncthreads();
    for (int p = p0 + t; p < p1; p += 256) {
        unsigned int pk = pairs[p];
        int pos = atomicAdd(&cur[pk & 255], 1);
        ss[pos] = pk >> 8;
    }
}

// ---------------- layer 0: aggregate pre-scaled x' (8-padded), GEMM to 128 ----------------

__global__ void k_agg5(const float* __restrict__ xs, const int* __restrict__ ss,
                       const int* __restrict__ offs, const float* __restrict__ dinv,
                       float* __restrict__ out5, int n) {
    int node = blockIdx.x * blockDim.x + threadIdx.x;
    if (node >= n) return;
    const float* xr = xs + (size_t)node * 8;
    float a0 = xr[0], a1 = xr[1], a2 = xr[2], a3 = xr[3], a4 = xr[4];
    int e = offs[node], e1 = offs[node + 1];
    for (; e + 4 <= e1; e += 4) {
        int s0 = ss[e], s1 = ss[e + 1], s2 = ss[e + 2], s3 = ss[e + 3];
        float4 v0 = *(const float4*)(xs + (size_t)s0 * 8);
        float  w0 = xs[(size_t)s0 * 8 + 4];
        float4 v1 = *(const float4*)(xs + (size_t)s1 * 8);
        float  w1 = xs[(size_t)s1 * 8 + 4];
        float4 v2 = *(const float4*)(xs + (size_t)s2 * 8);
        float  w2 = xs[(size_t)s2 * 8 + 4];
        float4 v3 = *(const float4*)(xs + (size_t)s3 * 8);
        float  w3 = xs[(size_t)s3 * 8 + 4];
        a0 += v0.x + v1.x + v2.x + v3.x;
        a1 += v0.y + v1.y + v2.y + v3.y;
        a2 += v0.z + v1.z + v2.z + v3.z;
        a3 += v0.w + v1.w + v2.w + v3.w;
        a4 += w0 + w1 + w2 + w3;
    }
    for (; e < e1; ++e) {
        int s = ss[e];
        float4 v = *(const float4*)(xs + (size_t)s * 8);
        a0 += v.x; a1 += v.y; a2 += v.z; a3 += v.w; a4 += xs[(size_t)s * 8 + 4];
    }
    float dn = dinv[node];
    float* o = out5 + (size_t)node * 5;
    o[0] = a0 * dn; o[1] = a1 * dn; o[2] = a2 * dn; o[3] = a3 * dn; o[4] = a4 * dn;
}

// writes bf16 h (packed pairs), 2 channels per thread
__global__ void k_gemm0(const float* __restrict__ out5, const float* __restrict__ W0,
                        const float* __restrict__ bias0, unsigned int* __restrict__ h, int n) {
    __shared__ float w[5 * 128];
    __shared__ float b[128];
    int tid = threadIdx.x;
    for (int i = tid; i < 640; i += blockDim.x) w[i] = W0[i];
    if (tid < 128) b[tid] = bias0[tid];
    __syncthreads();
    int idx = blockIdx.x * blockDim.x + tid;
    if (idx < n * 64) {
        int node = idx >> 6, c2 = idx & 63;
        int c0 = c2 * 2, c1 = c0 + 1;
        const float* a = out5 + (size_t)node * 5;
        float r0 = b[c0] + a[0]*w[c0] + a[1]*w[128+c0] + a[2]*w[256+c0]
                         + a[3]*w[384+c0] + a[4]*w[512+c0];
        float r1 = b[c1] + a[0]*w[c1] + a[1]*w[128+c1] + a[2]*w[256+c1]
                         + a[3]*w[384+c1] + a[4]*w[512+c1];
        __hip_bfloat162 b2 = __float22bfloat162_rn(make_float2(r0, r1));
        h[idx] = *reinterpret_cast<unsigned int*>(&b2);
    }
}

// ---------------- BatchNorm (reads bf16 h) ----------------

__global__ void k_bnstats(const __hip_bfloat16* __restrict__ h, float* __restrict__ part, int n) {
    int tid = threadIdx.x;
    int c = tid & 127, half = tid >> 7;
    float s = 0.f, q = 0.f;
    for (int r = blockIdx.x * 2 + half; r < n; r += gridDim.x * 2) {
        float v = __bfloat162float(h[(size_t)r * 128 + c]);
        s += v; q += v * v;
    }
    part[blockIdx.x * 512 + tid] = s;
    part[blockIdx.x * 512 + 256 + tid] = q;
}

__global__ void k_bnfinal(const float* __restrict__ part, int nblocks,
                          const float* __restrict__ gamma, const float* __restrict__ beta,
                          float* __restrict__ ab, int n) {
    int c = threadIdx.x;  // 128
    float s = 0.f, q = 0.f;
    for (int b = 0; b < nblocks; ++b) {
        const float* p = part + b * 512;
        s += p[c] + p[c + 128];
        q += p[256 + c] + p[256 + c + 128];
    }
    float mean = s / n;
    float var = q / n - mean * mean;
    float inv = rsqrtf(var + BN_EPS);
    float A = gamma[c] * inv;
    ab[c] = A;
    ab[128 + c] = beta[c] - mean * A;
}

// ------- MFMA bf16 GEMM: bf16 A in, BN+ReLU fused on A-load,
//         epilogue: scale row by dinv[row], emit bf16 -------

__global__ __launch_bounds__(256) void k_gemm128(const unsigned int* __restrict__ A,
                                                 const float* __restrict__ W,
                                                 const float* __restrict__ ab,
                                                 const float* __restrict__ dinv,
                                                 __hip_bfloat16* __restrict__ C, int n) {
    __shared__ uint4 AsU[2048];   // 32 KiB: As[row][k] bf16, byte ^= (row&7)<<4
    __shared__ uint4 WsU[2048];   // 32 KiB: Wt[col][k] bf16, byte ^= (col&7)<<4
    char* Asb = (char*)AsU;
    char* Wsb = (char*)WsU;
    int tid = threadIdx.x;
    int row0 = blockIdx.x * 128;

    const float4* W4 = (const float4*)W;
    for (int i = tid; i < 4096; i += 256) {
        float4 wv = W4[i];
        int k = i >> 5;
        int colq = (i & 31) << 2;
        #pragma unroll
        for (int j = 0; j < 4; ++j) {
            int col = colq + j;
            int byte = col * 256 + ((((k & ~7) * 2) ^ ((col & 7) << 4)) | ((k & 7) * 2));
            *(__hip_bfloat16*)(Wsb + byte) = __float2bfloat16((&wv.x)[j]);
        }
    }
    const float4* ab4 = (const float4*)ab;
    for (int g = tid; g < 2048; g += 256) {
        int r = g >> 4, kg = g & 15;
        int grow = row0 + r;
        uint4 pack = make_uint4(0, 0, 0, 0);
        if (grow < n) {
            uint4 raw = *(const uint4*)(A + (size_t)grow * 64 + kg * 4);
            float4 A0 = ab4[kg * 2], A1 = ab4[kg * 2 + 1];
            float4 B0 = ab4[32 + kg * 2], B1 = ab4[32 + kg * 2 + 1];
            float Af[8] = {A0.x, A0.y, A0.z, A0.w, A1.x, A1.y, A1.z, A1.w};
            float Bf[8] = {B0.x, B0.y, B0.z, B0.w, B1.x, B1.y, B1.z, B1.w};
            unsigned int* ru = (unsigned int*)&raw;
            unsigned int* pu = (unsigned int*)&pack;
            #pragma unroll
            for (int j = 0; j < 4; ++j) {
                unsigned int u = ru[j];
                float lo = __uint_as_float(u << 16);
                float hi = __uint_as_float(u & 0xffff0000u);
                float f0 = fmaxf(0.f, lo * Af[2 * j] + Bf[2 * j]);
                float f1 = fmaxf(0.f, hi * Af[2 * j + 1] + Bf[2 * j + 1]);
                __hip_bfloat162 b2 = __float22bfloat162_rn(make_float2(f0, f1));
                pu[j] = *reinterpret_cast<unsigned int*>(&b2);
            }
        }
        int byte = r * 256 + ((kg << 4) ^ ((r & 7) << 4));
        *(uint4*)(Asb + byte) = pack;
    }
    __syncthreads();

    int wv_ = tid >> 6, lane = tid & 63;
    int wr = wv_ * 32;
    int lrow = lane & 15, lk = lane >> 4;
    f32x4 acc[2][8];
    #pragma unroll
    for (int m = 0; m < 2; ++m)
        #pragma unroll
        for (int nf = 0; nf < 8; ++nf) acc[m][nf] = (f32x4)(0.f);

    #pragma unroll
    for (int kk = 0; kk < 4; ++kk) {
        int k0 = kk * 32 + lk * 8;
        int ra = wr + lrow;
        int rb = wr + 16 + lrow;
        short8 a0 = *(short8*)(Asb + ra * 256 + ((k0 * 2) ^ ((ra & 7) << 4)));
        short8 a1 = *(short8*)(Asb + rb * 256 + ((k0 * 2) ^ ((rb & 7) << 4)));
        #pragma unroll
        for (int nf = 0; nf < 8; ++nf) {
            int col = nf * 16 + lrow;
            short8 b = *(short8*)(Wsb + col * 256 + ((k0 * 2) ^ ((col & 7) << 4)));
            acc[0][nf] = __builtin_amdgcn_mfma_f32_16x16x32_bf16(a0, b, acc[0][nf], 0, 0, 0);
            acc[1][nf] = __builtin_amdgcn_mfma_f32_16x16x32_bf16(a1, b, acc[1][nf], 0, 0, 0);
        }
    }

    #pragma unroll
    for (int m = 0; m < 2; ++m) {
        #pragma unroll
        for (int r = 0; r < 4; ++r) {
            int grow = row0 + wr + m * 16 + lk * 4 + r;
            if (grow < n) {
                float dv = dinv[grow];
                __hip_bfloat16* crow = C + (size_t)grow * 128 + lrow;
                #pragma unroll
                for (int nf = 0; nf < 8; ++nf) {
                    crow[nf * 16] = __float2bfloat16(acc[m][nf][r] * dv);
                }
            }
        }
    }
}

// ---------------- 128-ch aggregation: one wave per node, bf16 in/out, 8x unroll ----------------

__global__ void k_agg128(const unsigned int* __restrict__ hb, const int* __restrict__ ss,
                         const int* __restrict__ offs, const float* __restrict__ dinv,
                         const float* __restrict__ bias, unsigned int* __restrict__ hout, int n) {
    int wid = threadIdx.x >> 6, lane = threadIdx.x & 63;
    int node = blockIdx.x * (blockDim.x >> 6) + wid;
    if (node >= n) return;
    unsigned int self = hb[(size_t)node * 64 + lane];
    float ax = __uint_as_float(self << 16);
    float ay = __uint_as_float(self & 0xffff0000u);
    int e = offs[node], e1 = offs[node + 1];
    for (; e + 8 <= e1; e += 8) {
        int s0 = ss[e], s1 = ss[e+1], s2 = ss[e+2], s3 = ss[e+3];
        int s4 = ss[e+4], s5 = ss[e+5], s6 = ss[e+6], s7 = ss[e+7];
        unsigned int v0 = hb[(size_t)s0 * 64 + lane];
        unsigned int v1 = hb[(size_t)s1 * 64 + lane];
        unsigned int v2 = hb[(size_t)s2 * 64 + lane];
        unsigned int v3 = hb[(size_t)s3 * 64 + lane];
        unsigned int v4 = hb[(size_t)s4 * 64 + lane];
        unsigned int v5 = hb[(size_t)s5 * 64 + lane];
        unsigned int v6 = hb[(size_t)s6 * 64 + lane];
        unsigned int v7 = hb[(size_t)s7 * 64 + lane];
        ax += __uint_as_float(v0 << 16); ay += __uint_as_float(v0 & 0xffff0000u);
        ax += __uint_as_float(v1 << 16); ay += __uint_as_float(v1 & 0xffff0000u);
        ax += __uint_as_float(v2 << 16); ay += __uint_as_float(v2 & 0xffff0000u);
        ax += __uint_as_float(v3 << 16); ay += __uint_as_float(v3 & 0xffff0000u);
        ax += __uint_as_float(v4 << 16); ay += __uint_as_float(v4 & 0xffff0000u);
        ax += __uint_as_float(v5 << 16); ay += __uint_as_float(v5 & 0xffff0000u);
        ax += __uint_as_float(v6 << 16); ay += __uint_as_float(v6 & 0xffff0000u);
        ax += __uint_as_float(v7 << 16); ay += __uint_as_float(v7 & 0xffff0000u);
    }
    for (; e + 4 <= e1; e += 4) {
        int s0 = ss[e], s1 = ss[e+1], s2 = ss[e+2], s3 = ss[e+3];
        unsigned int v0 = hb[(size_t)s0 * 64 + lane];
        unsigned int v1 = hb[(size_t)s1 * 64 + lane];
        unsigned int v2 = hb[(size_t)s2 * 64 + lane];
        unsigned int v3 = hb[(size_t)s3 * 64 + lane];
        ax += __uint_as_float(v0 << 16); ay += __uint_as_float(v0 & 0xffff0000u);
        ax += __uint_as_float(v1 << 16); ay += __uint_as_float(v1 & 0xffff0000u);
        ax += __uint_as_float(v2 << 16); ay += __uint_as_float(v2 & 0xffff0000u);
        ax += __uint_as_float(v3 << 16); ay += __uint_as_float(v3 & 0xffff0000u);
    }
    for (; e < e1; ++e) {
        unsigned int v = hb[(size_t)ss[e] * 64 + lane];
        ax += __uint_as_float(v << 16);
        ay += __uint_as_float(v & 0xffff0000u);
    }
    float dn = dinv[node];
    float2 b = ((const float2*)bias)[lane];
    float ox = ax * dn + b.x;
    float oy = ay * dn + b.y;
    __hip_bfloat162 b2 = __float22bfloat162_rn(make_float2(ox, oy));
    hout[(size_t)node * 64 + lane] = *reinterpret_cast<unsigned int*>(&b2);
}

// ---------------- pooling + head ----------------

// merged: zero gsum + per-graph bounds (batch sorted)
__global__ void k_preppool(const int* __restrict__ batch, float* __restrict__ gsum,
                           int* __restrict__ gcnt, int n) {
    __shared__ int bsh[65];
    int t = threadIdx.x;  // 256
    for (int i = t; i < 64 * 128; i += 256) gsum[i] = 0.f;
    if (t <= 64) {
        int lo = 0, hi = n;
        while (lo < hi) {
            int mid = (lo + hi) >> 1;
            if (batch[mid] < t) lo = mid + 1; else hi = mid;
        }
        bsh[t] = lo;
    }
    __syncthreads();
    if (t < 64) gcnt[t] = bsh[t + 1] - bsh[t];
}

// applies layer-2 BN+ReLU while pooling (bf16 h input)
__global__ void k_pool(const __hip_bfloat16* __restrict__ h, const int* __restrict__ batch,
                       const float* __restrict__ ab, float* __restrict__ gsum,
                       int n, int rows_per_block) {
    int tid = threadIdx.x; int c = tid & 127; int half = tid >> 7;
    int r0 = blockIdx.x * rows_per_block;
    int r1 = min(r0 + rows_per_block, n);
    int half_len = rows_per_block >> 1;
    int rs = r0 + half * half_len;
    int re = min(rs + half_len, r1);
    float A = ab[c], B = ab[128 + c];
    float acc = 0.f; int cur = -1;
    for (int r = rs; r < re; ++r) {
        int g = batch[r];
        if (g != cur) {
            if (cur >= 0) atomicAdd(&gsum[cur * 128 + c], acc);
            acc = 0.f; cur = g;
        }
        float v = __bfloat162float(h[(size_t)r * 128 + c]);
        acc += fmaxf(0.f, v * A + B);
    }
    if (cur >= 0) atomicAdd(&gsum[cur * 128 + c], acc);
}

__global__ void k_final(const float* __restrict__ gsum, const int* __restrict__ gcnt,
                        const float* __restrict__ embW, const float* __restrict__ embb,
                        float* __restrict__ out) {
    __shared__ float row[128];
    int g = blockIdx.x, j = threadIdx.x;  // 64 threads
    float invc = 1.f / fmaxf((float)gcnt[g], 1.f);
    for (int i = j; i < 128; i += 64) row[i] = gsum[g * 128 + i] * invc;
    __syncthreads();
    float acc = embb[j];
    for (int cdx = 0; cdx < 128; ++cdx) acc += row[cdx] * embW[cdx * 64 + j];
    out[g * 64 + j] = acc;
}

// ---------------- launch ----------------

extern "C" void kernel_launch(void* const* d_in, const int* in_sizes, int n_in,
                              void* d_out, int out_size, void* d_ws, size_t ws_size,
                              hipStream_t stream) {
    const float* x     = (const float*)d_in[0];
    const float* W0    = (const float*)d_in[1];
    const float* Wh    = (const float*)d_in[2];
    const float* bias  = (const float*)d_in[3];
    const float* gamma = (const float*)d_in[4];
    const float* beta  = (const float*)d_in[5];
    const float* embW  = (const float*)d_in[6];
    const float* embb  = (const float*)d_in[7];
    const int*   ei    = (const int*)d_in[8];
    const int*   batch = (const int*)d_in[9];
    int N = in_sizes[9];
    int E = in_sizes[8] / 2;
    const int* src = ei;
    const int* dst = ei + E;
    int B = (N + 255) >> 8;  // buckets of 256 nodes

    char* w = (char*)d_ws;
    size_t off = 0;
    auto carve = [&](size_t bytes) {
        char* p = w + off;
        off = (off + bytes + 255) & ~(size_t)255;
        return (void*)p;
    };
    float* dinv   = (float*)carve((size_t)N * 4);
    int*   offs   = (int*)carve((size_t)(N + 1) * 4);
    int*   ss     = (int*)carve((size_t)E * 4);
    unsigned int* pairs = (unsigned int*)carve((size_t)E * 4);
    int*   hist   = (int*)carve((size_t)B * 256 * 4);
    int*   sbase  = (int*)carve(((size_t)B * 256 + 1) * 4);
    float* out5   = (float*)carve((size_t)N * 5 * 4);
    float* xs     = (float*)carve((size_t)N * 8 * 4);
    unsigned int* hA = (unsigned int*)carve((size_t)N * 128 * 2);  // bf16 h
    __hip_bfloat16* hB = (__hip_bfloat16*)carve((size_t)N * 128 * 2);
    float* part   = (float*)carve(256 * 512 * 4);
    float* ab     = (float*)carve(256 * 4);
    float* gsum   = (float*)carve(64 * 128 * 4);
    int*   gcnt   = (int*)carve(64 * 4);
    int*   tsum   = (int*)carve(65536 * 4);
    int*   bsum   = (int*)carve(256 * 4);
    int*   bbase  = (int*)carve(257 * 4);
    (void)ws_size; (void)n_in; (void)out_size;

    int nb = (N + 255) / 256;
    int gb = (N + 127) / 128;
    int ab4 = (N + 3) / 4;
    int echunk = (E + 255) / 256;
    int nH = B * 256;
    int ctH = (nH + 65535) / 65536;

    // graph prep
    k_hist<<<256, 256, 0, stream>>>(dst, hist, E, B, echunk);
    g_scan1<<<256, 256, 0, stream>>>(hist, tsum, bsum, nH, ctH);
    g_scan2<<<1, 256, 0, stream>>>(bsum, bbase);
    g_scan3<<<256, 256, 0, stream>>>(hist, tsum, bbase, sbase, nH, ctH);
    k_scatter<<<256, 256, 0, stream>>>(src, dst, sbase, pairs, E, B, echunk);
    k_bucket<<<B, 256, 0, stream>>>(pairs, sbase, x, dinv, xs, offs, ss, N);

    // layer 0
    k_agg5<<<nb, 256, 0, stream>>>(xs, ss, offs, dinv, out5, N);
    k_gemm0<<<(N * 64 + 255) / 256, 256, 0, stream>>>(out5, W0, bias, hA, N);
    k_bnstats<<<256, 256, 0, stream>>>((const __hip_bfloat16*)hA, part, N);
    k_bnfinal<<<1, 128, 0, stream>>>(part, 256, gamma, beta, ab, N);

    // layer 1
    k_gemm128<<<gb, 256, 0, stream>>>(hA, Wh, ab, dinv, hB, N);
    k_agg128<<<ab4, 256, 0, stream>>>((const unsigned int*)hB, ss, offs, dinv, bias + 128, hA, N);
    k_bnstats<<<256, 256, 0, stream>>>((const __hip_bfloat16*)hA, part, N);
    k_bnfinal<<<1, 128, 0, stream>>>(part, 256, gamma + 128, beta + 128, ab, N);

    // layer 2
    k_gemm128<<<gb, 256, 0, stream>>>(hA, Wh + 128 * 128, ab, dinv, hB, N);
    k_agg128<<<ab4, 256, 0, stream>>>((const unsigned int*)hB, ss, offs, dinv, bias + 256, hA, N);
    k_bnstats<<<256, 256, 0, stream>>>((const __hip_bfloat16*)hA, part, N);
    k_bnfinal<<<1, 128, 0, stream>>>(part, 256, gamma + 256, beta + 256, ab, N);

    // pool (fuses layer-2 BN+ReLU) + head
    k_preppool<<<1, 256, 0, stream>>>(batch, gsum, gcnt, N);
    int rpb = 512;
    k_pool<<<(N + rpb - 1) / rpb, 256, 0, stream>>>((const __hip_bfloat16*)hA, batch, ab, gsum, N, rpb);
    k_final<<<64, 64, 0, stream>>>(gsum, gcnt, embW, embb, (float*)d_out);
}

// Round 11
// 841.547 us; speedup vs baseline: 3.1336x; 1.1003x over previous
//
#include <hip/hip_runtime.h>
#include <hip/hip_bf16.h>

constexpr float BN_EPS = 1e-5f;
typedef __attribute__((ext_vector_type(8))) short short8;
typedef __attribute__((ext_vector_type(4))) float f32x4;

// ---------------- weight prep: Wh (2x128x128 fp32) -> bf16 swizzled W^T ----------------
// layout: wt[L*32768 + col*256 + ((((k&~7)*2) ^ ((col&7)<<4)) | ((k&7)*2))] (bytes)

__global__ void k_prepw(const float* __restrict__ Wh, char* __restrict__ wt) {
    int t = blockIdx.x * blockDim.x + threadIdx.x;  // 32768
    int L = t >> 14;
    int rem = t & 16383;
    int k = rem >> 7, col = rem & 127;
    float v = Wh[(size_t)L * 16384 + k * 128 + col];
    int byte = L * 32768 + col * 256 + ((((k & ~7) * 2) ^ ((col & 7) << 4)) | ((k & 7) * 2));
    *(__hip_bfloat16*)(wt + byte) = __float2bfloat16(v);
}

// ---------------- graph preprocessing ----------------

__global__ void k_hist(const int* __restrict__ dst, int* __restrict__ hist,
                       int E, int B, int chunk) {
    __shared__ int lh[512];
    int t = threadIdx.x, blk = blockIdx.x;
    for (int i = t; i < 512; i += 256) lh[i] = 0;
    __syncthreads();
    int e0 = blk * chunk, e1 = min(E, e0 + chunk);
    for (int e = e0 + t; e < e1; e += 256) {
        atomicAdd(&lh[dst[e] >> 8], 1);
    }
    __syncthreads();
    for (int b = t; b < B; b += 256) hist[b * 256 + blk] = lh[b];
}

__global__ void g_scan1(const int* __restrict__ in, int* __restrict__ tsum,
                        int* __restrict__ bsum, int n, int ct) {
    int t = threadIdx.x, b = blockIdx.x;
    int i = b * 256 + t;
    int s0 = i * ct, s1 = min(n, s0 + ct);
    int s = 0;
    for (int k = s0; k < s1; ++k) s += in[k];
    tsum[i] = s;
    __shared__ int red[256];
    red[t] = s; __syncthreads();
    for (int d = 128; d > 0; d >>= 1) {
        if (t < d) red[t] += red[t + d];
        __syncthreads();
    }
    if (t == 0) bsum[b] = red[0];
}

// scan3 with inline bsum scan (removes old g_scan2)
__global__ void g_scan3(const int* __restrict__ in, const int* __restrict__ tsum,
                        const int* __restrict__ bsum, int* __restrict__ out,
                        int n, int ct) {
    int t = threadIdx.x, b = blockIdx.x;
    __shared__ int sh[256];
    __shared__ int bb[256];
    int bv = bsum[t];
    bb[t] = bv; __syncthreads();
    for (int d = 1; d < 256; d <<= 1) {
        int u = (t >= d) ? bb[t - d] : 0;
        __syncthreads();
        bb[t] += u;
        __syncthreads();
    }
    // bb now inclusive scan of bsum
    int v = tsum[b * 256 + t];
    sh[t] = v; __syncthreads();
    for (int d = 1; d < 256; d <<= 1) {
        int u = (t >= d) ? sh[t - d] : 0;
        __syncthreads();
        sh[t] += u;
        __syncthreads();
    }
    int bbase = bb[b] - bsum[b];  // exclusive block base
    int run = bbase + sh[t] - v;
    int i = b * 256 + t;
    int s0 = i * ct, s1 = min(n, s0 + ct);
    for (int k = s0; k < s1; ++k) {
        out[k] = run;
        run += in[k];
    }
    if (i == 65535) out[n] = bb[255];
}

__global__ void k_scatter(const int* __restrict__ src, const int* __restrict__ dst,
                          const int* __restrict__ sbase, unsigned int* __restrict__ pairs,
                          int E, int B, int chunk) {
    __shared__ int cur[512];
    int t = threadIdx.x, blk = blockIdx.x;
    for (int b = t; b < B; b += 256) cur[b] = sbase[b * 256 + blk];
    __syncthreads();
    int e0 = blk * chunk, e1 = min(E, e0 + chunk);
    for (int e = e0 + t; e < e1; e += 256) {
        int d = dst[e];
        int s = src[e];
        int p = atomicAdd(&cur[d >> 8], 1);
        pairs[p] = ((unsigned int)s << 8) | (unsigned int)(d & 255);
    }
}

__global__ void k_bucket(const unsigned int* __restrict__ pairs, const int* __restrict__ sbase,
                         const float* __restrict__ x, float* __restrict__ dinv,
                         float* __restrict__ xs, int* __restrict__ offs,
                         int* __restrict__ ss, int n) {
    __shared__ int sh[256];
    __shared__ int cur[256];
    int t = threadIdx.x, b = blockIdx.x;
    int p0 = sbase[b * 256];
    int p1 = sbase[b * 256 + 256];
    sh[t] = 0;
    __syncthreads();
    for (int p = p0 + t; p < p1; p += 256) {
        atomicAdd(&sh[pairs[p] & 255], 1);
    }
    __syncthreads();
    int cnt = sh[t];
    __syncthreads();
    sh[t] = cnt; __syncthreads();
    for (int d = 1; d < 256; d <<= 1) {
        int u = (t >= d) ? sh[t - d] : 0;
        __syncthreads();
        sh[t] += u;
        __syncthreads();
    }
    int excl = sh[t] - cnt;
    int node = b * 256 + t;
    if (node < n) {
        offs[node] = p0 + excl;
        if (node == n - 1) offs[n] = p0 + excl + cnt;
        float d = rsqrtf((float)(cnt + 1));  // +1 self loop
        dinv[node] = d;
        const float* xr = x + (size_t)node * 5;
        float* o = xs + (size_t)node * 8;
        #pragma unroll
        for (int j = 0; j < 5; ++j) o[j] = xr[j] * d;
        o[5] = 0.f; o[6] = 0.f; o[7] = 0.f;
    }
    cur[t] = p0 + excl;
    __syncthreads();
    for (int p = p0 + t; p < p1; p += 256) {
        unsigned int pk = pairs[p];
        int pos = atomicAdd(&cur[pk & 255], 1);
        ss[pos] = pk >> 8;
    }
}

// ---------------- layer 0 fused: agg5 + GEMM0 (+bias), bf16 out ----------------

__global__ __launch_bounds__(256) void k_layer0(const float* __restrict__ xs,
                                                const int* __restrict__ ss,
                                                const int* __restrict__ offs,
                                                const float* __restrict__ dinv,
                                                const float* __restrict__ W0,
                                                const float* __restrict__ bias0,
                                                unsigned int* __restrict__ h, int n) {
    __shared__ float xv[256 * 5];
    __shared__ float w[640];
    __shared__ float bsh[128];
    int t = threadIdx.x, blk = blockIdx.x;
    for (int i = t; i < 640; i += 256) w[i] = W0[i];
    if (t < 128) bsh[t] = bias0[t];

    int node = blk * 256 + t;
    float a0 = 0.f, a1 = 0.f, a2 = 0.f, a3 = 0.f, a4 = 0.f;
    if (node < n) {
        const float* xr = xs + (size_t)node * 8;
        a0 = xr[0]; a1 = xr[1]; a2 = xr[2]; a3 = xr[3]; a4 = xr[4];
        int e = offs[node], e1 = offs[node + 1];
        for (; e + 4 <= e1; e += 4) {
            int s0 = ss[e], s1 = ss[e + 1], s2 = ss[e + 2], s3 = ss[e + 3];
            float4 v0 = *(const float4*)(xs + (size_t)s0 * 8);
            float  w0 = xs[(size_t)s0 * 8 + 4];
            float4 v1 = *(const float4*)(xs + (size_t)s1 * 8);
            float  w1 = xs[(size_t)s1 * 8 + 4];
            float4 v2 = *(const float4*)(xs + (size_t)s2 * 8);
            float  w2 = xs[(size_t)s2 * 8 + 4];
            float4 v3 = *(const float4*)(xs + (size_t)s3 * 8);
            float  w3 = xs[(size_t)s3 * 8 + 4];
            a0 += v0.x + v1.x + v2.x + v3.x;
            a1 += v0.y + v1.y + v2.y + v3.y;
            a2 += v0.z + v1.z + v2.z + v3.z;
            a3 += v0.w + v1.w + v2.w + v3.w;
            a4 += w0 + w1 + w2 + w3;
        }
        for (; e < e1; ++e) {
            int s = ss[e];
            float4 v = *(const float4*)(xs + (size_t)s * 8);
            a0 += v.x; a1 += v.y; a2 += v.z; a3 += v.w; a4 += xs[(size_t)s * 8 + 4];
        }
        float dn = dinv[node];
        a0 *= dn; a1 *= dn; a2 *= dn; a3 *= dn; a4 *= dn;
    }
    float* xp = &xv[t * 5];
    xp[0] = a0; xp[1] = a1; xp[2] = a2; xp[3] = a3; xp[4] = a4;
    __syncthreads();

    // phase B: 64 lanes cover 128 channels; wave w handles local nodes w*64..w*64+63
    int cp = t & 63, wgrp = t >> 6;
    int c0 = cp * 2, c1 = c0 + 1;
    float w00 = w[c0], w01 = w[128 + c0], w02 = w[256 + c0], w03 = w[384 + c0], w04 = w[512 + c0];
    float w10 = w[c1], w11 = w[128 + c1], w12 = w[256 + c1], w13 = w[384 + c1], w14 = w[512 + c1];
    float b0 = bsh[c0], b1 = bsh[c1];
    for (int i = 0; i < 64; ++i) {
        int ln = wgrp * 64 + i;
        int gnode = blk * 256 + ln;
        if (gnode < n) {
            const float* a = &xv[ln * 5];
            float r0 = b0 + a[0]*w00 + a[1]*w01 + a[2]*w02 + a[3]*w03 + a[4]*w04;
            float r1 = b1 + a[0]*w10 + a[1]*w11 + a[2]*w12 + a[3]*w13 + a[4]*w14;
            __hip_bfloat162 b2 = __float22bfloat162_rn(make_float2(r0, r1));
            h[(size_t)gnode * 64 + cp] = *reinterpret_cast<unsigned int*>(&b2);
        }
    }
}

// ---------------- BatchNorm: 64 blocks, uint loads, LDS reduce -> part[64][256] ----------------

__global__ void k_bnstats(const unsigned int* __restrict__ h2, float* __restrict__ part, int n) {
    __shared__ float4 red[256];
    int t = threadIdx.x, blk = blockIdx.x;
    int cp = t & 63, rg = t >> 6;
    float s0 = 0.f, s1 = 0.f, q0 = 0.f, q1 = 0.f;
    for (int r = blk * 4 + rg; r < n; r += 256) {
        unsigned int v = h2[(size_t)r * 64 + cp];
        float lo = __uint_as_float(v << 16);
        float hi = __uint_as_float(v & 0xffff0000u);
        s0 += lo; s1 += hi; q0 += lo * lo; q1 += hi * hi;
    }
    red[t] = make_float4(s0, s1, q0, q1);
    __syncthreads();
    if (t < 64) {
        float4 a = red[t], b = red[t + 64], c = red[t + 128], d = red[t + 192];
        float fs0 = a.x + b.x + c.x + d.x;
        float fs1 = a.y + b.y + c.y + d.y;
        float fq0 = a.z + b.z + c.z + d.z;
        float fq1 = a.w + b.w + c.w + d.w;
        float* p = part + blk * 256;
        p[2 * t] = fs0; p[2 * t + 1] = fs1;
        p[128 + 2 * t] = fq0; p[128 + 2 * t + 1] = fq1;
    }
}

// also zeroes gsum when non-null (used on the last layer, right before pooling)
__global__ void k_bnfinal(const float* __restrict__ part,
                          const float* __restrict__ gamma, const float* __restrict__ beta,
                          float* __restrict__ ab, float* __restrict__ gsum, int n) {
    int c = threadIdx.x;  // 128
    float s = 0.f, q = 0.f;
    for (int b = 0; b < 64; ++b) {
        s += part[b * 256 + c];
        q += part[b * 256 + 128 + c];
    }
    float mean = s / n;
    float var = q / n - mean * mean;
    float inv = rsqrtf(var + BN_EPS);
    float A = gamma[c] * inv;
    ab[c] = A;
    ab[128 + c] = beta[c] - mean * A;
    if (gsum) {
        for (int i = c; i < 64 * 128; i += 128) gsum[i] = 0.f;
    }
}

// ------- MFMA bf16 GEMM: bf16 A in, BN+ReLU fused on A-load, pre-swizzled bf16 W^T,
//         epilogue: scale row by dinv[row], emit bf16 -------

__global__ __launch_bounds__(256) void k_gemm128(const unsigned int* __restrict__ A,
                                                 const char* __restrict__ wt,
                                                 const float* __restrict__ ab,
                                                 const float* __restrict__ dinv,
                                                 __hip_bfloat16* __restrict__ C, int n) {
    __shared__ uint4 AsU[2048];   // 32 KiB: As[row][k] bf16, byte ^= (row&7)<<4
    __shared__ uint4 WsU[2048];   // 32 KiB: pre-swizzled Wt
    char* Asb = (char*)AsU;
    char* Wsb = (char*)WsU;
    int tid = threadIdx.x;
    int row0 = blockIdx.x * 128;

    const uint4* wt4 = (const uint4*)wt;
    for (int i = tid; i < 2048; i += 256) WsU[i] = wt4[i];

    const float4* ab4 = (const float4*)ab;
    for (int g = tid; g < 2048; g += 256) {
        int r = g >> 4, kg = g & 15;
        int grow = row0 + r;
        uint4 pack = make_uint4(0, 0, 0, 0);
        if (grow < n) {
            uint4 raw = *(const uint4*)(A + (size_t)grow * 64 + kg * 4);
            float4 A0 = ab4[kg * 2], A1 = ab4[kg * 2 + 1];
            float4 B0 = ab4[32 + kg * 2], B1 = ab4[32 + kg * 2 + 1];
            float Af[8] = {A0.x, A0.y, A0.z, A0.w, A1.x, A1.y, A1.z, A1.w};
            float Bf[8] = {B0.x, B0.y, B0.z, B0.w, B1.x, B1.y, B1.z, B1.w};
            unsigned int* ru = (unsigned int*)&raw;
            unsigned int* pu = (unsigned int*)&pack;
            #pragma unroll
            for (int j = 0; j < 4; ++j) {
                unsigned int u = ru[j];
                float lo = __uint_as_float(u << 16);
                float hi = __uint_as_float(u & 0xffff0000u);
                float f0 = fmaxf(0.f, lo * Af[2 * j] + Bf[2 * j]);
                float f1 = fmaxf(0.f, hi * Af[2 * j + 1] + Bf[2 * j + 1]);
                __hip_bfloat162 b2 = __float22bfloat162_rn(make_float2(f0, f1));
                pu[j] = *reinterpret_cast<unsigned int*>(&b2);
            }
        }
        int byte = r * 256 + ((kg << 4) ^ ((r & 7) << 4));
        *(uint4*)(Asb + byte) = pack;
    }
    __syncthreads();

    int wv_ = tid >> 6, lane = tid & 63;
    int wr = wv_ * 32;
    int lrow = lane & 15, lk = lane >> 4;
    f32x4 acc[2][8];
    #pragma unroll
    for (int m = 0; m < 2; ++m)
        #pragma unroll
        for (int nf = 0; nf < 8; ++nf) acc[m][nf] = (f32x4)(0.f);

    #pragma unroll
    for (int kk = 0; kk < 4; ++kk) {
        int k0 = kk * 32 + lk * 8;
        int ra = wr + lrow;
        int rb = wr + 16 + lrow;
        short8 a0 = *(short8*)(Asb + ra * 256 + ((k0 * 2) ^ ((ra & 7) << 4)));
        short8 a1 = *(short8*)(Asb + rb * 256 + ((k0 * 2) ^ ((rb & 7) << 4)));
        #pragma unroll
        for (int nf = 0; nf < 8; ++nf) {
            int col = nf * 16 + lrow;
            short8 b = *(short8*)(Wsb + col * 256 + ((k0 * 2) ^ ((col & 7) << 4)));
            acc[0][nf] = __builtin_amdgcn_mfma_f32_16x16x32_bf16(a0, b, acc[0][nf], 0, 0, 0);
            acc[1][nf] = __builtin_amdgcn_mfma_f32_16x16x32_bf16(a1, b, acc[1][nf], 0, 0, 0);
        }
    }

    #pragma unroll
    for (int m = 0; m < 2; ++m) {
        #pragma unroll
        for (int r = 0; r < 4; ++r) {
            int grow = row0 + wr + m * 16 + lk * 4 + r;
            if (grow < n) {
                float dv = dinv[grow];
                __hip_bfloat16* crow = C + (size_t)grow * 128 + lrow;
                #pragma unroll
                for (int nf = 0; nf < 8; ++nf) {
                    crow[nf * 16] = __float2bfloat16(acc[m][nf][r] * dv);
                }
            }
        }
    }
}

// ---------------- 128-ch aggregation: one wave per node, bf16 in/out, 8x unroll ----------------

__global__ void k_agg128(const unsigned int* __restrict__ hb, const int* __restrict__ ss,
                         const int* __restrict__ offs, const float* __restrict__ dinv,
                         const float* __restrict__ bias, unsigned int* __restrict__ hout, int n) {
    int wid = threadIdx.x >> 6, lane = threadIdx.x & 63;
    int node = blockIdx.x * (blockDim.x >> 6) + wid;
    if (node >= n) return;
    unsigned int self = hb[(size_t)node * 64 + lane];
    float ax = __uint_as_float(self << 16);
    float ay = __uint_as_float(self & 0xffff0000u);
    int e = offs[node], e1 = offs[node + 1];
    for (; e + 8 <= e1; e += 8) {
        int s0 = ss[e], s1 = ss[e+1], s2 = ss[e+2], s3 = ss[e+3];
        int s4 = ss[e+4], s5 = ss[e+5], s6 = ss[e+6], s7 = ss[e+7];
        unsigned int v0 = hb[(size_t)s0 * 64 + lane];
        unsigned int v1 = hb[(size_t)s1 * 64 + lane];
        unsigned int v2 = hb[(size_t)s2 * 64 + lane];
        unsigned int v3 = hb[(size_t)s3 * 64 + lane];
        unsigned int v4 = hb[(size_t)s4 * 64 + lane];
        unsigned int v5 = hb[(size_t)s5 * 64 + lane];
        unsigned int v6 = hb[(size_t)s6 * 64 + lane];
        unsigned int v7 = hb[(size_t)s7 * 64 + lane];
        ax += __uint_as_float(v0 << 16); ay += __uint_as_float(v0 & 0xffff0000u);
        ax += __uint_as_float(v1 << 16); ay += __uint_as_float(v1 & 0xffff0000u);
        ax += __uint_as_float(v2 << 16); ay += __uint_as_float(v2 & 0xffff0000u);
        ax += __uint_as_float(v3 << 16); ay += __uint_as_float(v3 & 0xffff0000u);
        ax += __uint_as_float(v4 << 16); ay += __uint_as_float(v4 & 0xffff0000u);
        ax += __uint_as_float(v5 << 16); ay += __uint_as_float(v5 & 0xffff0000u);
        ax += __uint_as_float(v6 << 16); ay += __uint_as_float(v6 & 0xffff0000u);
        ax += __uint_as_float(v7 << 16); ay += __uint_as_float(v7 & 0xffff0000u);
    }
    for (; e + 4 <= e1; e += 4) {
        int s0 = ss[e], s1 = ss[e+1], s2 = ss[e+2], s3 = ss[e+3];
        unsigned int v0 = hb[(size_t)s0 * 64 + lane];
        unsigned int v1 = hb[(size_t)s1 * 64 + lane];
        unsigned int v2 = hb[(size_t)s2 * 64 + lane];
        unsigned int v3 = hb[(size_t)s3 * 64 + lane];
        ax += __uint_as_float(v0 << 16); ay += __uint_as_float(v0 & 0xffff0000u);
        ax += __uint_as_float(v1 << 16); ay += __uint_as_float(v1 & 0xffff0000u);
        ax += __uint_as_float(v2 << 16); ay += __uint_as_float(v2 & 0xffff0000u);
        ax += __uint_as_float(v3 << 16); ay += __uint_as_float(v3 & 0xffff0000u);
    }
    for (; e < e1; ++e) {
        unsigned int v = hb[(size_t)ss[e] * 64 + lane];
        ax += __uint_as_float(v << 16);
        ay += __uint_as_float(v & 0xffff0000u);
    }
    float dn = dinv[node];
    float2 b = ((const float2*)bias)[lane];
    float ox = ax * dn + b.x;
    float oy = ay * dn + b.y;
    __hip_bfloat162 b2 = __float22bfloat162_rn(make_float2(ox, oy));
    hout[(size_t)node * 64 + lane] = *reinterpret_cast<unsigned int*>(&b2);
}

// ---------------- pooling + head ----------------

// applies layer-2 BN+ReLU while pooling (bf16 h, uint loads, 2ch/thread)
__global__ void k_pool(const unsigned int* __restrict__ h2, const int* __restrict__ batch,
                       const float* __restrict__ ab, float* __restrict__ gsum,
                       int n, int rows_per_block) {
    int tid = threadIdx.x;
    int cp = tid & 63, rg = tid >> 6;
    int c0 = cp * 2, c1 = c0 + 1;
    int r0 = blockIdx.x * rows_per_block;
    int r1 = min(r0 + rows_per_block, n);
    int qlen = rows_per_block >> 2;
    int rs = r0 + rg * qlen;
    int re = min(rs + qlen, r1);
    float A0 = ab[c0], B0 = ab[128 + c0];
    float A1 = ab[c1], B1 = ab[128 + c1];
    float a0 = 0.f, a1 = 0.f; int cur = -1;
    for (int r = rs; r < re; ++r) {
        int g = batch[r];
        if (g != cur) {
            if (cur >= 0) {
                atomicAdd(&gsum[cur * 128 + c0], a0);
                atomicAdd(&gsum[cur * 128 + c1], a1);
            }
            a0 = 0.f; a1 = 0.f; cur = g;
        }
        unsigned int v = h2[(size_t)r * 64 + cp];
        float lo = __uint_as_float(v << 16);
        float hi = __uint_as_float(v & 0xffff0000u);
        a0 += fmaxf(0.f, lo * A0 + B0);
        a1 += fmaxf(0.f, hi * A1 + B1);
    }
    if (cur >= 0) {
        atomicAdd(&gsum[cur * 128 + c0], a0);
        atomicAdd(&gsum[cur * 128 + c1], a1);
    }
}

// head; computes its own per-graph counts (batch sorted)
__global__ void k_final(const float* __restrict__ gsum, const int* __restrict__ batch,
                        const float* __restrict__ embW, const float* __restrict__ embb,
                        float* __restrict__ out, int n) {
    __shared__ float row[128];
    __shared__ int bnd[2];
    int g = blockIdx.x, j = threadIdx.x;  // 64 threads
    if (j < 2) {
        int target = g + j;
        int lo = 0, hi = n;
        while (lo < hi) {
            int mid = (lo + hi) >> 1;
            if (batch[mid] < target) lo = mid + 1; else hi = mid;
        }
        bnd[j] = lo;
    }
    __syncthreads();
    float cnt = (float)(bnd[1] - bnd[0]);
    float invc = 1.f / fmaxf(cnt, 1.f);
    for (int i = j; i < 128; i += 64) row[i] = gsum[g * 128 + i] * invc;
    __syncthreads();
    float acc = embb[j];
    for (int cdx = 0; cdx < 128; ++cdx) acc += row[cdx] * embW[cdx * 64 + j];
    out[g * 64 + j] = acc;
}

// ---------------- launch ----------------

extern "C" void kernel_launch(void* const* d_in, const int* in_sizes, int n_in,
                              void* d_out, int out_size, void* d_ws, size_t ws_size,
                              hipStream_t stream) {
    const float* x     = (const float*)d_in[0];
    const float* W0    = (const float*)d_in[1];
    const float* Wh    = (const float*)d_in[2];
    const float* bias  = (const float*)d_in[3];
    const float* gamma = (const float*)d_in[4];
    const float* beta  = (const float*)d_in[5];
    const float* embW  = (const float*)d_in[6];
    const float* embb  = (const float*)d_in[7];
    const int*   ei    = (const int*)d_in[8];
    const int*   batch = (const int*)d_in[9];
    int N = in_sizes[9];
    int E = in_sizes[8] / 2;
    const int* src = ei;
    const int* dst = ei + E;
    int B = (N + 255) >> 8;  // buckets of 256 nodes

    char* w = (char*)d_ws;
    size_t off = 0;
    auto carve = [&](size_t bytes) {
        char* p = w + off;
        off = (off + bytes + 255) & ~(size_t)255;
        return (void*)p;
    };
    float* dinv   = (float*)carve((size_t)N * 4);
    int*   offs   = (int*)carve((size_t)(N + 1) * 4);
    int*   ss     = (int*)carve((size_t)E * 4);
    unsigned int* pairs = (unsigned int*)carve((size_t)E * 4);
    int*   hist   = (int*)carve((size_t)B * 256 * 4);
    int*   sbase  = (int*)carve(((size_t)B * 256 + 1) * 4);
    float* xs     = (float*)carve((size_t)N * 8 * 4);
    unsigned int* hA = (unsigned int*)carve((size_t)N * 128 * 2);  // bf16 h
    __hip_bfloat16* hB = (__hip_bfloat16*)carve((size_t)N * 128 * 2);
    char*  wt     = (char*)carve(2 * 32768);
    float* part   = (float*)carve(64 * 256 * 4);
    float* ab     = (float*)carve(256 * 4);
    float* gsum   = (float*)carve(64 * 128 * 4);
    int*   tsum   = (int*)carve(65536 * 4);
    int*   bsum   = (int*)carve(256 * 4);
    (void)ws_size; (void)n_in; (void)out_size;

    int nb = (N + 255) / 256;
    int gb = (N + 127) / 128;
    int ab4 = (N + 3) / 4;
    int echunk = (E + 255) / 256;
    int nH = B * 256;
    int ctH = (nH + 65535) / 65536;

    // weight prep + graph prep
    k_prepw<<<128, 256, 0, stream>>>(Wh, wt);
    k_hist<<<256, 256, 0, stream>>>(dst, hist, E, B, echunk);
    g_scan1<<<256, 256, 0, stream>>>(hist, tsum, bsum, nH, ctH);
    g_scan3<<<256, 256, 0, stream>>>(hist, tsum, bsum, sbase, nH, ctH);
    k_scatter<<<256, 256, 0, stream>>>(src, dst, sbase, pairs, E, B, echunk);
    k_bucket<<<B, 256, 0, stream>>>(pairs, sbase, x, dinv, xs, offs, ss, N);

    // layer 0 (fused agg5+gemm0)
    k_layer0<<<nb, 256, 0, stream>>>(xs, ss, offs, dinv, W0, bias, hA, N);
    k_bnstats<<<64, 256, 0, stream>>>(hA, part, N);
    k_bnfinal<<<1, 128, 0, stream>>>(part, gamma, beta, ab, nullptr, N);

    // layer 1
    k_gemm128<<<gb, 256, 0, stream>>>(hA, wt, ab, dinv, hB, N);
    k_agg128<<<ab4, 256, 0, stream>>>((const unsigned int*)hB, ss, offs, dinv, bias + 128, hA, N);
    k_bnstats<<<64, 256, 0, stream>>>(hA, part, N);
    k_bnfinal<<<1, 128, 0, stream>>>(part, gamma + 128, beta + 128, ab, nullptr, N);

    // layer 2
    k_gemm128<<<gb, 256, 0, stream>>>(hA, wt + 32768, ab, dinv, hB, N);
    k_agg128<<<ab4, 256, 0, stream>>>((const unsigned int*)hB, ss, offs, dinv, bias + 256, hA, N);
    k_bnstats<<<64, 256, 0, stream>>>(hA, part, N);
    k_bnfinal<<<1, 128, 0, stream>>>(part, gamma + 256, beta + 256, ab, gsum, N);  // zeroes gsum

    // pool (fuses layer-2 BN+ReLU) + head
    int rpb = 512;
    k_pool<<<(N + rpb - 1) / rpb, 256, 0, stream>>>(hA, batch, ab, gsum, N, rpb);
    k_final<<<64, 64, 0, stream>>>(gsum, batch, embW, embb, (float*)d_out, N);
}